// Round 1
// baseline (2067.015 us; speedup 1.0000x reference)
//
#include <hip/hip_runtime.h>
#include <math.h>

#define ROIN 116
#define NBZ 1024
#define FLATN 13456
#define NROWS (NBZ*ROIN)   // 118784
#define ALPHA 0.1f
#define ACOEF 0.9f
#define BETAC 2
#define EPSBN 1e-5f

__device__ __forceinline__ float leakyf(float v){ return v >= 0.f ? v : 0.2f*v; }

// ---------------------------------------------------------------------------
// Tiled fp32 GEMM, NN layout: C[M,N] = epi(A[M,K] @ B[K,N] (+ bias))
// EPI: 0 raw split-K partial (C += z*M*N, no bias), 1 bias, 2 relu(bias),
//      3 leaky(bias), 4 X + leaky(bias)
// Block: 256 threads, 64x64 tile, BK=16, 4x4 per-thread accumulators.
// M must be a multiple of 64 (true for 1024 and 118784). N,K arbitrary.
// ---------------------------------------------------------------------------
template<int EPI>
__global__ __launch_bounds__(256) void gemm_nn(
    const float* __restrict__ A, const float* __restrict__ B,
    const float* __restrict__ bias, const float* __restrict__ X,
    float* __restrict__ C, int M, int N, int K, int KS)
{
    __shared__ float As[16][65];
    __shared__ float Bs[16][65];
    const int tid = threadIdx.x;
    const int m0 = blockIdx.x * 64;
    const int n0 = blockIdx.y * 64;
    const int k0 = blockIdx.z * KS;
    const int k1 = min(K, k0 + KS);
    const int tm4 = (tid >> 4) * 4;
    const int tn4 = (tid & 15) * 4;
    const int mA  = tid >> 2;          // 0..63
    const int kbA = (tid & 3) * 4;     // 0,4,8,12
    const int nB  = tid & 63;          // 0..63
    const int kB0 = tid >> 6;          // 0..3
    float acc[4][4] = {};
    for (int kt = k0; kt < k1; kt += 16) {
        const float* Arow = A + (size_t)(m0 + mA) * K;
        #pragma unroll
        for (int kk = 0; kk < 4; ++kk) {
            int kg = kt + kbA + kk;
            As[kbA + kk][mA] = (kg < k1) ? Arow[kg] : 0.f;
        }
        #pragma unroll
        for (int q = 0; q < 4; ++q) {
            int k = kB0 + q * 4;
            int kg = kt + k;
            Bs[k][nB] = (kg < k1 && (n0 + nB) < N) ? B[(size_t)kg * N + n0 + nB] : 0.f;
        }
        __syncthreads();
        #pragma unroll
        for (int k = 0; k < 16; ++k) {
            float a[4], b[4];
            #pragma unroll
            for (int i = 0; i < 4; ++i) a[i] = As[k][tm4 + i];
            #pragma unroll
            for (int j = 0; j < 4; ++j) b[j] = Bs[k][tn4 + j];
            #pragma unroll
            for (int i = 0; i < 4; ++i)
                #pragma unroll
                for (int j = 0; j < 4; ++j)
                    acc[i][j] = fmaf(a[i], b[j], acc[i][j]);
        }
        __syncthreads();
    }
    float* Cb = (EPI == 0) ? (C + (size_t)blockIdx.z * M * N) : C;
    #pragma unroll
    for (int i = 0; i < 4; ++i) {
        int m = m0 + tm4 + i;
        #pragma unroll
        for (int j = 0; j < 4; ++j) {
            int n = n0 + tn4 + j;
            if (n < N) {
                size_t idx = (size_t)m * N + n;
                float v = acc[i][j];
                if (EPI == 0) { Cb[idx] = v; }
                else {
                    v += bias[n];
                    if (EPI == 2) v = fmaxf(v, 0.f);
                    else if (EPI == 3) v = leakyf(v);
                    else if (EPI == 4) v = X[idx] + leakyf(v);
                    Cb[idx] = v;
                }
            }
        }
    }
}

// ---------------------------------------------------------------------------
// Tiled fp32 GEMM, NT layout: C[M,N] = A[M,K] @ B2[N,K]^T (both row-major).
// MODE 0: full grid, scale, write C.  MODE 1: symmetric (skip lower blocks),
// scale, mirror write.  MODE 2: symmetric split-K raw partial.
// ---------------------------------------------------------------------------
template<int MODE>
__global__ __launch_bounds__(256) void gemm_nt(
    const float* __restrict__ A, const float* __restrict__ B2,
    float* __restrict__ C, int M, int N, int K, int KS, float scale)
{
    if (MODE >= 1 && blockIdx.y < blockIdx.x) return;
    __shared__ float As[16][65];
    __shared__ float Bs[16][65];
    const int tid = threadIdx.x;
    const int m0 = blockIdx.x * 64;
    const int n0 = blockIdx.y * 64;
    const int k0 = blockIdx.z * KS;
    const int k1 = min(K, k0 + KS);
    const int tm4 = (tid >> 4) * 4;
    const int tn4 = (tid & 15) * 4;
    const int rA  = tid >> 2;
    const int kbA = (tid & 3) * 4;
    float acc[4][4] = {};
    for (int kt = k0; kt < k1; kt += 16) {
        #pragma unroll
        for (int kk = 0; kk < 4; ++kk) {
            int kg = kt + kbA + kk;
            As[kbA + kk][rA] = (kg < k1) ? A[(size_t)(m0 + rA) * K + kg] : 0.f;
            Bs[kbA + kk][rA] = (kg < k1 && (n0 + rA) < N) ? B2[(size_t)(n0 + rA) * K + kg] : 0.f;
        }
        __syncthreads();
        #pragma unroll
        for (int k = 0; k < 16; ++k) {
            float a[4], b[4];
            #pragma unroll
            for (int i = 0; i < 4; ++i) a[i] = As[k][tm4 + i];
            #pragma unroll
            for (int j = 0; j < 4; ++j) b[j] = Bs[k][tn4 + j];
            #pragma unroll
            for (int i = 0; i < 4; ++i)
                #pragma unroll
                for (int j = 0; j < 4; ++j)
                    acc[i][j] = fmaf(a[i], b[j], acc[i][j]);
        }
        __syncthreads();
    }
    if (MODE == 2) {
        float* Cb = C + (size_t)blockIdx.z * M * N;
        #pragma unroll
        for (int i = 0; i < 4; ++i) {
            int m = m0 + tm4 + i;
            #pragma unroll
            for (int j = 0; j < 4; ++j) {
                int n = n0 + tn4 + j;
                if (n < N) Cb[(size_t)m * N + n] = acc[i][j];
            }
        }
    } else {
        #pragma unroll
        for (int i = 0; i < 4; ++i) {
            int m = m0 + tm4 + i;
            #pragma unroll
            for (int j = 0; j < 4; ++j) {
                int n = n0 + tn4 + j;
                if (n < N) {
                    float v = acc[i][j] * scale;
                    C[(size_t)m * N + n] = v;
                    if (MODE == 1) C[(size_t)n * M + m] = v;  // bitwise-equal on diag blocks
                }
            }
        }
    }
}

// split-K reduce for proj1 (+bias +relu)
__global__ void proj_reduce(const float* __restrict__ ppart,
                            const float* __restrict__ bias, float* __restrict__ t1)
{
    int e = blockIdx.x * 256 + threadIdx.x;
    if (e >= NBZ * ROIN) return;
    int n = e % ROIN;
    float s = 0.f;
    #pragma unroll
    for (int z = 0; z < 8; ++z) s += ppart[(size_t)z * NBZ * ROIN + e];
    t1[e] = fmaxf(s + bias[n], 0.f);
}

// split-K(4) reduce + symmetric mirror for Gram
__global__ void gram_reduce(const float* __restrict__ gpart, float* __restrict__ G)
{
    size_t e = (size_t)blockIdx.x * 256 + threadIdx.x;
    int i = (int)(e >> 10), j = (int)(e & 1023);
    if (j < i) return;
    float s = gpart[e] + gpart[1048576 + e] + gpart[2u * 1048576 + e] + gpart[3u * 1048576 + e];
    G[e] = s;
    G[((size_t)j << 10) + i] = s;
}

// p[1024,116] -> row L2-normalize in place
__global__ void rownorm(float* __restrict__ p)
{
    int row = blockIdx.x, t = threadIdx.x;   // 128 threads
    __shared__ float red[128];
    float x = 0.f, v = 0.f;
    if (t < ROIN) { x = p[row * ROIN + t]; v = x * x; }
    red[t] = v; __syncthreads();
    for (int off = 64; off > 0; off >>= 1) { if (t < off) red[t] += red[t + off]; __syncthreads(); }
    float inv = 1.f / sqrtf(red[0]);
    if (t < ROIN) p[row * ROIN + t] = x * inv;
}

// sq[i] = sum_k xf[i,k]^2
__global__ void row_sumsq(const float* __restrict__ xf, float* __restrict__ sq)
{
    int row = blockIdx.x, t = threadIdx.x;
    const float4* fr = (const float4*)(xf + (size_t)row * FLATN);
    float s = 0.f;
    for (int c = t; c < FLATN / 4; c += 256) {
        float4 v = fr[c];
        s += v.x * v.x + v.y * v.y + v.z * v.z + v.w * v.w;
    }
    __shared__ float red[256];
    red[t] = s; __syncthreads();
    for (int off = 128; off > 0; off >>= 1) { if (t < off) red[t] += red[t + off]; __syncthreads(); }
    if (t == 0) sq[row] = red[0];
}

// global min/max of sim
__global__ void minmax_part(const float* __restrict__ sim, float* __restrict__ mm)
{
    int t = threadIdx.x, b = blockIdx.x;   // 512 x 256
    float mn = 1e30f, mx = -1e30f;
    for (size_t i = (size_t)b * 256 + t; i < 1048576u; i += 512u * 256u) {
        float v = sim[i]; mn = fminf(mn, v); mx = fmaxf(mx, v);
    }
    __shared__ float smn[256], smx[256];
    smn[t] = mn; smx[t] = mx; __syncthreads();
    for (int off = 128; off > 0; off >>= 1) {
        if (t < off) { smn[t] = fminf(smn[t], smn[t + off]); smx[t] = fmaxf(smx[t], smx[t + off]); }
        __syncthreads();
    }
    if (t == 0) { mm[b] = smn[0]; mm[512 + b] = smx[0]; }
}
__global__ void minmax_final(const float* __restrict__ mm, float* __restrict__ fscal)
{
    int t = threadIdx.x;   // 512 threads
    __shared__ float smn[512], smx[512];
    smn[t] = mm[t]; smx[t] = mm[512 + t]; __syncthreads();
    for (int off = 256; off > 0; off >>= 1) {
        if (t < off) { smn[t] = fminf(smn[t], smn[t + off]); smx[t] = fmaxf(smx[t], smx[t + off]); }
        __syncthreads();
    }
    if (t == 0) { fscal[0] = smn[0]; fscal[1] = smx[0]; }
}

// labels[i] = argmax(site[i,0..3]) (first max)
__global__ void labels_k(const int* __restrict__ site, int* __restrict__ labels)
{
    int i = blockIdx.x * 256 + threadIdx.x;
    if (i >= NBZ) return;
    int best = site[4 * i], bi = 0;
    #pragma unroll
    for (int k = 1; k < 4; ++k) { int v = site[4 * i + k]; if (v > best) { best = v; bi = k; } }
    labels[i] = bi;
}

__global__ void rowcnt_k(const int* __restrict__ labels, int* __restrict__ rowcnt)
{
    int i = blockIdx.x * 256 + threadIdx.x;
    if (i >= NBZ) return;
    int li = labels[i], c = 0;
    for (int j = 0; j < NBZ; ++j) c += (labels[j] == li);
    rowcnt[i] = c;
}

// exclusive scan of per-row positive counts; iscal[0]=npos, iscal[1]=m
__global__ __launch_bounds__(1024) void scan_k(const int* __restrict__ rowcnt,
                                               int* __restrict__ rowoff, int* __restrict__ iscal)
{
    __shared__ int s[1024];
    int t = threadIdx.x;
    int c = rowcnt[t];
    s[t] = c; __syncthreads();
    for (int off = 1; off < 1024; off <<= 1) {
        int v = (t >= off) ? s[t - off] : 0;
        __syncthreads();
        s[t] += v;
        __syncthreads();
    }
    rowoff[t] = s[t] - c;
    if (t == 1023) {
        int npos = s[1023];
        int nneg = 1024 * 1024 - npos;
        iscal[0] = npos;
        iscal[1] = (npos < nneg) ? npos : nneg;
    }
}

// scatter sim values to rank-paired pos/neg arrays (flat row-major rank order)
__global__ void pair_scatter(const int* __restrict__ labels, const int* __restrict__ rowoff,
                             const int* __restrict__ iscal, const float* __restrict__ sim,
                             float* __restrict__ posval, float* __restrict__ negval)
{
    int row = blockIdx.x, t = threadIdx.x;
    int m = iscal[1];
    int li = labels[row];
    int j0 = t * 4;
    int eq[4]; int c = 0;
    #pragma unroll
    for (int kk = 0; kk < 4; ++kk) { eq[kk] = (labels[j0 + kk] == li); c += eq[kk]; }
    __shared__ int s[256];
    s[t] = c; __syncthreads();
    for (int off = 1; off < 256; off <<= 1) {
        int v = (t >= off) ? s[t - off] : 0;
        __syncthreads();
        s[t] += v;
        __syncthreads();
    }
    int r = rowoff[row] + s[t] - c;   // positives strictly before flat index
    size_t base = (size_t)row * 1024;
    #pragma unroll
    for (int kk = 0; kk < 4; ++kk) {
        size_t f = base + j0 + kk;
        float v = sim[f];
        if (eq[kk]) { if (r < m) posval[r] = v; r++; }
        else { long nr = (long)f - r; if (nr < m) negval[nr] = v; }
    }
}

__global__ void loss_part(const float* __restrict__ posval, const float* __restrict__ negval,
                          const int* __restrict__ iscal, float* __restrict__ lp)
{
    int m = iscal[1];
    int t = threadIdx.x, b = blockIdx.x;   // 1024 x 256
    float s = 0.f;
    for (int k = b * 256 + t; k < m; k += 1024 * 256) {
        float d = negval[k] - posval[k];
        s += fmaxf(d, 0.f) + log1pf(expf(-fabsf(d)));   // stable softplus
    }
    __shared__ float red[256];
    red[t] = s; __syncthreads();
    for (int off = 128; off > 0; off >>= 1) { if (t < off) red[t] += red[t + off]; __syncthreads(); }
    if (t == 0) lp[b] = red[0];
}

__global__ void loss_final(const float* __restrict__ lp, const int* __restrict__ iscal,
                           float* __restrict__ outp)
{
    int t = threadIdx.x;   // 256
    double s = 0.0;
    for (int k = t; k < 1024; k += 256) s += (double)lp[k];
    __shared__ double red[256];
    red[t] = s; __syncthreads();
    for (int off = 128; off > 0; off >>= 1) { if (t < off) red[t] += red[t + off]; __syncthreads(); }
    if (t == 0) {
        int m = iscal[1]; if (m < 1) m = 1;
        outp[0] = (float)(red[0] / (double)m);
    }
}

// dist (in place over G): total * (cond ? 0.9 : 0.1)
__global__ void dist_k(float* __restrict__ G, const float* __restrict__ sim,
                       const float* __restrict__ sq, const int* __restrict__ ages,
                       const int* __restrict__ genders, const float* __restrict__ fscal)
{
    size_t e = (size_t)blockIdx.x * 256 + threadIdx.x;
    int i = (int)(e >> 10), j = (int)(e & 1023);
    float smin = fscal[0], smax = fscal[1];
    float sn = (sim[e] - smin) / (smax - smin);
    float d2 = fmaxf(sq[i] + sq[j] - 2.f * G[e], 0.f);
    float fs = expf(-ALPHA * sqrtf(d2));
    float total = fs * (1.f - sn) + sn;
    int da = ages[i] - ages[j]; if (da < 0) da = -da;
    bool cond = (da <= BETAC) && (genders[i] == genders[j]);
    G[e] = total * (cond ? ACOEF : 1.f - ACOEF);
}

// row-wise top-8 (ties -> lower index, matching lax.top_k)
__global__ void topk8(const float* __restrict__ dist, float* __restrict__ topv, int* __restrict__ topi)
{
    int row = blockIdx.x, t = threadIdx.x;
    __shared__ float sv[1024];
    __shared__ float rv[256];
    __shared__ int   ri[256];
    for (int j = t; j < 1024; j += 256) sv[j] = dist[(size_t)row * 1024 + j];
    __syncthreads();
    for (int k = 0; k < 8; ++k) {
        float bv = -1e30f; int bi = 1 << 20;
        for (int j = t; j < 1024; j += 256) {
            float x = sv[j];
            if (x > bv || (x == bv && j < bi)) { bv = x; bi = j; }
        }
        rv[t] = bv; ri[t] = bi;
        __syncthreads();
        for (int s = 128; s > 0; s >>= 1) {
            if (t < s) {
                float ov = rv[t + s]; int oi = ri[t + s];
                if (ov > rv[t] || (ov == rv[t] && oi < ri[t])) { rv[t] = ov; ri[t] = oi; }
            }
            __syncthreads();
        }
        if (t == 0) { topv[row * 8 + k] = rv[0]; topi[row * 8 + k] = ri[0]; sv[ri[0]] = -1e30f; }
        __syncthreads();
    }
}

// out[row,:] = sum_k vals[row,k] * feat[idx[row,k], :]   (adj @ feat, 8-sparse rows)
__global__ void adj_gather(const float* __restrict__ vals, const int* __restrict__ idxs,
                           const float* __restrict__ feat, float* __restrict__ out)
{
    int row = blockIdx.x, t = threadIdx.x;
    __shared__ float v[8]; __shared__ int ix[8];
    if (t < 8) { v[t] = vals[row * 8 + t]; ix[t] = idxs[row * 8 + t]; }
    __syncthreads();
    float vv[8]; const float4* fp[8];
    #pragma unroll
    for (int k = 0; k < 8; ++k) { vv[k] = v[k]; fp[k] = (const float4*)(feat + (size_t)ix[k] * FLATN); }
    float4* op = (float4*)(out + (size_t)row * FLATN);
    for (int c = t; c < FLATN / 4; c += 256) {
        float4 acc = {0.f, 0.f, 0.f, 0.f};
        #pragma unroll
        for (int k = 0; k < 8; ++k) {
            float4 x = fp[k][c];
            acc.x = fmaf(vv[k], x.x, acc.x);
            acc.y = fmaf(vv[k], x.y, acc.y);
            acc.z = fmaf(vv[k], x.z, acc.z);
            acc.w = fmaf(vv[k], x.w, acc.w);
        }
        op[c] = acc;
    }
}

// BatchNorm over [118784, 116], per-column, two-stage deterministic
__global__ void bn_part(const float* __restrict__ X, float* __restrict__ part)
{
    int b = blockIdx.x, t = threadIdx.x;   // 116 blocks x 128 threads
    if (t >= ROIN) return;
    float s = 0.f, s2 = 0.f;
    size_t base = (size_t)b * 1024 * ROIN;
    for (int r = 0; r < 1024; ++r) {
        float v = X[base + (size_t)r * ROIN + t];
        s += v; s2 += v * v;
    }
    part[b * 232 + t] = s;
    part[b * 232 + 116 + t] = s2;
}
__global__ void bn_final(const float* __restrict__ part, float* __restrict__ mv)
{
    int t = threadIdx.x;
    if (t >= ROIN) return;
    float s = 0.f, s2 = 0.f;
    for (int b = 0; b < 116; ++b) { s += part[b * 232 + t]; s2 += part[b * 232 + 116 + t]; }
    float mean = s / (float)NROWS;
    float var = s2 / (float)NROWS - mean * mean;
    mv[t] = mean;
    mv[116 + t] = 1.f / sqrtf(var + EPSBN);
}
__global__ void bn_apply(const float* __restrict__ X, const float* __restrict__ mv,
                         const float* __restrict__ g, const float* __restrict__ bta,
                         float* __restrict__ Y)
{
    size_t e = ((size_t)blockIdx.x * 256 + threadIdx.x) * 4;
    if (e >= (size_t)NROWS * ROIN) return;
    int c = (int)(e % ROIN);   // 116 % 4 == 0 -> 4 elems stay in-row
    float4 v = *(const float4*)(X + e);
    float4 r;
    r.x = (v.x - mv[c])     * mv[116 + c]     * g[c]     + bta[c];
    r.y = (v.y - mv[c + 1]) * mv[116 + c + 1] * g[c + 1] + bta[c + 1];
    r.z = (v.z - mv[c + 2]) * mv[116 + c + 2] * g[c + 2] + bta[c + 2];
    r.w = (v.w - mv[c + 3]) * mv[116 + c + 3] * g[c + 3] + bta[c + 3];
    *(float4*)(Y + e) = r;
}

// bn3: per-ROI-channel stats over (N=1024, L=8); writes final output
__global__ void bn3_k(const float* __restrict__ X, const float* __restrict__ g,
                      const float* __restrict__ bta, float* __restrict__ out)
{
    int c = blockIdx.x, t = threadIdx.x;   // 116 x 256
    float s = 0.f, s2 = 0.f;
    for (int k = t; k < 8192; k += 256) {
        int n = k >> 3, l = k & 7;
        float v = X[(size_t)n * 928 + c * 8 + l];
        s += v; s2 += v * v;
    }
    __shared__ float rs[256], rs2[256];
    rs[t] = s; rs2[t] = s2; __syncthreads();
    for (int off = 128; off > 0; off >>= 1) {
        if (t < off) { rs[t] += rs[t + off]; rs2[t] += rs2[t + off]; }
        __syncthreads();
    }
    __shared__ float sm, sr;
    if (t == 0) {
        float mean = rs[0] / 8192.f;
        float var = rs2[0] / 8192.f - mean * mean;
        sm = mean; sr = 1.f / sqrtf(var + EPSBN);
    }
    __syncthreads();
    float mean = sm, rstd = sr, gg = g[c], bb = bta[c];
    for (int k = t; k < 8192; k += 256) {
        int n = k >> 3, l = k & 7;
        size_t idx = (size_t)n * 928 + c * 8 + l;
        out[idx] = (X[idx] - mean) * rstd * gg + bb;
    }
}

// ---------------------------------------------------------------------------
extern "C" void kernel_launch(void* const* d_in, const int* in_sizes, int n_in,
                              void* d_out, int out_size, void* d_ws, size_t ws_size,
                              hipStream_t stream)
{
    const float* x        = (const float*)d_in[0];
    const float* pseudo   = (const float*)d_in[1];
    const int*   ages     = (const int*)d_in[2];
    const int*   genders  = (const int*)d_in[3];
    const int*   site     = (const int*)d_in[4];
    const float* fc_p_w   = (const float*)d_in[5];
    const float* fc_p_b   = (const float*)d_in[6];
    const float* proj_w1  = (const float*)d_in[7];
    const float* proj_b1  = (const float*)d_in[8];
    const float* proj_w2  = (const float*)d_in[9];
    const float* proj_b2  = (const float*)d_in[10];
    const float* gcn_w1   = (const float*)d_in[11];
    const float* gcn_b1   = (const float*)d_in[12];
    const float* gcn_w2   = (const float*)d_in[13];
    const float* gcn_b2   = (const float*)d_in[14];
    const float* gcn1_w   = (const float*)d_in[15];
    const float* gcn1_b   = (const float*)d_in[16];
    const float* gcn2_w1  = (const float*)d_in[17];
    const float* gcn2_b1  = (const float*)d_in[18];
    const float* gcn2_w2  = (const float*)d_in[19];
    const float* gcn2_b2  = (const float*)d_in[20];
    const float* bn1_g    = (const float*)d_in[21];
    const float* bn1_b    = (const float*)d_in[22];
    const float* bn2_g    = (const float*)d_in[23];
    const float* bn2_b    = (const float*)d_in[24];
    const float* bn3_g    = (const float*)d_in[25];
    const float* bn3_b    = (const float*)d_in[26];
    float* dout = (float*)d_out;

    // workspace carve-up (256B aligned)
    char* w = (char*)d_ws;
    size_t off = 0;
    auto carve = [&](size_t bytes) { char* p = w + off; off = (off + bytes + 255) & ~(size_t)255; return p; };
    float* xf     = (float*)carve((size_t)NROWS * ROIN * 4);   // 55.1 MB
    float* hA     = (float*)carve((size_t)NROWS * ROIN * 4);   // 55.1 MB
    float* hB     = (float*)carve((size_t)NROWS * ROIN * 4);   // 55.1 MB
    float* G      = (float*)carve(1048576u * 4);
    float* simb   = (float*)carve(1048576u * 4);
    float* t1     = (float*)carve((size_t)NBZ * ROIN * 4);
    float* pbuf   = (float*)carve((size_t)NBZ * ROIN * 4);
    float* sq     = (float*)carve(4096);
    int*   labels = (int*)carve(4096);
    int*   rowcnt = (int*)carve(4096);
    int*   rowoff = (int*)carve(4096);
    int*   iscal  = (int*)carve(256);
    float* fscal  = (float*)carve(256);
    float* posval = (float*)carve(524288u * 4);
    float* negval = (float*)carve(524288u * 4);
    float* lpart  = (float*)carve(4096);
    float* mmpart = (float*)carve(4096);
    float* topv   = (float*)carve(32768);
    int*   topi   = (int*)carve(32768);
    float* bnpart = (float*)carve(116 * 232 * 4);
    float* bnmv   = (float*)carve(1024);
    // aliases into dead phases:
    float* gpart  = hA;   // Gram split-K partials (16.8 MB), before hA is first written
    float* ppart  = hB;   // proj1 split-K partials (3.8 MB), before hB is first written

    const int GX = NROWS / 64;   // 1856

    // 1. xf = x + leaky(pseudo @ fc_p_w + fc_p_b)
    gemm_nn<4><<<dim3(GX, 2, 1), 256, 0, stream>>>(pseudo, fc_p_w, fc_p_b, x, xf, NROWS, ROIN, ROIN, ROIN);

    // 2. proj head
    gemm_nn<0><<<dim3(16, 2, 8), 256, 0, stream>>>(xf, proj_w1, nullptr, nullptr, ppart, NBZ, ROIN, FLATN, FLATN / 8);
    proj_reduce<<<(NBZ * ROIN + 255) / 256, 256, 0, stream>>>(ppart, proj_b1, t1);
    gemm_nn<1><<<dim3(16, 2, 1), 256, 0, stream>>>(t1, proj_w2, proj_b2, nullptr, pbuf, NBZ, ROIN, ROIN, ROIN);
    rownorm<<<NBZ, 128, 0, stream>>>(pbuf);

    // 3. sim = (pn @ pn^T) / TEMP
    gemm_nt<1><<<dim3(16, 16, 1), 256, 0, stream>>>(pbuf, pbuf, simb, NBZ, NBZ, ROIN, ROIN, 1.f / 0.07f);

    // 4. contrastive loss (rank-paired pos/neg)
    labels_k<<<4, 256, 0, stream>>>(site, labels);
    rowcnt_k<<<4, 256, 0, stream>>>(labels, rowcnt);
    scan_k<<<1, 1024, 0, stream>>>(rowcnt, rowoff, iscal);
    pair_scatter<<<NBZ, 256, 0, stream>>>(labels, rowoff, iscal, simb, posval, negval);
    loss_part<<<1024, 256, 0, stream>>>(posval, negval, iscal, lpart);
    loss_final<<<1, 256, 0, stream>>>(lpart, iscal, dout + (size_t)NBZ * ROIN * 8);

    // 5. sim min/max, row sumsq, Gram, dist, top-k
    minmax_part<<<512, 256, 0, stream>>>(simb, mmpart);
    minmax_final<<<1, 512, 0, stream>>>(mmpart, fscal);
    row_sumsq<<<NBZ, 256, 0, stream>>>(xf, sq);
    gemm_nt<2><<<dim3(16, 16, 4), 256, 0, stream>>>(xf, xf, gpart, NBZ, NBZ, FLATN, FLATN / 4, 1.f);
    gram_reduce<<<4096, 256, 0, stream>>>(gpart, G);
    dist_k<<<4096, 256, 0, stream>>>(G, simb, sq, ages, genders, fscal);
    topk8<<<NBZ, 256, 0, stream>>>(G, topv, topi);

    // 6. GCN stack (adj@X as 8-sparse gathers)
    adj_gather<<<NBZ, 256, 0, stream>>>(topv, topi, xf, hA);
    gemm_nn<3><<<dim3(GX, 2, 1), 256, 0, stream>>>(hA, gcn_w1, gcn_b1, nullptr, hB, NROWS, ROIN, ROIN, ROIN);
    gemm_nn<1><<<dim3(GX, 2, 1), 256, 0, stream>>>(hB, gcn_w2, gcn_b2, nullptr, hA, NROWS, ROIN, ROIN, ROIN);
    bn_part<<<116, 128, 0, stream>>>(hA, bnpart);
    bn_final<<<1, 128, 0, stream>>>(bnpart, bnmv);
    bn_apply<<<13456, 256, 0, stream>>>(hA, bnmv, bn1_g, bn1_b, hB);

    adj_gather<<<NBZ, 256, 0, stream>>>(topv, topi, hB, xf);
    gemm_nn<3><<<dim3(GX, 2, 1), 256, 0, stream>>>(xf, gcn1_w, gcn1_b, nullptr, hA, NROWS, ROIN, ROIN, ROIN);
    bn_part<<<116, 128, 0, stream>>>(hA, bnpart);
    bn_final<<<1, 128, 0, stream>>>(bnpart, bnmv);
    bn_apply<<<13456, 256, 0, stream>>>(hA, bnmv, bn2_g, bn2_b, hB);

    adj_gather<<<NBZ, 256, 0, stream>>>(topv, topi, hB, xf);
    gemm_nn<3><<<dim3(GX, 1, 1), 256, 0, stream>>>(xf, gcn2_w1, gcn2_b1, nullptr, hA, NROWS, 64, ROIN, ROIN);
    gemm_nn<3><<<dim3(GX, 1, 1), 256, 0, stream>>>(hA, gcn2_w2, gcn2_b2, nullptr, hB, NROWS, 8, 64, 64);

    // 7. bn3 -> d_out
    bn3_k<<<116, 256, 0, stream>>>(hB, bn3_g, bn3_b, dout);
}

// Round 2
// 1349.826 us; speedup vs baseline: 1.5313x; 1.5313x over previous
//
#include <hip/hip_runtime.h>
#include <math.h>

#define ROIN 116
#define NBZ 1024
#define FLATN 13456
#define NROWS (NBZ*ROIN)   // 118784
#define ALPHA 0.1f
#define ACOEF 0.9f
#define BETAC 2
#define EPSBN 1e-5f

typedef __attribute__((ext_vector_type(8))) short bf16x8;
typedef __attribute__((ext_vector_type(4))) float f32x4;

__device__ __forceinline__ float leakyf(float v){ return v >= 0.f ? v : 0.2f*v; }

__device__ __forceinline__ short f2bf(float f){
    unsigned u = __builtin_bit_cast(unsigned, f);
    unsigned r = u + 0x7fffu + ((u >> 16) & 1u);   // RNE
    return (short)(r >> 16);
}

// ---------------------------------------------------------------------------
// Tiled fp32 GEMM, NN layout: C[M,N] = epi(A[M,K] @ B[K,N] (+ bias))
// EPI: 0 raw split-K partial, 1 bias, 2 relu(bias), 3 leaky(bias), 4 X+leaky(bias)
// ---------------------------------------------------------------------------
template<int EPI>
__global__ __launch_bounds__(256) void gemm_nn(
    const float* __restrict__ A, const float* __restrict__ B,
    const float* __restrict__ bias, const float* __restrict__ X,
    float* __restrict__ C, int M, int N, int K, int KS)
{
    __shared__ float As[16][65];
    __shared__ float Bs[16][65];
    const int tid = threadIdx.x;
    const int m0 = blockIdx.x * 64;
    const int n0 = blockIdx.y * 64;
    const int k0 = blockIdx.z * KS;
    const int k1 = min(K, k0 + KS);
    const int tm4 = (tid >> 4) * 4;
    const int tn4 = (tid & 15) * 4;
    const int mA  = tid >> 2;          // 0..63
    const int kbA = (tid & 3) * 4;     // 0,4,8,12
    const int nB  = tid & 63;          // 0..63
    const int kB0 = tid >> 6;          // 0..3
    float acc[4][4] = {};
    for (int kt = k0; kt < k1; kt += 16) {
        const float* Arow = A + (size_t)(m0 + mA) * K;
        int kg = kt + kbA;
        if (kg + 4 <= k1) {            // aligned: K*4 % 16 == 0 for all our K, kg % 4 == 0
            float4 v = *(const float4*)(Arow + kg);
            As[kbA + 0][mA] = v.x; As[kbA + 1][mA] = v.y;
            As[kbA + 2][mA] = v.z; As[kbA + 3][mA] = v.w;
        } else {
            #pragma unroll
            for (int kk = 0; kk < 4; ++kk)
                As[kbA + kk][mA] = (kg + kk < k1) ? Arow[kg + kk] : 0.f;
        }
        #pragma unroll
        for (int q = 0; q < 4; ++q) {
            int k = kB0 + q * 4;
            int kgb = kt + k;
            Bs[k][nB] = (kgb < k1 && (n0 + nB) < N) ? B[(size_t)kgb * N + n0 + nB] : 0.f;
        }
        __syncthreads();
        #pragma unroll
        for (int k = 0; k < 16; ++k) {
            float a[4], b[4];
            #pragma unroll
            for (int i = 0; i < 4; ++i) a[i] = As[k][tm4 + i];
            #pragma unroll
            for (int j = 0; j < 4; ++j) b[j] = Bs[k][tn4 + j];
            #pragma unroll
            for (int i = 0; i < 4; ++i)
                #pragma unroll
                for (int j = 0; j < 4; ++j)
                    acc[i][j] = fmaf(a[i], b[j], acc[i][j]);
        }
        __syncthreads();
    }
    float* Cb = (EPI == 0) ? (C + (size_t)blockIdx.z * M * N) : C;
    #pragma unroll
    for (int i = 0; i < 4; ++i) {
        int m = m0 + tm4 + i;
        #pragma unroll
        for (int j = 0; j < 4; ++j) {
            int n = n0 + tn4 + j;
            if (n < N) {
                size_t idx = (size_t)m * N + n;
                float v = acc[i][j];
                if (EPI == 0) { Cb[idx] = v; }
                else {
                    v += bias[n];
                    if (EPI == 2) v = fmaxf(v, 0.f);
                    else if (EPI == 3) v = leakyf(v);
                    else if (EPI == 4) v = X[idx] + leakyf(v);
                    Cb[idx] = v;
                }
            }
        }
    }
}

// ---------------------------------------------------------------------------
// fp32 GEMM NT (only used for sim = pn @ pn^T, K=116), symmetric mirror write
// ---------------------------------------------------------------------------
__global__ __launch_bounds__(256) void gemm_nt_sym(
    const float* __restrict__ A, float* __restrict__ C, int M, int K, float scale)
{
    if ((int)blockIdx.y < (int)blockIdx.x) return;
    __shared__ float As[16][65];
    __shared__ float Bs[16][65];
    const int tid = threadIdx.x;
    const int m0 = blockIdx.x * 64;
    const int n0 = blockIdx.y * 64;
    const int tm4 = (tid >> 4) * 4;
    const int tn4 = (tid & 15) * 4;
    const int rA  = tid >> 2;
    const int kbA = (tid & 3) * 4;
    float acc[4][4] = {};
    for (int kt = 0; kt < K; kt += 16) {
        int kg = kt + kbA;
        if (kg + 4 <= K) {
            float4 va = *(const float4*)(A + (size_t)(m0 + rA) * K + kg);
            As[kbA + 0][rA] = va.x; As[kbA + 1][rA] = va.y;
            As[kbA + 2][rA] = va.z; As[kbA + 3][rA] = va.w;
            float4 vb = *(const float4*)(A + (size_t)(n0 + rA) * K + kg);
            Bs[kbA + 0][rA] = vb.x; Bs[kbA + 1][rA] = vb.y;
            Bs[kbA + 2][rA] = vb.z; Bs[kbA + 3][rA] = vb.w;
        } else {
            #pragma unroll
            for (int kk = 0; kk < 4; ++kk) {
                int kgg = kg + kk;
                As[kbA + kk][rA] = (kgg < K) ? A[(size_t)(m0 + rA) * K + kgg] : 0.f;
                Bs[kbA + kk][rA] = (kgg < K) ? A[(size_t)(n0 + rA) * K + kgg] : 0.f;
            }
        }
        __syncthreads();
        #pragma unroll
        for (int k = 0; k < 16; ++k) {
            float a[4], b[4];
            #pragma unroll
            for (int i = 0; i < 4; ++i) a[i] = As[k][tm4 + i];
            #pragma unroll
            for (int j = 0; j < 4; ++j) b[j] = Bs[k][tn4 + j];
            #pragma unroll
            for (int i = 0; i < 4; ++i)
                #pragma unroll
                for (int j = 0; j < 4; ++j)
                    acc[i][j] = fmaf(a[i], b[j], acc[i][j]);
        }
        __syncthreads();
    }
    #pragma unroll
    for (int i = 0; i < 4; ++i) {
        int m = m0 + tm4 + i;
        #pragma unroll
        for (int j = 0; j < 4; ++j) {
            int n = n0 + tn4 + j;
            float v = acc[i][j] * scale;
            C[(size_t)m * M + n] = v;
            C[(size_t)n * M + m] = v;
        }
    }
}

// fp32 -> bf16 (RNE), 8 elems/thread
__global__ void cvt_bf16(const float* __restrict__ X, short* __restrict__ Y)
{
    size_t i = ((size_t)blockIdx.x * 256 + threadIdx.x) * 8;
    if (i >= (size_t)NBZ * FLATN) return;
    float4 a = *(const float4*)(X + i);
    float4 b = *(const float4*)(X + i + 4);
    bf16x8 o;
    o[0] = f2bf(a.x); o[1] = f2bf(a.y); o[2] = f2bf(a.z); o[3] = f2bf(a.w);
    o[4] = f2bf(b.x); o[5] = f2bf(b.y); o[6] = f2bf(b.z); o[7] = f2bf(b.w);
    *(bf16x8*)(Y + i) = o;
}

// ---------------------------------------------------------------------------
// Gram via bf16 MFMA: gpart[z] += Xh[64*bx..][k0:k1] @ Xh[64*by..][k0:k1]^T
// 4 waves/block, each wave a 32x32 tile via 4x mfma_f32_16x16x32_bf16.
// Direct global->VGPR fragment loads (16B/lane, rows of Xh).
// ---------------------------------------------------------------------------
__global__ __launch_bounds__(256) void gram_mfma(
    const short* __restrict__ Xh, float* __restrict__ gpart, int K, int KS)
{
    if ((int)blockIdx.y < (int)blockIdx.x) return;
    const int k0 = blockIdx.z * KS;
    const int k1 = min(K, k0 + KS);
    const int wave = threadIdx.x >> 6;
    const int lane = threadIdx.x & 63;
    const int r0 = blockIdx.x * 64 + (wave >> 1) * 32;
    const int c0 = blockIdx.y * 64 + (wave & 1) * 32;
    const int row  = lane & 15;
    const int koff = (lane >> 4) * 8;
    const short* Ap0 = Xh + (size_t)(r0 + row)      * K;
    const short* Ap1 = Xh + (size_t)(r0 + 16 + row) * K;
    const short* Bp0 = Xh + (size_t)(c0 + row)      * K;
    const short* Bp1 = Xh + (size_t)(c0 + 16 + row) * K;
    f32x4 acc00 = {0.f,0.f,0.f,0.f}, acc01 = {0.f,0.f,0.f,0.f};
    f32x4 acc10 = {0.f,0.f,0.f,0.f}, acc11 = {0.f,0.f,0.f,0.f};
    const bf16x8 zf = {0,0,0,0,0,0,0,0};
    for (int k = k0; k < k1; k += 32) {
        int kk = k + koff;
        bool ok = (kk + 8 <= k1);
        bf16x8 a0 = ok ? *(const bf16x8*)(Ap0 + kk) : zf;
        bf16x8 a1 = ok ? *(const bf16x8*)(Ap1 + kk) : zf;
        bf16x8 b0 = ok ? *(const bf16x8*)(Bp0 + kk) : zf;
        bf16x8 b1 = ok ? *(const bf16x8*)(Bp1 + kk) : zf;
        acc00 = __builtin_amdgcn_mfma_f32_16x16x32_bf16(a0, b0, acc00, 0, 0, 0);
        acc01 = __builtin_amdgcn_mfma_f32_16x16x32_bf16(a0, b1, acc01, 0, 0, 0);
        acc10 = __builtin_amdgcn_mfma_f32_16x16x32_bf16(a1, b0, acc10, 0, 0, 0);
        acc11 = __builtin_amdgcn_mfma_f32_16x16x32_bf16(a1, b1, acc11, 0, 0, 0);
    }
    // C/D layout: col = lane&15, row = (lane>>4)*4 + reg  [measured m89]
    float* Cb = gpart + (size_t)blockIdx.z * 1024 * 1024;
    const int crow = (lane >> 4) * 4;
    const int ccol = lane & 15;
    #pragma unroll
    for (int j = 0; j < 4; ++j) {
        Cb[(size_t)(r0 + crow + j)      * 1024 + (c0 + ccol)]      = acc00[j];
        Cb[(size_t)(r0 + crow + j)      * 1024 + (c0 + 16 + ccol)] = acc01[j];
        Cb[(size_t)(r0 + 16 + crow + j) * 1024 + (c0 + ccol)]      = acc10[j];
        Cb[(size_t)(r0 + 16 + crow + j) * 1024 + (c0 + 16 + ccol)] = acc11[j];
    }
}

// split-K(8) reduce + symmetric mirror for Gram
__global__ void gram_reduce8(const float* __restrict__ gpart, float* __restrict__ G)
{
    size_t e = (size_t)blockIdx.x * 256 + threadIdx.x;
    int i = (int)(e >> 10), j = (int)(e & 1023);
    if (j < i) return;
    float s = 0.f;
    #pragma unroll
    for (int z = 0; z < 8; ++z) s += gpart[(size_t)z * 1048576 + e];
    G[e] = s;
    G[((size_t)j << 10) + i] = s;
}

// split-K reduce for proj1 (+bias +relu)
__global__ void proj_reduce(const float* __restrict__ ppart,
                            const float* __restrict__ bias, float* __restrict__ t1)
{
    int e = blockIdx.x * 256 + threadIdx.x;
    if (e >= NBZ * ROIN) return;
    int n = e % ROIN;
    float s = 0.f;
    #pragma unroll
    for (int z = 0; z < 8; ++z) s += ppart[(size_t)z * NBZ * ROIN + e];
    t1[e] = fmaxf(s + bias[n], 0.f);
}

// p[1024,116] -> row L2-normalize in place
__global__ void rownorm(float* __restrict__ p)
{
    int row = blockIdx.x, t = threadIdx.x;   // 128 threads
    __shared__ float red[128];
    float x = 0.f, v = 0.f;
    if (t < ROIN) { x = p[row * ROIN + t]; v = x * x; }
    red[t] = v; __syncthreads();
    for (int off = 64; off > 0; off >>= 1) { if (t < off) red[t] += red[t + off]; __syncthreads(); }
    float inv = 1.f / sqrtf(red[0]);
    if (t < ROIN) p[row * ROIN + t] = x * inv;
}

// sq[i] = sum_k xf[i,k]^2
__global__ void row_sumsq(const float* __restrict__ xf, float* __restrict__ sq)
{
    int row = blockIdx.x, t = threadIdx.x;
    const float4* fr = (const float4*)(xf + (size_t)row * FLATN);
    float s = 0.f;
    for (int c = t; c < FLATN / 4; c += 256) {
        float4 v = fr[c];
        s += v.x * v.x + v.y * v.y + v.z * v.z + v.w * v.w;
    }
    __shared__ float red[256];
    red[t] = s; __syncthreads();
    for (int off = 128; off > 0; off >>= 1) { if (t < off) red[t] += red[t + off]; __syncthreads(); }
    if (t == 0) sq[row] = red[0];
}

// global min/max of sim
__global__ void minmax_part(const float* __restrict__ sim, float* __restrict__ mm)
{
    int t = threadIdx.x, b = blockIdx.x;   // 512 x 256
    float mn = 1e30f, mx = -1e30f;
    for (size_t i = (size_t)b * 256 + t; i < 1048576u; i += 512u * 256u) {
        float v = sim[i]; mn = fminf(mn, v); mx = fmaxf(mx, v);
    }
    __shared__ float smn[256], smx[256];
    smn[t] = mn; smx[t] = mx; __syncthreads();
    for (int off = 128; off > 0; off >>= 1) {
        if (t < off) { smn[t] = fminf(smn[t], smn[t + off]); smx[t] = fmaxf(smx[t], smx[t + off]); }
        __syncthreads();
    }
    if (t == 0) { mm[b] = smn[0]; mm[512 + b] = smx[0]; }
}
__global__ void minmax_final(const float* __restrict__ mm, float* __restrict__ fscal)
{
    int t = threadIdx.x;   // 512 threads
    __shared__ float smn[512], smx[512];
    smn[t] = mm[t]; smx[t] = mm[512 + t]; __syncthreads();
    for (int off = 256; off > 0; off >>= 1) {
        if (t < off) { smn[t] = fminf(smn[t], smn[t + off]); smx[t] = fmaxf(smx[t], smx[t + off]); }
        __syncthreads();
    }
    if (t == 0) { fscal[0] = smn[0]; fscal[1] = smx[0]; }
}

// labels[i] = argmax(site[i,0..3]) (first max)
__global__ void labels_k(const int* __restrict__ site, int* __restrict__ labels)
{
    int i = blockIdx.x * 256 + threadIdx.x;
    if (i >= NBZ) return;
    int best = site[4 * i], bi = 0;
    #pragma unroll
    for (int k = 1; k < 4; ++k) { int v = site[4 * i + k]; if (v > best) { best = v; bi = k; } }
    labels[i] = bi;
}

__global__ void rowcnt_k(const int* __restrict__ labels, int* __restrict__ rowcnt)
{
    int i = blockIdx.x * 256 + threadIdx.x;
    if (i >= NBZ) return;
    int li = labels[i], c = 0;
    for (int j = 0; j < NBZ; ++j) c += (labels[j] == li);
    rowcnt[i] = c;
}

// exclusive scan of per-row positive counts; iscal[0]=npos, iscal[1]=m
__global__ __launch_bounds__(1024) void scan_k(const int* __restrict__ rowcnt,
                                               int* __restrict__ rowoff, int* __restrict__ iscal)
{
    __shared__ int s[1024];
    int t = threadIdx.x;
    int c = rowcnt[t];
    s[t] = c; __syncthreads();
    for (int off = 1; off < 1024; off <<= 1) {
        int v = (t >= off) ? s[t - off] : 0;
        __syncthreads();
        s[t] += v;
        __syncthreads();
    }
    rowoff[t] = s[t] - c;
    if (t == 1023) {
        int npos = s[1023];
        int nneg = 1024 * 1024 - npos;
        iscal[0] = npos;
        iscal[1] = (npos < nneg) ? npos : nneg;
    }
}

// scatter sim values to rank-paired pos/neg arrays (flat row-major rank order)
__global__ void pair_scatter(const int* __restrict__ labels, const int* __restrict__ rowoff,
                             const int* __restrict__ iscal, const float* __restrict__ sim,
                             float* __restrict__ posval, float* __restrict__ negval)
{
    int row = blockIdx.x, t = threadIdx.x;
    int m = iscal[1];
    int li = labels[row];
    int j0 = t * 4;
    int eq[4]; int c = 0;
    #pragma unroll
    for (int kk = 0; kk < 4; ++kk) { eq[kk] = (labels[j0 + kk] == li); c += eq[kk]; }
    __shared__ int s[256];
    s[t] = c; __syncthreads();
    for (int off = 1; off < 256; off <<= 1) {
        int v = (t >= off) ? s[t - off] : 0;
        __syncthreads();
        s[t] += v;
        __syncthreads();
    }
    int r = rowoff[row] + s[t] - c;   // positives strictly before flat index
    size_t base = (size_t)row * 1024;
    #pragma unroll
    for (int kk = 0; kk < 4; ++kk) {
        size_t f = base + j0 + kk;
        float v = sim[f];
        if (eq[kk]) { if (r < m) posval[r] = v; r++; }
        else { long nr = (long)f - r; if (nr < m) negval[nr] = v; }
    }
}

__global__ void loss_part(const float* __restrict__ posval, const float* __restrict__ negval,
                          const int* __restrict__ iscal, float* __restrict__ lp)
{
    int m = iscal[1];
    int t = threadIdx.x, b = blockIdx.x;   // 1024 x 256
    float s = 0.f;
    for (int k = b * 256 + t; k < m; k += 1024 * 256) {
        float d = negval[k] - posval[k];
        s += fmaxf(d, 0.f) + log1pf(expf(-fabsf(d)));   // stable softplus
    }
    __shared__ float red[256];
    red[t] = s; __syncthreads();
    for (int off = 128; off > 0; off >>= 1) { if (t < off) red[t] += red[t + off]; __syncthreads(); }
    if (t == 0) lp[b] = red[0];
}

__global__ void loss_final(const float* __restrict__ lp, const int* __restrict__ iscal,
                           float* __restrict__ outp)
{
    int t = threadIdx.x;   // 256
    double s = 0.0;
    for (int k = t; k < 1024; k += 256) s += (double)lp[k];
    __shared__ double red[256];
    red[t] = s; __syncthreads();
    for (int off = 128; off > 0; off >>= 1) { if (t < off) red[t] += red[t + off]; __syncthreads(); }
    if (t == 0) {
        int m = iscal[1]; if (m < 1) m = 1;
        outp[0] = (float)(red[0] / (double)m);
    }
}

// dist (in place over G): total * (cond ? 0.9 : 0.1)
__global__ void dist_k(float* __restrict__ G, const float* __restrict__ sim,
                       const float* __restrict__ sq, const int* __restrict__ ages,
                       const int* __restrict__ genders, const float* __restrict__ fscal)
{
    size_t e = (size_t)blockIdx.x * 256 + threadIdx.x;
    int i = (int)(e >> 10), j = (int)(e & 1023);
    float smin = fscal[0], smax = fscal[1];
    float sn = (sim[e] - smin) / (smax - smin);
    float d2 = fmaxf(sq[i] + sq[j] - 2.f * G[e], 0.f);
    float fs = expf(-ALPHA * sqrtf(d2));
    float total = fs * (1.f - sn) + sn;
    int da = ages[i] - ages[j]; if (da < 0) da = -da;
    bool cond = (da <= BETAC) && (genders[i] == genders[j]);
    G[e] = total * (cond ? ACOEF : 1.f - ACOEF);
}

// row-wise top-8 (ties -> lower index, matching lax.top_k)
__global__ void topk8(const float* __restrict__ dist, float* __restrict__ topv, int* __restrict__ topi)
{
    int row = blockIdx.x, t = threadIdx.x;
    __shared__ float sv[1024];
    __shared__ float rv[256];
    __shared__ int   ri[256];
    for (int j = t; j < 1024; j += 256) sv[j] = dist[(size_t)row * 1024 + j];
    __syncthreads();
    for (int k = 0; k < 8; ++k) {
        float bv = -1e30f; int bi = 1 << 20;
        for (int j = t; j < 1024; j += 256) {
            float x = sv[j];
            if (x > bv || (x == bv && j < bi)) { bv = x; bi = j; }
        }
        rv[t] = bv; ri[t] = bi;
        __syncthreads();
        for (int s = 128; s > 0; s >>= 1) {
            if (t < s) {
                float ov = rv[t + s]; int oi = ri[t + s];
                if (ov > rv[t] || (ov == rv[t] && oi < ri[t])) { rv[t] = ov; ri[t] = oi; }
            }
            __syncthreads();
        }
        if (t == 0) { topv[row * 8 + k] = rv[0]; topi[row * 8 + k] = ri[0]; sv[ri[0]] = -1e30f; }
        __syncthreads();
    }
}

// out[row,:] = sum_k vals[row,k] * feat[idx[row,k], :]   (adj @ feat, 8-sparse rows)
__global__ void adj_gather(const float* __restrict__ vals, const int* __restrict__ idxs,
                           const float* __restrict__ feat, float* __restrict__ out)
{
    int row = blockIdx.x, t = threadIdx.x;
    __shared__ float v[8]; __shared__ int ix[8];
    if (t < 8) { v[t] = vals[row * 8 + t]; ix[t] = idxs[row * 8 + t]; }
    __syncthreads();
    float vv[8]; const float4* fp[8];
    #pragma unroll
    for (int k = 0; k < 8; ++k) { vv[k] = v[k]; fp[k] = (const float4*)(feat + (size_t)ix[k] * FLATN); }
    float4* op = (float4*)(out + (size_t)row * FLATN);
    for (int c = t; c < FLATN / 4; c += 256) {
        float4 acc = {0.f, 0.f, 0.f, 0.f};
        #pragma unroll
        for (int k = 0; k < 8; ++k) {
            float4 x = fp[k][c];
            acc.x = fmaf(vv[k], x.x, acc.x);
            acc.y = fmaf(vv[k], x.y, acc.y);
            acc.z = fmaf(vv[k], x.z, acc.z);
            acc.w = fmaf(vv[k], x.w, acc.w);
        }
        op[c] = acc;
    }
}

// BatchNorm over [118784, 116], per-column, two-stage deterministic
// 464 blocks x 256 rows each
__global__ void bn_part(const float* __restrict__ X, float* __restrict__ part)
{
    int b = blockIdx.x, t = threadIdx.x;   // 464 blocks x 128 threads
    if (t >= ROIN) return;
    float s = 0.f, s2 = 0.f;
    size_t base = (size_t)b * 256 * ROIN;
    for (int r = 0; r < 256; ++r) {
        float v = X[base + (size_t)r * ROIN + t];
        s += v; s2 += v * v;
    }
    part[b * 232 + t] = s;
    part[b * 232 + 116 + t] = s2;
}
__global__ void bn_final(const float* __restrict__ part, float* __restrict__ mv)
{
    int t = threadIdx.x;
    if (t >= ROIN) return;
    float s = 0.f, s2 = 0.f;
    for (int b = 0; b < 464; ++b) { s += part[b * 232 + t]; s2 += part[b * 232 + 116 + t]; }
    float mean = s / (float)NROWS;
    float var = s2 / (float)NROWS - mean * mean;
    mv[t] = mean;
    mv[116 + t] = 1.f / sqrtf(var + EPSBN);
}
__global__ void bn_apply(const float* __restrict__ X, const float* __restrict__ mv,
                         const float* __restrict__ g, const float* __restrict__ bta,
                         float* __restrict__ Y)
{
    size_t e = ((size_t)blockIdx.x * 256 + threadIdx.x) * 4;
    if (e >= (size_t)NROWS * ROIN) return;
    int c = (int)(e % ROIN);   // 116 % 4 == 0 -> 4 elems stay in-row
    float4 v = *(const float4*)(X + e);
    float4 r;
    r.x = (v.x - mv[c])     * mv[116 + c]     * g[c]     + bta[c];
    r.y = (v.y - mv[c + 1]) * mv[116 + c + 1] * g[c + 1] + bta[c + 1];
    r.z = (v.z - mv[c + 2]) * mv[116 + c + 2] * g[c + 2] + bta[c + 2];
    r.w = (v.w - mv[c + 3]) * mv[116 + c + 3] * g[c + 3] + bta[c + 3];
    *(float4*)(Y + e) = r;
}

// bn3: per-ROI-channel stats over (N=1024, L=8); writes final output
__global__ void bn3_k(const float* __restrict__ X, const float* __restrict__ g,
                      const float* __restrict__ bta, float* __restrict__ out)
{
    int c = blockIdx.x, t = threadIdx.x;   // 116 x 256
    float s = 0.f, s2 = 0.f;
    for (int k = t; k < 8192; k += 256) {
        int n = k >> 3, l = k & 7;
        float v = X[(size_t)n * 928 + c * 8 + l];
        s += v; s2 += v * v;
    }
    __shared__ float rs[256], rs2[256];
    rs[t] = s; rs2[t] = s2; __syncthreads();
    for (int off = 128; off > 0; off >>= 1) {
        if (t < off) { rs[t] += rs[t + off]; rs2[t] += rs2[t + off]; }
        __syncthreads();
    }
    __shared__ float sm, sr;
    if (t == 0) {
        float mean = rs[0] / 8192.f;
        float var = rs2[0] / 8192.f - mean * mean;
        sm = mean; sr = 1.f / sqrtf(var + EPSBN);
    }
    __syncthreads();
    float mean = sm, rstd = sr, gg = g[c], bb = bta[c];
    for (int k = t; k < 8192; k += 256) {
        int n = k >> 3, l = k & 7;
        size_t idx = (size_t)n * 928 + c * 8 + l;
        out[idx] = (X[idx] - mean) * rstd * gg + bb;
    }
}

// ---------------------------------------------------------------------------
extern "C" void kernel_launch(void* const* d_in, const int* in_sizes, int n_in,
                              void* d_out, int out_size, void* d_ws, size_t ws_size,
                              hipStream_t stream)
{
    const float* x        = (const float*)d_in[0];
    const float* pseudo   = (const float*)d_in[1];
    const int*   ages     = (const int*)d_in[2];
    const int*   genders  = (const int*)d_in[3];
    const int*   site     = (const int*)d_in[4];
    const float* fc_p_w   = (const float*)d_in[5];
    const float* fc_p_b   = (const float*)d_in[6];
    const float* proj_w1  = (const float*)d_in[7];
    const float* proj_b1  = (const float*)d_in[8];
    const float* proj_w2  = (const float*)d_in[9];
    const float* proj_b2  = (const float*)d_in[10];
    const float* gcn_w1   = (const float*)d_in[11];
    const float* gcn_b1   = (const float*)d_in[12];
    const float* gcn_w2   = (const float*)d_in[13];
    const float* gcn_b2   = (const float*)d_in[14];
    const float* gcn1_w   = (const float*)d_in[15];
    const float* gcn1_b   = (const float*)d_in[16];
    const float* gcn2_w1  = (const float*)d_in[17];
    const float* gcn2_b1  = (const float*)d_in[18];
    const float* gcn2_w2  = (const float*)d_in[19];
    const float* gcn2_b2  = (const float*)d_in[20];
    const float* bn1_g    = (const float*)d_in[21];
    const float* bn1_b    = (const float*)d_in[22];
    const float* bn2_g    = (const float*)d_in[23];
    const float* bn2_b    = (const float*)d_in[24];
    const float* bn3_g    = (const float*)d_in[25];
    const float* bn3_b    = (const float*)d_in[26];
    float* dout = (float*)d_out;

    // workspace carve-up (256B aligned)
    char* w = (char*)d_ws;
    size_t off = 0;
    auto carve = [&](size_t bytes) { char* p = w + off; off = (off + bytes + 255) & ~(size_t)255; return p; };
    float* xf     = (float*)carve((size_t)NROWS * ROIN * 4);   // 55.1 MB
    float* hA     = (float*)carve((size_t)NROWS * ROIN * 4);   // 55.1 MB
    float* hB     = (float*)carve((size_t)NROWS * ROIN * 4);   // 55.1 MB
    float* G      = (float*)carve(1048576u * 4);
    float* simb   = (float*)carve(1048576u * 4);
    float* t1     = (float*)carve((size_t)NBZ * ROIN * 4);
    float* pbuf   = (float*)carve((size_t)NBZ * ROIN * 4);
    float* sq     = (float*)carve(4096);
    int*   labels = (int*)carve(4096);
    int*   rowcnt = (int*)carve(4096);
    int*   rowoff = (int*)carve(4096);
    int*   iscal  = (int*)carve(256);
    float* fscal  = (float*)carve(256);
    float* posval = (float*)carve(524288u * 4);
    float* negval = (float*)carve(524288u * 4);
    float* lpart  = (float*)carve(4096);
    float* mmpart = (float*)carve(4096);
    float* topv   = (float*)carve(32768);
    int*   topi   = (int*)carve(32768);
    float* bnpart = (float*)carve(464 * 232 * 4);
    float* bnmv   = (float*)carve(1024);
    // aliases into dead phases:
    float* gpart  = hA;            // Gram split-K partials (8 x 4 MB), dead before adj_gather->hA
    float* ppart  = hB;            // proj1 split-K partials (3.8 MB), dead after proj_reduce
    short* xfh    = (short*)hB;    // bf16 xf (27.5 MB), written after ppart dead, dead before hB GEMM dest

    const int GX = NROWS / 64;   // 1856
    const int GRAM_KS = 1688;    // 8 chunks, k0 multiple of 8 (16B-aligned bf16 loads)

    // 1. xf = x + leaky(pseudo @ fc_p_w + fc_p_b)
    gemm_nn<4><<<dim3(GX, 2, 1), 256, 0, stream>>>(pseudo, fc_p_w, fc_p_b, x, xf, NROWS, ROIN, ROIN, ROIN);

    // 2. proj head
    gemm_nn<0><<<dim3(16, 2, 8), 256, 0, stream>>>(xf, proj_w1, nullptr, nullptr, ppart, NBZ, ROIN, FLATN, FLATN / 8);
    proj_reduce<<<(NBZ * ROIN + 255) / 256, 256, 0, stream>>>(ppart, proj_b1, t1);
    gemm_nn<1><<<dim3(16, 2, 1), 256, 0, stream>>>(t1, proj_w2, proj_b2, nullptr, pbuf, NBZ, ROIN, ROIN, ROIN);
    rownorm<<<NBZ, 128, 0, stream>>>(pbuf);

    // 3. sim = (pn @ pn^T) / TEMP
    gemm_nt_sym<<<dim3(16, 16, 1), 256, 0, stream>>>(pbuf, simb, NBZ, ROIN, 1.f / 0.07f);

    // 4. contrastive loss (rank-paired pos/neg)
    labels_k<<<4, 256, 0, stream>>>(site, labels);
    rowcnt_k<<<4, 256, 0, stream>>>(labels, rowcnt);
    scan_k<<<1, 1024, 0, stream>>>(rowcnt, rowoff, iscal);
    pair_scatter<<<NBZ, 256, 0, stream>>>(labels, rowoff, iscal, simb, posval, negval);
    loss_part<<<1024, 256, 0, stream>>>(posval, negval, iscal, lpart);
    loss_final<<<1, 256, 0, stream>>>(lpart, iscal, dout + (size_t)NBZ * ROIN * 8);

    // 5. sim min/max, row sumsq, Gram (bf16 MFMA), dist, top-k
    minmax_part<<<512, 256, 0, stream>>>(simb, mmpart);
    minmax_final<<<1, 512, 0, stream>>>(mmpart, fscal);
    row_sumsq<<<NBZ, 256, 0, stream>>>(xf, sq);
    cvt_bf16<<<(NBZ * FLATN) / (256 * 8), 256, 0, stream>>>(xf, xfh);
    gram_mfma<<<dim3(16, 16, 8), 256, 0, stream>>>(xfh, gpart, FLATN, GRAM_KS);
    gram_reduce8<<<4096, 256, 0, stream>>>(gpart, G);
    dist_k<<<4096, 256, 0, stream>>>(G, simb, sq, ages, genders, fscal);
    topk8<<<NBZ, 256, 0, stream>>>(G, topv, topi);

    // 6. GCN stack (adj@X as 8-sparse gathers)
    adj_gather<<<NBZ, 256, 0, stream>>>(topv, topi, xf, hA);
    gemm_nn<3><<<dim3(GX, 2, 1), 256, 0, stream>>>(hA, gcn_w1, gcn_b1, nullptr, hB, NROWS, ROIN, ROIN, ROIN);
    gemm_nn<1><<<dim3(GX, 2, 1), 256, 0, stream>>>(hB, gcn_w2, gcn_b2, nullptr, hA, NROWS, ROIN, ROIN, ROIN);
    bn_part<<<464, 128, 0, stream>>>(hA, bnpart);
    bn_final<<<1, 128, 0, stream>>>(bnpart, bnmv);
    bn_apply<<<(int)(((size_t)NROWS * ROIN / 4 + 255) / 256), 256, 0, stream>>>(hA, bnmv, bn1_g, bn1_b, hB);

    adj_gather<<<NBZ, 256, 0, stream>>>(topv, topi, hB, xf);
    gemm_nn<3><<<dim3(GX, 2, 1), 256, 0, stream>>>(xf, gcn1_w, gcn1_b, nullptr, hA, NROWS, ROIN, ROIN, ROIN);
    bn_part<<<464, 128, 0, stream>>>(hA, bnpart);
    bn_final<<<1, 128, 0, stream>>>(bnpart, bnmv);
    bn_apply<<<(int)(((size_t)NROWS * ROIN / 4 + 255) / 256), 256, 0, stream>>>(hA, bnmv, bn2_g, bn2_b, hB);

    adj_gather<<<NBZ, 256, 0, stream>>>(topv, topi, hB, xf);
    gemm_nn<3><<<dim3(GX, 1, 1), 256, 0, stream>>>(xf, gcn2_w1, gcn2_b1, nullptr, hA, NROWS, 64, ROIN, ROIN);
    gemm_nn<3><<<dim3(GX, 1, 1), 256, 0, stream>>>(hA, gcn2_w2, gcn2_b2, nullptr, hB, NROWS, 8, 64, 64);

    // 7. bn3 -> d_out
    bn3_k<<<116, 256, 0, stream>>>(hB, bn3_g, bn3_b, dout);
}

// Round 3
// 1035.672 us; speedup vs baseline: 1.9958x; 1.3033x over previous
//
#include <hip/hip_runtime.h>
#include <math.h>

#define ROIN 116
#define NBZ 1024
#define FLATN 13456
#define NROWS (NBZ*ROIN)   // 118784
#define ALPHA 0.1f
#define ACOEF 0.9f
#define BETAC 2
#define EPSBN 1e-5f
#define PZ 31              // proj1 split-K chunks
#define PCH 448            // proj1 K-chunk (14 MFMA k-steps)
#define W1LD 14336         // padded K for transposed proj_w1

typedef __attribute__((ext_vector_type(8))) short bf16x8;
typedef __attribute__((ext_vector_type(4))) float f32x4;

__device__ __forceinline__ float leakyf(float v){ return v >= 0.f ? v : 0.2f*v; }

__device__ __forceinline__ short f2bf(float f){
    unsigned u = __builtin_bit_cast(unsigned, f);
    unsigned r = u + 0x7fffu + ((u >> 16) & 1u);   // RNE
    return (short)(r >> 16);
}
__device__ __forceinline__ float bf2f(short h){
    unsigned u = ((unsigned)(unsigned short)h) << 16;
    return __builtin_bit_cast(float, u);
}

// ---------------------------------------------------------------------------
// Weight pretranspose + bf16 hi/lo split.
// Small weights -> WT[128][128] (row n, col k), zero-padded.
// ---------------------------------------------------------------------------
__global__ void wt_conv(const float* __restrict__ W, short* __restrict__ hi,
                        short* __restrict__ lo, int K, int N)
{
    int idx = blockIdx.x * 256 + threadIdx.x;   // 16384
    int n = idx >> 7, k = idx & 127;
    float v = (n < N && k < K) ? W[(size_t)k * N + n] : 0.f;
    short h = f2bf(v);
    hi[idx] = h;
    lo[idx] = f2bf(v - bf2f(h));
}

// proj_w1 [13456,116] -> WT1[128][14336] hi/lo
__global__ void wt1_conv(const float* __restrict__ W, short* __restrict__ hi,
                         short* __restrict__ lo)
{
    int idx = blockIdx.x * 256 + threadIdx.x;   // 128*14336
    int n = idx / W1LD, k = idx - n * W1LD;
    float v = (n < ROIN && k < FLATN) ? W[(size_t)k * ROIN + n] : 0.f;
    short h = f2bf(v);
    hi[idx] = h;
    lo[idx] = f2bf(v - bf2f(h));
}

// ---------------------------------------------------------------------------
// bf16x2 MFMA GEMM, small K (<=128): C[M,N] = epi(A[M,K]fp32 @ W)
// W pre-split as WT_hi/WT_lo [128][128] (row n, col k).
// 4 waves/block, each wave = 16 output rows x N cols (NF 16-col frags).
// EPI: 1 bias, 3 leaky(bias), 4 X + leaky(bias)
// Lane maps (HW-verified by gram_mfma, m89): A/B-frag row=lane&15,
// k=(lane>>4)*8; C/D col=lane&15, row=(lane>>4)*4+reg.
// ---------------------------------------------------------------------------
template<int EPI, int NF>
__global__ __launch_bounds__(256) void mfma_gemm(
    const float* __restrict__ A, const short* __restrict__ wt_hi,
    const short* __restrict__ wt_lo, const float* __restrict__ bias,
    const float* __restrict__ X, float* __restrict__ C, int M, int N, int K)
{
    const int wave = threadIdx.x >> 6, lane = threadIdx.x & 63;
    const int m0 = blockIdx.x * 64 + wave * 16;
    const int rl = lane & 15, g = lane >> 4;
    const float* Arow = A + (size_t)(m0 + rl) * K;
    f32x4 acc[NF];
    #pragma unroll
    for (int nf = 0; nf < NF; ++nf) acc[nf] = (f32x4){0.f,0.f,0.f,0.f};
    const int ksteps = (K + 31) / 32;
    for (int s = 0; s < ksteps; ++s) {
        const int kk = s * 32 + g * 8;
        float av[8];
        if (kk + 8 <= K) {
            float4 p = *(const float4*)(Arow + kk);
            float4 q = *(const float4*)(Arow + kk + 4);
            av[0]=p.x; av[1]=p.y; av[2]=p.z; av[3]=p.w;
            av[4]=q.x; av[5]=q.y; av[6]=q.z; av[7]=q.w;
        } else if (kk + 4 <= K) {
            float4 p = *(const float4*)(Arow + kk);
            av[0]=p.x; av[1]=p.y; av[2]=p.z; av[3]=p.w;
            av[4]=0.f; av[5]=0.f; av[6]=0.f; av[7]=0.f;
        } else {
            #pragma unroll
            for (int j = 0; j < 8; ++j) av[j] = 0.f;
        }
        bf16x8 ah, al;
        #pragma unroll
        for (int j = 0; j < 8; ++j) {
            short h = f2bf(av[j]); ah[j] = h;
            al[j] = f2bf(av[j] - bf2f(h));
        }
        #pragma unroll
        for (int nf = 0; nf < NF; ++nf) {
            size_t boff = (size_t)(nf * 16 + rl) * 128 + kk;
            bf16x8 bh = *(const bf16x8*)(wt_hi + boff);
            bf16x8 bl = *(const bf16x8*)(wt_lo + boff);
            acc[nf] = __builtin_amdgcn_mfma_f32_16x16x32_bf16(ah, bh, acc[nf], 0, 0, 0);
            acc[nf] = __builtin_amdgcn_mfma_f32_16x16x32_bf16(al, bh, acc[nf], 0, 0, 0);
            acc[nf] = __builtin_amdgcn_mfma_f32_16x16x32_bf16(ah, bl, acc[nf], 0, 0, 0);
        }
    }
    const int cm = g * 4;
    #pragma unroll
    for (int nf = 0; nf < NF; ++nf) {
        int n = nf * 16 + rl;
        if (n < N) {
            float bb = bias[n];
            #pragma unroll
            for (int j = 0; j < 4; ++j) {
                int m = m0 + cm + j;
                size_t idx = (size_t)m * N + n;
                float v = acc[nf][j] + bb;
                if (EPI == 3) v = leakyf(v);
                else if (EPI == 4) v = X[idx] + leakyf(v);
                C[idx] = v;
            }
        }
    }
}

// ---------------------------------------------------------------------------
// proj1 via bf16x2 MFMA, split-K: part[z] = xf[:, z*448:(z+1)*448] @ W1-chunk
// grid (16, 1, PZ). Output partials [PZ][1024][116].
// ---------------------------------------------------------------------------
__global__ __launch_bounds__(256) void mfma_proj1(
    const float* __restrict__ A, const short* __restrict__ wt_hi,
    const short* __restrict__ wt_lo, float* __restrict__ part)
{
    const int wave = threadIdx.x >> 6, lane = threadIdx.x & 63;
    const int m0 = blockIdx.x * 64 + wave * 16;
    const int rl = lane & 15, g = lane >> 4;
    const int kbase = blockIdx.z * PCH;
    const float* Arow = A + (size_t)(m0 + rl) * FLATN;
    f32x4 acc[8];
    #pragma unroll
    for (int nf = 0; nf < 8; ++nf) acc[nf] = (f32x4){0.f,0.f,0.f,0.f};
    for (int s = 0; s < 14; ++s) {
        const int kk = kbase + s * 32 + g * 8;
        float av[8];
        if (kk + 8 <= FLATN) {     // FLATN % 8 == 0 -> full or empty
            float4 p = *(const float4*)(Arow + kk);
            float4 q = *(const float4*)(Arow + kk + 4);
            av[0]=p.x; av[1]=p.y; av[2]=p.z; av[3]=p.w;
            av[4]=q.x; av[5]=q.y; av[6]=q.z; av[7]=q.w;
        } else {
            #pragma unroll
            for (int j = 0; j < 8; ++j) av[j] = 0.f;
        }
        bf16x8 ah, al;
        #pragma unroll
        for (int j = 0; j < 8; ++j) {
            short h = f2bf(av[j]); ah[j] = h;
            al[j] = f2bf(av[j] - bf2f(h));
        }
        #pragma unroll
        for (int nf = 0; nf < 8; ++nf) {
            size_t boff = (size_t)(nf * 16 + rl) * W1LD + kk;
            bf16x8 bh = *(const bf16x8*)(wt_hi + boff);
            bf16x8 bl = *(const bf16x8*)(wt_lo + boff);
            acc[nf] = __builtin_amdgcn_mfma_f32_16x16x32_bf16(ah, bh, acc[nf], 0, 0, 0);
            acc[nf] = __builtin_amdgcn_mfma_f32_16x16x32_bf16(al, bh, acc[nf], 0, 0, 0);
            acc[nf] = __builtin_amdgcn_mfma_f32_16x16x32_bf16(ah, bl, acc[nf], 0, 0, 0);
        }
    }
    float* Cb = part + (size_t)blockIdx.z * NBZ * ROIN;
    const int cm = g * 4;
    #pragma unroll
    for (int nf = 0; nf < 8; ++nf) {
        int n = nf * 16 + rl;
        if (n < ROIN) {
            #pragma unroll
            for (int j = 0; j < 4; ++j)
                Cb[(size_t)(m0 + cm + j) * ROIN + n] = acc[nf][j];
        }
    }
}

// split-K reduce for proj1 (+bias +relu)
__global__ void proj_reduce(const float* __restrict__ ppart,
                            const float* __restrict__ bias, float* __restrict__ t1)
{
    int e = blockIdx.x * 256 + threadIdx.x;
    if (e >= NBZ * ROIN) return;
    int n = e % ROIN;
    float s = 0.f;
    for (int z = 0; z < PZ; ++z) s += ppart[(size_t)z * NBZ * ROIN + e];
    t1[e] = fmaxf(s + bias[n], 0.f);
}

// ---------------------------------------------------------------------------
// fp32 GEMM NT (sim = pn @ pn^T, K=116), symmetric mirror write
// ---------------------------------------------------------------------------
__global__ __launch_bounds__(256) void gemm_nt_sym(
    const float* __restrict__ A, float* __restrict__ C, int M, int K, float scale)
{
    if ((int)blockIdx.y < (int)blockIdx.x) return;
    __shared__ float As[16][65];
    __shared__ float Bs[16][65];
    const int tid = threadIdx.x;
    const int m0 = blockIdx.x * 64;
    const int n0 = blockIdx.y * 64;
    const int tm4 = (tid >> 4) * 4;
    const int tn4 = (tid & 15) * 4;
    const int rA  = tid >> 2;
    const int kbA = (tid & 3) * 4;
    float acc[4][4] = {};
    for (int kt = 0; kt < K; kt += 16) {
        int kg = kt + kbA;
        if (kg + 4 <= K) {
            float4 va = *(const float4*)(A + (size_t)(m0 + rA) * K + kg);
            As[kbA + 0][rA] = va.x; As[kbA + 1][rA] = va.y;
            As[kbA + 2][rA] = va.z; As[kbA + 3][rA] = va.w;
            float4 vb = *(const float4*)(A + (size_t)(n0 + rA) * K + kg);
            Bs[kbA + 0][rA] = vb.x; Bs[kbA + 1][rA] = vb.y;
            Bs[kbA + 2][rA] = vb.z; Bs[kbA + 3][rA] = vb.w;
        } else {
            #pragma unroll
            for (int kk = 0; kk < 4; ++kk) {
                int kgg = kg + kk;
                As[kbA + kk][rA] = (kgg < K) ? A[(size_t)(m0 + rA) * K + kgg] : 0.f;
                Bs[kbA + kk][rA] = (kgg < K) ? A[(size_t)(n0 + rA) * K + kgg] : 0.f;
            }
        }
        __syncthreads();
        #pragma unroll
        for (int k = 0; k < 16; ++k) {
            float a[4], b[4];
            #pragma unroll
            for (int i = 0; i < 4; ++i) a[i] = As[k][tm4 + i];
            #pragma unroll
            for (int j = 0; j < 4; ++j) b[j] = Bs[k][tn4 + j];
            #pragma unroll
            for (int i = 0; i < 4; ++i)
                #pragma unroll
                for (int j = 0; j < 4; ++j)
                    acc[i][j] = fmaf(a[i], b[j], acc[i][j]);
        }
        __syncthreads();
    }
    #pragma unroll
    for (int i = 0; i < 4; ++i) {
        int m = m0 + tm4 + i;
        #pragma unroll
        for (int j = 0; j < 4; ++j) {
            int n = n0 + tn4 + j;
            float v = acc[i][j] * scale;
            C[(size_t)m * M + n] = v;
            C[(size_t)n * M + m] = v;
        }
    }
}

// fp32 -> bf16 (RNE), 8 elems/thread
__global__ void cvt_bf16(const float* __restrict__ X, short* __restrict__ Y)
{
    size_t i = ((size_t)blockIdx.x * 256 + threadIdx.x) * 8;
    if (i >= (size_t)NBZ * FLATN) return;
    float4 a = *(const float4*)(X + i);
    float4 b = *(const float4*)(X + i + 4);
    bf16x8 o;
    o[0] = f2bf(a.x); o[1] = f2bf(a.y); o[2] = f2bf(a.z); o[3] = f2bf(a.w);
    o[4] = f2bf(b.x); o[5] = f2bf(b.y); o[6] = f2bf(b.z); o[7] = f2bf(b.w);
    *(bf16x8*)(Y + i) = o;
}

// ---------------------------------------------------------------------------
// Gram via bf16 MFMA (fsim path only; bf16 rounding invisible through exp(-d))
// ---------------------------------------------------------------------------
__global__ __launch_bounds__(256) void gram_mfma(
    const short* __restrict__ Xh, float* __restrict__ gpart, int K, int KS)
{
    if ((int)blockIdx.y < (int)blockIdx.x) return;
    const int k0 = blockIdx.z * KS;
    const int k1 = min(K, k0 + KS);
    const int wave = threadIdx.x >> 6;
    const int lane = threadIdx.x & 63;
    const int r0 = blockIdx.x * 64 + (wave >> 1) * 32;
    const int c0 = blockIdx.y * 64 + (wave & 1) * 32;
    const int row  = lane & 15;
    const int koff = (lane >> 4) * 8;
    const short* Ap0 = Xh + (size_t)(r0 + row)      * K;
    const short* Ap1 = Xh + (size_t)(r0 + 16 + row) * K;
    const short* Bp0 = Xh + (size_t)(c0 + row)      * K;
    const short* Bp1 = Xh + (size_t)(c0 + 16 + row) * K;
    f32x4 acc00 = {0.f,0.f,0.f,0.f}, acc01 = {0.f,0.f,0.f,0.f};
    f32x4 acc10 = {0.f,0.f,0.f,0.f}, acc11 = {0.f,0.f,0.f,0.f};
    const bf16x8 zf = {0,0,0,0,0,0,0,0};
    for (int k = k0; k < k1; k += 32) {
        int kk = k + koff;
        bool ok = (kk + 8 <= k1);
        bf16x8 a0 = ok ? *(const bf16x8*)(Ap0 + kk) : zf;
        bf16x8 a1 = ok ? *(const bf16x8*)(Ap1 + kk) : zf;
        bf16x8 b0 = ok ? *(const bf16x8*)(Bp0 + kk) : zf;
        bf16x8 b1 = ok ? *(const bf16x8*)(Bp1 + kk) : zf;
        acc00 = __builtin_amdgcn_mfma_f32_16x16x32_bf16(a0, b0, acc00, 0, 0, 0);
        acc01 = __builtin_amdgcn_mfma_f32_16x16x32_bf16(a0, b1, acc01, 0, 0, 0);
        acc10 = __builtin_amdgcn_mfma_f32_16x16x32_bf16(a1, b0, acc10, 0, 0, 0);
        acc11 = __builtin_amdgcn_mfma_f32_16x16x32_bf16(a1, b1, acc11, 0, 0, 0);
    }
    float* Cb = gpart + (size_t)blockIdx.z * 1024 * 1024;
    const int crow = (lane >> 4) * 4;
    const int ccol = lane & 15;
    #pragma unroll
    for (int j = 0; j < 4; ++j) {
        Cb[(size_t)(r0 + crow + j)      * 1024 + (c0 + ccol)]      = acc00[j];
        Cb[(size_t)(r0 + crow + j)      * 1024 + (c0 + 16 + ccol)] = acc01[j];
        Cb[(size_t)(r0 + 16 + crow + j) * 1024 + (c0 + ccol)]      = acc10[j];
        Cb[(size_t)(r0 + 16 + crow + j) * 1024 + (c0 + 16 + ccol)] = acc11[j];
    }
}

// split-K(8) reduce + symmetric mirror for Gram
__global__ void gram_reduce8(const float* __restrict__ gpart, float* __restrict__ G)
{
    size_t e = (size_t)blockIdx.x * 256 + threadIdx.x;
    int i = (int)(e >> 10), j = (int)(e & 1023);
    if (j < i) return;
    float s = 0.f;
    #pragma unroll
    for (int z = 0; z < 8; ++z) s += gpart[(size_t)z * 1048576 + e];
    G[e] = s;
    G[((size_t)j << 10) + i] = s;
}

// p[1024,116] -> row L2-normalize in place
__global__ void rownorm(float* __restrict__ p)
{
    int row = blockIdx.x, t = threadIdx.x;   // 128 threads
    __shared__ float red[128];
    float x = 0.f, v = 0.f;
    if (t < ROIN) { x = p[row * ROIN + t]; v = x * x; }
    red[t] = v; __syncthreads();
    for (int off = 64; off > 0; off >>= 1) { if (t < off) red[t] += red[t + off]; __syncthreads(); }
    float inv = 1.f / sqrtf(red[0]);
    if (t < ROIN) p[row * ROIN + t] = x * inv;
}

// sq[i] = sum_k xf[i,k]^2
__global__ void row_sumsq(const float* __restrict__ xf, float* __restrict__ sq)
{
    int row = blockIdx.x, t = threadIdx.x;
    const float4* fr = (const float4*)(xf + (size_t)row * FLATN);
    float s = 0.f;
    for (int c = t; c < FLATN / 4; c += 256) {
        float4 v = fr[c];
        s += v.x * v.x + v.y * v.y + v.z * v.z + v.w * v.w;
    }
    __shared__ float red[256];
    red[t] = s; __syncthreads();
    for (int off = 128; off > 0; off >>= 1) { if (t < off) red[t] += red[t + off]; __syncthreads(); }
    if (t == 0) sq[row] = red[0];
}

// global min/max of sim
__global__ void minmax_part(const float* __restrict__ sim, float* __restrict__ mm)
{
    int t = threadIdx.x, b = blockIdx.x;   // 512 x 256
    float mn = 1e30f, mx = -1e30f;
    for (size_t i = (size_t)b * 256 + t; i < 1048576u; i += 512u * 256u) {
        float v = sim[i]; mn = fminf(mn, v); mx = fmaxf(mx, v);
    }
    __shared__ float smn[256], smx[256];
    smn[t] = mn; smx[t] = mx; __syncthreads();
    for (int off = 128; off > 0; off >>= 1) {
        if (t < off) { smn[t] = fminf(smn[t], smn[t + off]); smx[t] = fmaxf(smx[t], smx[t + off]); }
        __syncthreads();
    }
    if (t == 0) { mm[b] = smn[0]; mm[512 + b] = smx[0]; }
}
__global__ void minmax_final(const float* __restrict__ mm, float* __restrict__ fscal)
{
    int t = threadIdx.x;   // 512 threads
    __shared__ float smn[512], smx[512];
    smn[t] = mm[t]; smx[t] = mm[512 + t]; __syncthreads();
    for (int off = 256; off > 0; off >>= 1) {
        if (t < off) { smn[t] = fminf(smn[t], smn[t + off]); smx[t] = fmaxf(smx[t], smx[t + off]); }
        __syncthreads();
    }
    if (t == 0) { fscal[0] = smn[0]; fscal[1] = smx[0]; }
}

// labels[i] = argmax(site[i,0..3]) (first max)
__global__ void labels_k(const int* __restrict__ site, int* __restrict__ labels)
{
    int i = blockIdx.x * 256 + threadIdx.x;
    if (i >= NBZ) return;
    int best = site[4 * i], bi = 0;
    #pragma unroll
    for (int k = 1; k < 4; ++k) { int v = site[4 * i + k]; if (v > best) { best = v; bi = k; } }
    labels[i] = bi;
}

__global__ void rowcnt_k(const int* __restrict__ labels, int* __restrict__ rowcnt)
{
    int i = blockIdx.x * 256 + threadIdx.x;
    if (i >= NBZ) return;
    int li = labels[i], c = 0;
    for (int j = 0; j < NBZ; ++j) c += (labels[j] == li);
    rowcnt[i] = c;
}

// exclusive scan of per-row positive counts; iscal[0]=npos, iscal[1]=m
__global__ __launch_bounds__(1024) void scan_k(const int* __restrict__ rowcnt,
                                               int* __restrict__ rowoff, int* __restrict__ iscal)
{
    __shared__ int s[1024];
    int t = threadIdx.x;
    int c = rowcnt[t];
    s[t] = c; __syncthreads();
    for (int off = 1; off < 1024; off <<= 1) {
        int v = (t >= off) ? s[t - off] : 0;
        __syncthreads();
        s[t] += v;
        __syncthreads();
    }
    rowoff[t] = s[t] - c;
    if (t == 1023) {
        int npos = s[1023];
        int nneg = 1024 * 1024 - npos;
        iscal[0] = npos;
        iscal[1] = (npos < nneg) ? npos : nneg;
    }
}

// scatter sim values to rank-paired pos/neg arrays (flat row-major rank order)
__global__ void pair_scatter(const int* __restrict__ labels, const int* __restrict__ rowoff,
                             const int* __restrict__ iscal, const float* __restrict__ sim,
                             float* __restrict__ posval, float* __restrict__ negval)
{
    int row = blockIdx.x, t = threadIdx.x;
    int m = iscal[1];
    int li = labels[row];
    int j0 = t * 4;
    int eq[4]; int c = 0;
    #pragma unroll
    for (int kk = 0; kk < 4; ++kk) { eq[kk] = (labels[j0 + kk] == li); c += eq[kk]; }
    __shared__ int s[256];
    s[t] = c; __syncthreads();
    for (int off = 1; off < 256; off <<= 1) {
        int v = (t >= off) ? s[t - off] : 0;
        __syncthreads();
        s[t] += v;
        __syncthreads();
    }
    int r = rowoff[row] + s[t] - c;
    size_t base = (size_t)row * 1024;
    #pragma unroll
    for (int kk = 0; kk < 4; ++kk) {
        size_t f = base + j0 + kk;
        float v = sim[f];
        if (eq[kk]) { if (r < m) posval[r] = v; r++; }
        else { long nr = (long)f - r; if (nr < m) negval[nr] = v; }
    }
}

__global__ void loss_part(const float* __restrict__ posval, const float* __restrict__ negval,
                          const int* __restrict__ iscal, float* __restrict__ lp)
{
    int m = iscal[1];
    int t = threadIdx.x, b = blockIdx.x;   // 1024 x 256
    float s = 0.f;
    for (int k = b * 256 + t; k < m; k += 1024 * 256) {
        float d = negval[k] - posval[k];
        s += fmaxf(d, 0.f) + log1pf(expf(-fabsf(d)));
    }
    __shared__ float red[256];
    red[t] = s; __syncthreads();
    for (int off = 128; off > 0; off >>= 1) { if (t < off) red[t] += red[t + off]; __syncthreads(); }
    if (t == 0) lp[b] = red[0];
}

__global__ void loss_final(const float* __restrict__ lp, const int* __restrict__ iscal,
                           float* __restrict__ outp)
{
    int t = threadIdx.x;   // 256
    double s = 0.0;
    for (int k = t; k < 1024; k += 256) s += (double)lp[k];
    __shared__ double red[256];
    red[t] = s; __syncthreads();
    for (int off = 128; off > 0; off >>= 1) { if (t < off) red[t] += red[t + off]; __syncthreads(); }
    if (t == 0) {
        int m = iscal[1]; if (m < 1) m = 1;
        outp[0] = (float)(red[0] / (double)m);
    }
}

// dist (in place over G): total * (cond ? 0.9 : 0.1)
__global__ void dist_k(float* __restrict__ G, const float* __restrict__ sim,
                       const float* __restrict__ sq, const int* __restrict__ ages,
                       const int* __restrict__ genders, const float* __restrict__ fscal)
{
    size_t e = (size_t)blockIdx.x * 256 + threadIdx.x;
    int i = (int)(e >> 10), j = (int)(e & 1023);
    float smin = fscal[0], smax = fscal[1];
    float sn = (sim[e] - smin) / (smax - smin);
    float d2 = fmaxf(sq[i] + sq[j] - 2.f * G[e], 0.f);
    float fs = expf(-ALPHA * sqrtf(d2));
    float total = fs * (1.f - sn) + sn;
    int da = ages[i] - ages[j]; if (da < 0) da = -da;
    bool cond = (da <= BETAC) && (genders[i] == genders[j]);
    G[e] = total * (cond ? ACOEF : 1.f - ACOEF);
}

// row-wise top-8 (ties -> lower index, matching lax.top_k)
__global__ void topk8(const float* __restrict__ dist, float* __restrict__ topv, int* __restrict__ topi)
{
    int row = blockIdx.x, t = threadIdx.x;
    __shared__ float sv[1024];
    __shared__ float rv[256];
    __shared__ int   ri[256];
    for (int j = t; j < 1024; j += 256) sv[j] = dist[(size_t)row * 1024 + j];
    __syncthreads();
    for (int k = 0; k < 8; ++k) {
        float bv = -1e30f; int bi = 1 << 20;
        for (int j = t; j < 1024; j += 256) {
            float x = sv[j];
            if (x > bv || (x == bv && j < bi)) { bv = x; bi = j; }
        }
        rv[t] = bv; ri[t] = bi;
        __syncthreads();
        for (int s = 128; s > 0; s >>= 1) {
            if (t < s) {
                float ov = rv[t + s]; int oi = ri[t + s];
                if (ov > rv[t] || (ov == rv[t] && oi < ri[t])) { rv[t] = ov; ri[t] = oi; }
            }
            __syncthreads();
        }
        if (t == 0) { topv[row * 8 + k] = rv[0]; topi[row * 8 + k] = ri[0]; sv[ri[0]] = -1e30f; }
        __syncthreads();
    }
}

// out[row,:] = sum_k vals[row,k] * feat[idx[row,k], :]
__global__ void adj_gather(const float* __restrict__ vals, const int* __restrict__ idxs,
                           const float* __restrict__ feat, float* __restrict__ out)
{
    int row = blockIdx.x, t = threadIdx.x;
    __shared__ float v[8]; __shared__ int ix[8];
    if (t < 8) { v[t] = vals[row * 8 + t]; ix[t] = idxs[row * 8 + t]; }
    __syncthreads();
    float vv[8]; const float4* fp[8];
    #pragma unroll
    for (int k = 0; k < 8; ++k) { vv[k] = v[k]; fp[k] = (const float4*)(feat + (size_t)ix[k] * FLATN); }
    float4* op = (float4*)(out + (size_t)row * FLATN);
    for (int c = t; c < FLATN / 4; c += 256) {
        float4 acc = {0.f, 0.f, 0.f, 0.f};
        #pragma unroll
        for (int k = 0; k < 8; ++k) {
            float4 x = fp[k][c];
            acc.x = fmaf(vv[k], x.x, acc.x);
            acc.y = fmaf(vv[k], x.y, acc.y);
            acc.z = fmaf(vv[k], x.z, acc.z);
            acc.w = fmaf(vv[k], x.w, acc.w);
        }
        op[c] = acc;
    }
}

// BatchNorm over [118784, 116]
__global__ void bn_part(const float* __restrict__ X, float* __restrict__ part)
{
    int b = blockIdx.x, t = threadIdx.x;   // 464 blocks x 128 threads
    if (t >= ROIN) return;
    float s = 0.f, s2 = 0.f;
    size_t base = (size_t)b * 256 * ROIN;
    for (int r = 0; r < 256; ++r) {
        float v = X[base + (size_t)r * ROIN + t];
        s += v; s2 += v * v;
    }
    part[b * 232 + t] = s;
    part[b * 232 + 116 + t] = s2;
}
__global__ void bn_final(const float* __restrict__ part, float* __restrict__ mv)
{
    int t = threadIdx.x;
    if (t >= ROIN) return;
    float s = 0.f, s2 = 0.f;
    for (int b = 0; b < 464; ++b) { s += part[b * 232 + t]; s2 += part[b * 232 + 116 + t]; }
    float mean = s / (float)NROWS;
    float var = s2 / (float)NROWS - mean * mean;
    mv[t] = mean;
    mv[116 + t] = 1.f / sqrtf(var + EPSBN);
}
__global__ void bn_apply(const float* __restrict__ X, const float* __restrict__ mv,
                         const float* __restrict__ g, const float* __restrict__ bta,
                         float* __restrict__ Y)
{
    size_t e = ((size_t)blockIdx.x * 256 + threadIdx.x) * 4;
    if (e >= (size_t)NROWS * ROIN) return;
    int c = (int)(e % ROIN);
    float4 v = *(const float4*)(X + e);
    float4 r;
    r.x = (v.x - mv[c])     * mv[116 + c]     * g[c]     + bta[c];
    r.y = (v.y - mv[c + 1]) * mv[116 + c + 1] * g[c + 1] + bta[c + 1];
    r.z = (v.z - mv[c + 2]) * mv[116 + c + 2] * g[c + 2] + bta[c + 2];
    r.w = (v.w - mv[c + 3]) * mv[116 + c + 3] * g[c + 3] + bta[c + 3];
    *(float4*)(Y + e) = r;
}

// bn3: per-ROI-channel stats over (N=1024, L=8); writes final output
__global__ void bn3_k(const float* __restrict__ X, const float* __restrict__ g,
                      const float* __restrict__ bta, float* __restrict__ out)
{
    int c = blockIdx.x, t = threadIdx.x;   // 116 x 256
    float s = 0.f, s2 = 0.f;
    for (int k = t; k < 8192; k += 256) {
        int n = k >> 3, l = k & 7;
        float v = X[(size_t)n * 928 + c * 8 + l];
        s += v; s2 += v * v;
    }
    __shared__ float rs[256], rs2[256];
    rs[t] = s; rs2[t] = s2; __syncthreads();
    for (int off = 128; off > 0; off >>= 1) {
        if (t < off) { rs[t] += rs[t + off]; rs2[t] += rs2[t + off]; }
        __syncthreads();
    }
    __shared__ float sm, sr;
    if (t == 0) {
        float mean = rs[0] / 8192.f;
        float var = rs2[0] / 8192.f - mean * mean;
        sm = mean; sr = 1.f / sqrtf(var + EPSBN);
    }
    __syncthreads();
    float mean = sm, rstd = sr, gg = g[c], bb = bta[c];
    for (int k = t; k < 8192; k += 256) {
        int n = k >> 3, l = k & 7;
        size_t idx = (size_t)n * 928 + c * 8 + l;
        out[idx] = (X[idx] - mean) * rstd * gg + bb;
    }
}

// ---------------------------------------------------------------------------
extern "C" void kernel_launch(void* const* d_in, const int* in_sizes, int n_in,
                              void* d_out, int out_size, void* d_ws, size_t ws_size,
                              hipStream_t stream)
{
    const float* x        = (const float*)d_in[0];
    const float* pseudo   = (const float*)d_in[1];
    const int*   ages     = (const int*)d_in[2];
    const int*   genders  = (const int*)d_in[3];
    const int*   site     = (const int*)d_in[4];
    const float* fc_p_w   = (const float*)d_in[5];
    const float* fc_p_b   = (const float*)d_in[6];
    const float* proj_w1  = (const float*)d_in[7];
    const float* proj_b1  = (const float*)d_in[8];
    const float* proj_w2  = (const float*)d_in[9];
    const float* proj_b2  = (const float*)d_in[10];
    const float* gcn_w1   = (const float*)d_in[11];
    const float* gcn_b1   = (const float*)d_in[12];
    const float* gcn_w2   = (const float*)d_in[13];
    const float* gcn_b2   = (const float*)d_in[14];
    const float* gcn1_w   = (const float*)d_in[15];
    const float* gcn1_b   = (const float*)d_in[16];
    const float* gcn2_w1  = (const float*)d_in[17];
    const float* gcn2_b1  = (const float*)d_in[18];
    const float* gcn2_w2  = (const float*)d_in[19];
    const float* gcn2_b2  = (const float*)d_in[20];
    const float* bn1_g    = (const float*)d_in[21];
    const float* bn1_b    = (const float*)d_in[22];
    const float* bn2_g    = (const float*)d_in[23];
    const float* bn2_b    = (const float*)d_in[24];
    const float* bn3_g    = (const float*)d_in[25];
    const float* bn3_b    = (const float*)d_in[26];
    float* dout = (float*)d_out;

    char* w = (char*)d_ws;
    size_t off = 0;
    auto carve = [&](size_t bytes) { char* p = w + off; off = (off + bytes + 255) & ~(size_t)255; return p; };
    float* xf     = (float*)carve((size_t)NROWS * ROIN * 4);   // 55.1 MB
    float* hA     = (float*)carve((size_t)NROWS * ROIN * 4);   // 55.1 MB
    float* hB     = (float*)carve((size_t)NROWS * ROIN * 4);   // 55.1 MB
    float* G      = (float*)carve(1048576u * 4);
    float* simb   = (float*)carve(1048576u * 4);
    float* t1     = (float*)carve((size_t)NBZ * ROIN * 4);
    float* pbuf   = (float*)carve((size_t)NBZ * ROIN * 4);
    float* sq     = (float*)carve(4096);
    int*   labels = (int*)carve(4096);
    int*   rowcnt = (int*)carve(4096);
    int*   rowoff = (int*)carve(4096);
    int*   iscal  = (int*)carve(256);
    float* fscal  = (float*)carve(256);
    float* posval = (float*)carve(524288u * 4);
    float* negval = (float*)carve(524288u * 4);
    float* lpart  = (float*)carve(4096);
    float* mmpart = (float*)carve(4096);
    float* topv   = (float*)carve(32768);
    int*   topi   = (int*)carve(32768);
    float* bnpart = (float*)carve(464 * 232 * 4);
    float* bnmv   = (float*)carve(1024);
    short* wt1_hi = (short*)carve((size_t)128 * W1LD * 2);   // 3.67 MB
    short* wt1_lo = (short*)carve((size_t)128 * W1LD * 2);   // 3.67 MB
    short* wts    = (short*)carve((size_t)7 * 2 * 16384 * 2); // 7 weights x (hi,lo) x 32KB
    // aliases into dead phases:
    float* gpart  = hA;            // Gram split-K partials (8 x 4 MB), dead before adj_gather->hA
    float* ppart  = hB;            // proj1 split-K partials (PZ x 475KB), dead after proj_reduce
    short* xfh    = (short*)hB;    // bf16 xf (27.5 MB), written after ppart dead, dead before gcn_w1->hB

    auto wt_hi = [&](int i) { return wts + (size_t)i * 2 * 16384; };
    auto wt_lo = [&](int i) { return wts + (size_t)i * 2 * 16384 + 16384; };

    const int GX = NROWS / 64;   // 1856
    const int GRAM_KS = 1688;

    // 0. weight pretranspose + hi/lo split
    wt1_conv<<<(128 * W1LD) / 256, 256, 0, stream>>>(proj_w1, wt1_hi, wt1_lo);
    wt_conv<<<64, 256, 0, stream>>>(fc_p_w,   wt_hi(0), wt_lo(0), 116, 116);
    wt_conv<<<64, 256, 0, stream>>>(proj_w2,  wt_hi(1), wt_lo(1), 116, 116);
    wt_conv<<<64, 256, 0, stream>>>(gcn_w1,   wt_hi(2), wt_lo(2), 116, 116);
    wt_conv<<<64, 256, 0, stream>>>(gcn_w2,   wt_hi(3), wt_lo(3), 116, 116);
    wt_conv<<<64, 256, 0, stream>>>(gcn1_w,   wt_hi(4), wt_lo(4), 116, 116);
    wt_conv<<<64, 256, 0, stream>>>(gcn2_w1,  wt_hi(5), wt_lo(5), 116, 64);
    wt_conv<<<64, 256, 0, stream>>>(gcn2_w2,  wt_hi(6), wt_lo(6), 64, 8);

    // 1. xf = x + leaky(pseudo @ fc_p_w + fc_p_b)
    mfma_gemm<4, 8><<<GX, 256, 0, stream>>>(pseudo, wt_hi(0), wt_lo(0), fc_p_b, x, xf, NROWS, ROIN, ROIN);

    // 2. proj head
    mfma_proj1<<<dim3(16, 1, PZ), 256, 0, stream>>>(xf, wt1_hi, wt1_lo, ppart);
    proj_reduce<<<(NBZ * ROIN + 255) / 256, 256, 0, stream>>>(ppart, proj_b1, t1);
    mfma_gemm<1, 8><<<16, 256, 0, stream>>>(t1, wt_hi(1), wt_lo(1), proj_b2, nullptr, pbuf, NBZ, ROIN, ROIN);
    rownorm<<<NBZ, 128, 0, stream>>>(pbuf);

    // 3. sim = (pn @ pn^T) / TEMP
    gemm_nt_sym<<<dim3(16, 16, 1), 256, 0, stream>>>(pbuf, simb, NBZ, ROIN, 1.f / 0.07f);

    // 4. contrastive loss
    labels_k<<<4, 256, 0, stream>>>(site, labels);
    rowcnt_k<<<4, 256, 0, stream>>>(labels, rowcnt);
    scan_k<<<1, 1024, 0, stream>>>(rowcnt, rowoff, iscal);
    pair_scatter<<<NBZ, 256, 0, stream>>>(labels, rowoff, iscal, simb, posval, negval);
    loss_part<<<1024, 256, 0, stream>>>(posval, negval, iscal, lpart);
    loss_final<<<1, 256, 0, stream>>>(lpart, iscal, dout + (size_t)NBZ * ROIN * 8);

    // 5. sim min/max, row sumsq, Gram, dist, top-k
    minmax_part<<<512, 256, 0, stream>>>(simb, mmpart);
    minmax_final<<<1, 512, 0, stream>>>(mmpart, fscal);
    row_sumsq<<<NBZ, 256, 0, stream>>>(xf, sq);
    cvt_bf16<<<(NBZ * FLATN) / (256 * 8), 256, 0, stream>>>(xf, xfh);
    gram_mfma<<<dim3(16, 16, 8), 256, 0, stream>>>(xfh, gpart, FLATN, GRAM_KS);
    gram_reduce8<<<4096, 256, 0, stream>>>(gpart, G);
    dist_k<<<4096, 256, 0, stream>>>(G, simb, sq, ages, genders, fscal);
    topk8<<<NBZ, 256, 0, stream>>>(G, topv, topi);

    // 6. GCN stack
    adj_gather<<<NBZ, 256, 0, stream>>>(topv, topi, xf, hA);
    mfma_gemm<3, 8><<<GX, 256, 0, stream>>>(hA, wt_hi(2), wt_lo(2), gcn_b1, nullptr, hB, NROWS, ROIN, ROIN);
    mfma_gemm<1, 8><<<GX, 256, 0, stream>>>(hB, wt_hi(3), wt_lo(3), gcn_b2, nullptr, hA, NROWS, ROIN, ROIN);
    bn_part<<<464, 128, 0, stream>>>(hA, bnpart);
    bn_final<<<1, 128, 0, stream>>>(bnpart, bnmv);
    bn_apply<<<(int)(((size_t)NROWS * ROIN / 4 + 255) / 256), 256, 0, stream>>>(hA, bnmv, bn1_g, bn1_b, hB);

    adj_gather<<<NBZ, 256, 0, stream>>>(topv, topi, hB, xf);
    mfma_gemm<3, 8><<<GX, 256, 0, stream>>>(xf, wt_hi(4), wt_lo(4), gcn1_b, nullptr, hA, NROWS, ROIN, ROIN);
    bn_part<<<464, 128, 0, stream>>>(hA, bnpart);
    bn_final<<<1, 128, 0, stream>>>(bnpart, bnmv);
    bn_apply<<<(int)(((size_t)NROWS * ROIN / 4 + 255) / 256), 256, 0, stream>>>(hA, bnmv, bn2_g, bn2_b, hB);

    adj_gather<<<NBZ, 256, 0, stream>>>(topv, topi, hB, xf);
    mfma_gemm<3, 4><<<GX, 256, 0, stream>>>(xf, wt_hi(5), wt_lo(5), gcn2_b1, nullptr, hA, NROWS, 64, ROIN);
    mfma_gemm<3, 1><<<GX, 256, 0, stream>>>(hA, wt_hi(6), wt_lo(6), gcn2_b2, nullptr, hB, NROWS, 8, 64);

    // 7. bn3 -> d_out
    bn3_k<<<116, 256, 0, stream>>>(hB, bn3_g, bn3_b, dout);
}

// Round 4
// 968.893 us; speedup vs baseline: 2.1334x; 1.0689x over previous
//
#include <hip/hip_runtime.h>
#include <math.h>

#define ROIN 116
#define NBZ 1024
#define FLATN 13456
#define NROWS (NBZ*ROIN)   // 118784
#define ALPHA 0.1f
#define ACOEF 0.9f
#define BETAC 2
#define EPSBN 1e-5f
#define PZ 31              // proj1 split-K chunks
#define PCH 448            // proj1 K-chunk
#define W1LD 14336         // padded K for transposed proj_w1
#define GX 1856            // NROWS/64
#define GRAMZ 16
#define GRAMKS 848
#define NTRI 136           // upper-tri 64x64 block pairs of 16x16 grid

typedef __attribute__((ext_vector_type(8))) short bf16x8;
typedef __attribute__((ext_vector_type(4))) float f32x4;

__device__ __forceinline__ float leakyf(float v){ return v >= 0.f ? v : 0.2f*v; }

__device__ __forceinline__ short f2bf(float f){
    unsigned u = __builtin_bit_cast(unsigned, f);
    unsigned r = u + 0x7fffu + ((u >> 16) & 1u);   // RNE
    return (short)(r >> 16);
}
__device__ __forceinline__ float bf2f(short h){
    unsigned u = ((unsigned)(unsigned short)h) << 16;
    return __builtin_bit_cast(float, u);
}

// ---------------------------------------------------------------------------
// Weight pretranspose + bf16 hi/lo split. Small weights -> WT[128][128].
// ---------------------------------------------------------------------------
__global__ void wt_conv(const float* __restrict__ W, short* __restrict__ hi,
                        short* __restrict__ lo, int K, int N)
{
    int idx = blockIdx.x * 256 + threadIdx.x;   // 16384
    int n = idx >> 7, k = idx & 127;
    float v = (n < N && k < K) ? W[(size_t)k * N + n] : 0.f;
    short h = f2bf(v);
    hi[idx] = h;
    lo[idx] = f2bf(v - bf2f(h));
}

// proj_w1 [13456,116] -> WT1[128][14336] hi/lo
__global__ void wt1_conv(const float* __restrict__ W, short* __restrict__ hi,
                         short* __restrict__ lo)
{
    int idx = blockIdx.x * 256 + threadIdx.x;
    int n = idx / W1LD, k = idx - n * W1LD;
    float v = (n < ROIN && k < FLATN) ? W[(size_t)k * ROIN + n] : 0.f;
    short h = f2bf(v);
    hi[idx] = h;
    lo[idx] = f2bf(v - bf2f(h));
}

// ---------------------------------------------------------------------------
// bf16x2 MFMA GEMM (K<=128): C[M,N] = epi(A[M,K]fp32 @ W)
// EPI: 1 bias, 3 leaky(bias), 4 X + leaky(bias)
// XTRA: 0 none; 1 also write bf16 C + per-row sumsq partials;
//       2 also write per-block BN column stats (sum, sumsq)
// Lane maps HW-verified (m89): A/B row=lane&15, k=(lane>>4)*8;
// C/D col=lane&15, row=(lane>>4)*4+reg.
// ---------------------------------------------------------------------------
template<int EPI, int NF, int XTRA>
__global__ __launch_bounds__(256) void mfma_gemm(
    const float* __restrict__ A, const short* __restrict__ wt_hi,
    const short* __restrict__ wt_lo, const float* __restrict__ bias,
    const float* __restrict__ X, float* __restrict__ C,
    short* __restrict__ bfout, float* __restrict__ rsq, float* __restrict__ statp,
    int M, int N, int K)
{
    __shared__ float st[4][2][128];
    const int wave = threadIdx.x >> 6, lane = threadIdx.x & 63;
    const int m0 = blockIdx.x * 64 + wave * 16;
    const int rl = lane & 15, g = lane >> 4;
    const float* Arow = A + (size_t)(m0 + rl) * K;
    f32x4 acc[NF];
    #pragma unroll
    for (int nf = 0; nf < NF; ++nf) acc[nf] = (f32x4){0.f,0.f,0.f,0.f};
    const int ksteps = (K + 31) / 32;
    for (int s = 0; s < ksteps; ++s) {
        const int kk = s * 32 + g * 8;
        float av[8];
        if (kk + 8 <= K) {
            float4 p = *(const float4*)(Arow + kk);
            float4 q = *(const float4*)(Arow + kk + 4);
            av[0]=p.x; av[1]=p.y; av[2]=p.z; av[3]=p.w;
            av[4]=q.x; av[5]=q.y; av[6]=q.z; av[7]=q.w;
        } else if (kk + 4 <= K) {
            float4 p = *(const float4*)(Arow + kk);
            av[0]=p.x; av[1]=p.y; av[2]=p.z; av[3]=p.w;
            av[4]=0.f; av[5]=0.f; av[6]=0.f; av[7]=0.f;
        } else {
            #pragma unroll
            for (int j = 0; j < 8; ++j) av[j] = 0.f;
        }
        bf16x8 ah, al;
        #pragma unroll
        for (int j = 0; j < 8; ++j) {
            short h = f2bf(av[j]); ah[j] = h;
            al[j] = f2bf(av[j] - bf2f(h));
        }
        #pragma unroll
        for (int nf = 0; nf < NF; ++nf) {
            size_t boff = (size_t)(nf * 16 + rl) * 128 + kk;
            bf16x8 bh = *(const bf16x8*)(wt_hi + boff);
            bf16x8 bl = *(const bf16x8*)(wt_lo + boff);
            acc[nf] = __builtin_amdgcn_mfma_f32_16x16x32_bf16(ah, bh, acc[nf], 0, 0, 0);
            acc[nf] = __builtin_amdgcn_mfma_f32_16x16x32_bf16(al, bh, acc[nf], 0, 0, 0);
            acc[nf] = __builtin_amdgcn_mfma_f32_16x16x32_bf16(ah, bl, acc[nf], 0, 0, 0);
        }
    }
    const int cm = g * 4;
    float rq[4] = {0.f, 0.f, 0.f, 0.f};
    #pragma unroll
    for (int nf = 0; nf < NF; ++nf) {
        int n = nf * 16 + rl;
        float c1 = 0.f, c2 = 0.f;
        if (n < N) {
            float bb = bias[n];
            #pragma unroll
            for (int j = 0; j < 4; ++j) {
                int m = m0 + cm + j;
                size_t idx = (size_t)m * N + n;
                float v = acc[nf][j] + bb;
                if (EPI == 3) v = leakyf(v);
                else if (EPI == 4) v = X[idx] + leakyf(v);
                C[idx] = v;
                if (XTRA == 1) { bfout[idx] = f2bf(v); rq[j] += v * v; }
                if (XTRA == 2) { c1 += v; c2 += v * v; }
            }
        }
        if (XTRA == 2) {
            // sum over the wave's 16 rows: lanes {rl, rl+16, rl+32, rl+48}
            c1 += __shfl_xor(c1, 16); c1 += __shfl_xor(c1, 32);
            c2 += __shfl_xor(c2, 16); c2 += __shfl_xor(c2, 32);
            if (lane < 16) { st[wave][0][n & 127] = c1; st[wave][1][n & 127] = c2; }
        }
    }
    if (XTRA == 1) {
        // per-row sumsq: reduce across rl (16 lanes within g-group)
        #pragma unroll
        for (int j = 0; j < 4; ++j) {
            rq[j] += __shfl_xor(rq[j], 1);
            rq[j] += __shfl_xor(rq[j], 2);
            rq[j] += __shfl_xor(rq[j], 4);
            rq[j] += __shfl_xor(rq[j], 8);
        }
        if (rl == 0) {
            #pragma unroll
            for (int j = 0; j < 4; ++j) rsq[m0 + cm + j] = rq[j];
        }
    }
    if (XTRA == 2) {
        __syncthreads();
        int tid = threadIdx.x;
        if (tid < 232) {
            int sel = tid < 116 ? 0 : 1;
            int c = sel ? tid - 116 : tid;
            float s = st[0][sel][c] + st[1][sel][c] + st[2][sel][c] + st[3][sel][c];
            statp[(size_t)(sel * 116 + c) * GX + blockIdx.x] = s;
        }
    }
}

// BN finalize: statp[(c)*GX + b], statp[(116+c)*GX + b] -> s=rstd*g, t=b-mean*rstd*g
__global__ void bn_final_st(const float* __restrict__ statp, const float* __restrict__ g,
                            const float* __restrict__ bta, float* __restrict__ sb,
                            float* __restrict__ tb)
{
    int c = blockIdx.x, tid = threadIdx.x;   // 116 x 256
    float a1 = 0.f, a2 = 0.f;
    for (int i = tid; i < GX; i += 256) {
        a1 += statp[(size_t)c * GX + i];
        a2 += statp[(size_t)(116 + c) * GX + i];
    }
    __shared__ float r1[256], r2[256];
    r1[tid] = a1; r2[tid] = a2; __syncthreads();
    for (int off = 128; off > 0; off >>= 1) {
        if (tid < off) { r1[tid] += r1[tid + off]; r2[tid] += r2[tid + off]; }
        __syncthreads();
    }
    if (tid == 0) {
        float mean = r1[0] / (float)NROWS;
        float var = r2[0] / (float)NROWS - mean * mean;
        float rstd = 1.f / sqrtf(var + EPSBN);
        float s = rstd * g[c];
        sb[c] = s;
        tb[c] = bta[c] - mean * s;
    }
}

// sq[bz] = sum of 116 per-M-row sumsq partials
__global__ void sq_reduce(const float* __restrict__ rsq, float* __restrict__ sq)
{
    int i = blockIdx.x * 256 + threadIdx.x;
    if (i >= NBZ) return;
    const float* p = rsq + (size_t)i * ROIN;
    float s = 0.f;
    #pragma unroll 4
    for (int r = 0; r < ROIN; ++r) s += p[r];
    sq[i] = s;
}

// ---------------------------------------------------------------------------
// proj1 via bf16x2 MFMA, split-K
// ---------------------------------------------------------------------------
__global__ __launch_bounds__(256) void mfma_proj1(
    const float* __restrict__ A, const short* __restrict__ wt_hi,
    const short* __restrict__ wt_lo, float* __restrict__ part)
{
    const int wave = threadIdx.x >> 6, lane = threadIdx.x & 63;
    const int m0 = blockIdx.x * 64 + wave * 16;
    const int rl = lane & 15, g = lane >> 4;
    const int kbase = blockIdx.z * PCH;
    const float* Arow = A + (size_t)(m0 + rl) * FLATN;
    f32x4 acc[8];
    #pragma unroll
    for (int nf = 0; nf < 8; ++nf) acc[nf] = (f32x4){0.f,0.f,0.f,0.f};
    for (int s = 0; s < 14; ++s) {
        const int kk = kbase + s * 32 + g * 8;
        float av[8];
        if (kk + 8 <= FLATN) {
            float4 p = *(const float4*)(Arow + kk);
            float4 q = *(const float4*)(Arow + kk + 4);
            av[0]=p.x; av[1]=p.y; av[2]=p.z; av[3]=p.w;
            av[4]=q.x; av[5]=q.y; av[6]=q.z; av[7]=q.w;
        } else {
            #pragma unroll
            for (int j = 0; j < 8; ++j) av[j] = 0.f;
        }
        bf16x8 ah, al;
        #pragma unroll
        for (int j = 0; j < 8; ++j) {
            short h = f2bf(av[j]); ah[j] = h;
            al[j] = f2bf(av[j] - bf2f(h));
        }
        #pragma unroll
        for (int nf = 0; nf < 8; ++nf) {
            size_t boff = (size_t)(nf * 16 + rl) * W1LD + kk;
            bf16x8 bh = *(const bf16x8*)(wt_hi + boff);
            bf16x8 bl = *(const bf16x8*)(wt_lo + boff);
            acc[nf] = __builtin_amdgcn_mfma_f32_16x16x32_bf16(ah, bh, acc[nf], 0, 0, 0);
            acc[nf] = __builtin_amdgcn_mfma_f32_16x16x32_bf16(al, bh, acc[nf], 0, 0, 0);
            acc[nf] = __builtin_amdgcn_mfma_f32_16x16x32_bf16(ah, bl, acc[nf], 0, 0, 0);
        }
    }
    float* Cb = part + (size_t)blockIdx.z * NBZ * ROIN;
    const int cm = g * 4;
    #pragma unroll
    for (int nf = 0; nf < 8; ++nf) {
        int n = nf * 16 + rl;
        if (n < ROIN) {
            #pragma unroll
            for (int j = 0; j < 4; ++j)
                Cb[(size_t)(m0 + cm + j) * ROIN + n] = acc[nf][j];
        }
    }
}

// split-K reduce for proj1 (+bias +relu)
__global__ void proj_reduce(const float* __restrict__ ppart,
                            const float* __restrict__ bias, float* __restrict__ t1)
{
    int e = blockIdx.x * 256 + threadIdx.x;
    if (e >= NBZ * ROIN) return;
    int n = e % ROIN;
    float s = 0.f;
    for (int z = 0; z < PZ; ++z) s += ppart[(size_t)z * NBZ * ROIN + e];
    t1[e] = fmaxf(s + bias[n], 0.f);
}

// ---------------------------------------------------------------------------
// fp32 GEMM NT (sim = pn @ pn^T, K=116), symmetric mirror write
// ---------------------------------------------------------------------------
__global__ __launch_bounds__(256) void gemm_nt_sym(
    const float* __restrict__ A, float* __restrict__ C, int M, int K, float scale)
{
    if ((int)blockIdx.y < (int)blockIdx.x) return;
    __shared__ float As[16][65];
    __shared__ float Bs[16][65];
    const int tid = threadIdx.x;
    const int m0 = blockIdx.x * 64;
    const int n0 = blockIdx.y * 64;
    const int tm4 = (tid >> 4) * 4;
    const int tn4 = (tid & 15) * 4;
    const int rA  = tid >> 2;
    const int kbA = (tid & 3) * 4;
    float acc[4][4] = {};
    for (int kt = 0; kt < K; kt += 16) {
        int kg = kt + kbA;
        if (kg + 4 <= K) {
            float4 va = *(const float4*)(A + (size_t)(m0 + rA) * K + kg);
            As[kbA + 0][rA] = va.x; As[kbA + 1][rA] = va.y;
            As[kbA + 2][rA] = va.z; As[kbA + 3][rA] = va.w;
            float4 vb = *(const float4*)(A + (size_t)(n0 + rA) * K + kg);
            Bs[kbA + 0][rA] = vb.x; Bs[kbA + 1][rA] = vb.y;
            Bs[kbA + 2][rA] = vb.z; Bs[kbA + 3][rA] = vb.w;
        } else {
            #pragma unroll
            for (int kk = 0; kk < 4; ++kk) {
                int kgg = kg + kk;
                As[kbA + kk][rA] = (kgg < K) ? A[(size_t)(m0 + rA) * K + kgg] : 0.f;
                Bs[kbA + kk][rA] = (kgg < K) ? A[(size_t)(n0 + rA) * K + kgg] : 0.f;
            }
        }
        __syncthreads();
        #pragma unroll
        for (int k = 0; k < 16; ++k) {
            float a[4], b[4];
            #pragma unroll
            for (int i = 0; i < 4; ++i) a[i] = As[k][tm4 + i];
            #pragma unroll
            for (int j = 0; j < 4; ++j) b[j] = Bs[k][tn4 + j];
            #pragma unroll
            for (int i = 0; i < 4; ++i)
                #pragma unroll
                for (int j = 0; j < 4; ++j)
                    acc[i][j] = fmaf(a[i], b[j], acc[i][j]);
        }
        __syncthreads();
    }
    #pragma unroll
    for (int i = 0; i < 4; ++i) {
        int m = m0 + tm4 + i;
        #pragma unroll
        for (int j = 0; j < 4; ++j) {
            int n = n0 + tn4 + j;
            float v = acc[i][j] * scale;
            C[(size_t)m * M + n] = v;
            C[(size_t)n * M + m] = v;
        }
    }
}

// ---------------------------------------------------------------------------
// Gram via bf16 MFMA, packed upper-tri partials, 16-way split-K
// ---------------------------------------------------------------------------
__global__ __launch_bounds__(256) void gram_mfma(
    const short* __restrict__ Xh, float* __restrict__ gpart)
{
    const int bx = blockIdx.x, by = blockIdx.y;
    if (by < bx) return;
    const int tri = bx * 16 + by - (bx * (bx + 1)) / 2;
    const int k0 = blockIdx.z * GRAMKS;
    const int k1 = min(FLATN, k0 + GRAMKS);
    const int wave = threadIdx.x >> 6;
    const int lane = threadIdx.x & 63;
    const int r0 = (wave >> 1) * 32;
    const int c0 = (wave & 1) * 32;
    const int row  = lane & 15;
    const int koff = (lane >> 4) * 8;
    const short* Ap0 = Xh + (size_t)(bx * 64 + r0 + row)      * FLATN;
    const short* Ap1 = Xh + (size_t)(bx * 64 + r0 + 16 + row) * FLATN;
    const short* Bp0 = Xh + (size_t)(by * 64 + c0 + row)      * FLATN;
    const short* Bp1 = Xh + (size_t)(by * 64 + c0 + 16 + row) * FLATN;
    f32x4 acc00 = {0.f,0.f,0.f,0.f}, acc01 = {0.f,0.f,0.f,0.f};
    f32x4 acc10 = {0.f,0.f,0.f,0.f}, acc11 = {0.f,0.f,0.f,0.f};
    const bf16x8 zf = {0,0,0,0,0,0,0,0};
    for (int k = k0; k < k1; k += 32) {
        int kk = k + koff;
        bool ok = (kk + 8 <= k1);
        bf16x8 a0 = ok ? *(const bf16x8*)(Ap0 + kk) : zf;
        bf16x8 a1 = ok ? *(const bf16x8*)(Ap1 + kk) : zf;
        bf16x8 b0 = ok ? *(const bf16x8*)(Bp0 + kk) : zf;
        bf16x8 b1 = ok ? *(const bf16x8*)(Bp1 + kk) : zf;
        acc00 = __builtin_amdgcn_mfma_f32_16x16x32_bf16(a0, b0, acc00, 0, 0, 0);
        acc01 = __builtin_amdgcn_mfma_f32_16x16x32_bf16(a0, b1, acc01, 0, 0, 0);
        acc10 = __builtin_amdgcn_mfma_f32_16x16x32_bf16(a1, b0, acc10, 0, 0, 0);
        acc11 = __builtin_amdgcn_mfma_f32_16x16x32_bf16(a1, b1, acc11, 0, 0, 0);
    }
    float* Cb = gpart + ((size_t)blockIdx.z * NTRI + tri) * 4096;
    const int crow = (lane >> 4) * 4;
    const int ccol = lane & 15;
    #pragma unroll
    for (int j = 0; j < 4; ++j) {
        Cb[(size_t)(r0 + crow + j)      * 64 + (c0 + ccol)]      = acc00[j];
        Cb[(size_t)(r0 + crow + j)      * 64 + (c0 + 16 + ccol)] = acc01[j];
        Cb[(size_t)(r0 + 16 + crow + j) * 64 + (c0 + ccol)]      = acc10[j];
        Cb[(size_t)(r0 + 16 + crow + j) * 64 + (c0 + 16 + ccol)] = acc11[j];
    }
}

// reduce 16 packed-tri partials -> G (with mirror)
__global__ void gram_reduce_p(const float* __restrict__ gpart, float* __restrict__ G)
{
    const int t = blockIdx.x;   // 0..135
    int bx = 0;
    #pragma unroll
    for (int b = 1; b < 16; ++b) {
        int base = b * 17 - (b * (b + 1)) / 2;   // tri(b,b)
        if (base <= t) bx = b;
    }
    const int by = t - bx * 16 + (bx * (bx + 1)) / 2;
    for (int e = threadIdx.x; e < 4096; e += 256) {
        float s = 0.f;
        #pragma unroll
        for (int z = 0; z < GRAMZ; ++z)
            s += gpart[((size_t)z * NTRI + t) * 4096 + e];
        int i = bx * 64 + (e >> 6), j = by * 64 + (e & 63);
        G[((size_t)i << 10) + j] = s;
        G[((size_t)j << 10) + i] = s;
    }
}

// p[1024,116] -> row L2-normalize in place
__global__ void rownorm(float* __restrict__ p)
{
    int row = blockIdx.x, t = threadIdx.x;   // 128 threads
    __shared__ float red[128];
    float x = 0.f, v = 0.f;
    if (t < ROIN) { x = p[row * ROIN + t]; v = x * x; }
    red[t] = v; __syncthreads();
    for (int off = 64; off > 0; off >>= 1) { if (t < off) red[t] += red[t + off]; __syncthreads(); }
    float inv = 1.f / sqrtf(red[0]);
    if (t < ROIN) p[row * ROIN + t] = x * inv;
}

// global min/max of sim
__global__ void minmax_part(const float* __restrict__ sim, float* __restrict__ mm)
{
    int t = threadIdx.x, b = blockIdx.x;   // 512 x 256
    float mn = 1e30f, mx = -1e30f;
    for (size_t i = (size_t)b * 256 + t; i < 1048576u; i += 512u * 256u) {
        float v = sim[i]; mn = fminf(mn, v); mx = fmaxf(mx, v);
    }
    __shared__ float smn[256], smx[256];
    smn[t] = mn; smx[t] = mx; __syncthreads();
    for (int off = 128; off > 0; off >>= 1) {
        if (t < off) { smn[t] = fminf(smn[t], smn[t + off]); smx[t] = fmaxf(smx[t], smx[t + off]); }
        __syncthreads();
    }
    if (t == 0) { mm[b] = smn[0]; mm[512 + b] = smx[0]; }
}
__global__ void minmax_final(const float* __restrict__ mm, float* __restrict__ fscal)
{
    int t = threadIdx.x;   // 512 threads
    __shared__ float smn[512], smx[512];
    smn[t] = mm[t]; smx[t] = mm[512 + t]; __syncthreads();
    for (int off = 256; off > 0; off >>= 1) {
        if (t < off) { smn[t] = fminf(smn[t], smn[t + off]); smx[t] = fmaxf(smx[t], smx[t + off]); }
        __syncthreads();
    }
    if (t == 0) { fscal[0] = smn[0]; fscal[1] = smx[0]; }
}

// labels[i] = argmax(site[i,0..3]) (first max)
__global__ void labels_k(const int* __restrict__ site, int* __restrict__ labels)
{
    int i = blockIdx.x * 256 + threadIdx.x;
    if (i >= NBZ) return;
    int best = site[4 * i], bi = 0;
    #pragma unroll
    for (int k = 1; k < 4; ++k) { int v = site[4 * i + k]; if (v > best) { best = v; bi = k; } }
    labels[i] = bi;
}

__global__ void rowcnt_k(const int* __restrict__ labels, int* __restrict__ rowcnt)
{
    int i = blockIdx.x * 256 + threadIdx.x;
    if (i >= NBZ) return;
    int li = labels[i], c = 0;
    for (int j = 0; j < NBZ; ++j) c += (labels[j] == li);
    rowcnt[i] = c;
}

// exclusive scan of per-row positive counts; iscal[0]=npos, iscal[1]=m
__global__ __launch_bounds__(1024) void scan_k(const int* __restrict__ rowcnt,
                                               int* __restrict__ rowoff, int* __restrict__ iscal)
{
    __shared__ int s[1024];
    int t = threadIdx.x;
    int c = rowcnt[t];
    s[t] = c; __syncthreads();
    for (int off = 1; off < 1024; off <<= 1) {
        int v = (t >= off) ? s[t - off] : 0;
        __syncthreads();
        s[t] += v;
        __syncthreads();
    }
    rowoff[t] = s[t] - c;
    if (t == 1023) {
        int npos = s[1023];
        int nneg = 1024 * 1024 - npos;
        iscal[0] = npos;
        iscal[1] = (npos < nneg) ? npos : nneg;
    }
}

// scatter sim values to rank-paired pos/neg arrays
__global__ void pair_scatter(const int* __restrict__ labels, const int* __restrict__ rowoff,
                             const int* __restrict__ iscal, const float* __restrict__ sim,
                             float* __restrict__ posval, float* __restrict__ negval)
{
    int row = blockIdx.x, t = threadIdx.x;
    int m = iscal[1];
    int li = labels[row];
    int j0 = t * 4;
    int eq[4]; int c = 0;
    #pragma unroll
    for (int kk = 0; kk < 4; ++kk) { eq[kk] = (labels[j0 + kk] == li); c += eq[kk]; }
    __shared__ int s[256];
    s[t] = c; __syncthreads();
    for (int off = 1; off < 256; off <<= 1) {
        int v = (t >= off) ? s[t - off] : 0;
        __syncthreads();
        s[t] += v;
        __syncthreads();
    }
    int r = rowoff[row] + s[t] - c;
    size_t base = (size_t)row * 1024;
    #pragma unroll
    for (int kk = 0; kk < 4; ++kk) {
        size_t f = base + j0 + kk;
        float v = sim[f];
        if (eq[kk]) { if (r < m) posval[r] = v; r++; }
        else { long nr = (long)f - r; if (nr < m) negval[nr] = v; }
    }
}

__global__ void loss_part(const float* __restrict__ posval, const float* __restrict__ negval,
                          const int* __restrict__ iscal, float* __restrict__ lp)
{
    int m = iscal[1];
    int t = threadIdx.x, b = blockIdx.x;   // 1024 x 256
    float s = 0.f;
    for (int k = b * 256 + t; k < m; k += 1024 * 256) {
        float d = negval[k] - posval[k];
        s += fmaxf(d, 0.f) + log1pf(expf(-fabsf(d)));
    }
    __shared__ float red[256];
    red[t] = s; __syncthreads();
    for (int off = 128; off > 0; off >>= 1) { if (t < off) red[t] += red[t + off]; __syncthreads(); }
    if (t == 0) lp[b] = red[0];
}

__global__ void loss_final(const float* __restrict__ lp, const int* __restrict__ iscal,
                           float* __restrict__ outp)
{
    int t = threadIdx.x;   // 256
    double s = 0.0;
    for (int k = t; k < 1024; k += 256) s += (double)lp[k];
    __shared__ double red[256];
    red[t] = s; __syncthreads();
    for (int off = 128; off > 0; off >>= 1) { if (t < off) red[t] += red[t + off]; __syncthreads(); }
    if (t == 0) {
        int m = iscal[1]; if (m < 1) m = 1;
        outp[0] = (float)(red[0] / (double)m);
    }
}

// dist (in place over G): total * (cond ? 0.9 : 0.1)
__global__ void dist_k(float* __restrict__ G, const float* __restrict__ sim,
                       const float* __restrict__ sq, const int* __restrict__ ages,
                       const int* __restrict__ genders, const float* __restrict__ fscal)
{
    size_t e = (size_t)blockIdx.x * 256 + threadIdx.x;
    int i = (int)(e >> 10), j = (int)(e & 1023);
    float smin = fscal[0], smax = fscal[1];
    float sn = (sim[e] - smin) / (smax - smin);
    float d2 = fmaxf(sq[i] + sq[j] - 2.f * G[e], 0.f);
    float fs = expf(-ALPHA * sqrtf(d2));
    float total = fs * (1.f - sn) + sn;
    int da = ages[i] - ages[j]; if (da < 0) da = -da;
    bool cond = (da <= BETAC) && (genders[i] == genders[j]);
    G[e] = total * (cond ? ACOEF : 1.f - ACOEF);
}

// row-wise top-8 (ties -> lower index)
__global__ void topk8(const float* __restrict__ dist, float* __restrict__ topv, int* __restrict__ topi)
{
    int row = blockIdx.x, t = threadIdx.x;
    __shared__ float sv[1024];
    __shared__ float rv[256];
    __shared__ int   ri[256];
    for (int j = t; j < 1024; j += 256) sv[j] = dist[(size_t)row * 1024 + j];
    __syncthreads();
    for (int k = 0; k < 8; ++k) {
        float bv = -1e30f; int bi = 1 << 20;
        for (int j = t; j < 1024; j += 256) {
            float x = sv[j];
            if (x > bv || (x == bv && j < bi)) { bv = x; bi = j; }
        }
        rv[t] = bv; ri[t] = bi;
        __syncthreads();
        for (int s = 128; s > 0; s >>= 1) {
            if (t < s) {
                float ov = rv[t + s]; int oi = ri[t + s];
                if (ov > rv[t] || (ov == rv[t] && oi < ri[t])) { rv[t] = ov; ri[t] = oi; }
            }
            __syncthreads();
        }
        if (t == 0) { topv[row * 8 + k] = rv[0]; topi[row * 8 + k] = ri[0]; sv[ri[0]] = -1e30f; }
        __syncthreads();
    }
}

// out[row,:] = sum_k vals[row,k] * feat[idx[row,k], :]
// FOLD: apply per-column BN affine to feat on the fly:
//   out = s_c * acc + wsum * t_c
template<int FOLD>
__global__ void adj_gather(const float* __restrict__ vals, const int* __restrict__ idxs,
                           const float* __restrict__ feat, const float* __restrict__ sb,
                           const float* __restrict__ tb, float* __restrict__ out)
{
    int row = blockIdx.x, t = threadIdx.x;
    __shared__ float v[8]; __shared__ int ix[8];
    if (t < 8) { v[t] = vals[row * 8 + t]; ix[t] = idxs[row * 8 + t]; }
    __syncthreads();
    float vv[8]; const float4* fp[8];
    #pragma unroll
    for (int k = 0; k < 8; ++k) { vv[k] = v[k]; fp[k] = (const float4*)(feat + (size_t)ix[k] * FLATN); }
    float wsum = 0.f;
    if (FOLD) {
        #pragma unroll
        for (int k = 0; k < 8; ++k) wsum += vv[k];
    }
    float4* op = (float4*)(out + (size_t)row * FLATN);
    for (int c = t; c < FLATN / 4; c += 256) {
        float4 acc = {0.f, 0.f, 0.f, 0.f};
        #pragma unroll
        for (int k = 0; k < 8; ++k) {
            float4 x = fp[k][c];
            acc.x = fmaf(vv[k], x.x, acc.x);
            acc.y = fmaf(vv[k], x.y, acc.y);
            acc.z = fmaf(vv[k], x.z, acc.z);
            acc.w = fmaf(vv[k], x.w, acc.w);
        }
        if (FOLD) {
            int cb = (c * 4) % ROIN;   // multiple of 4, <= 112
            acc.x = sb[cb]     * acc.x + wsum * tb[cb];
            acc.y = sb[cb + 1] * acc.y + wsum * tb[cb + 1];
            acc.z = sb[cb + 2] * acc.z + wsum * tb[cb + 2];
            acc.w = sb[cb + 3] * acc.w + wsum * tb[cb + 3];
        }
        op[c] = acc;
    }
}

// bn3: per-ROI-channel stats over (N=1024, L=8); writes final output
__global__ void bn3_k(const float* __restrict__ X, const float* __restrict__ g,
                      const float* __restrict__ bta, float* __restrict__ out)
{
    int c = blockIdx.x, t = threadIdx.x;   // 116 x 256
    float s = 0.f, s2 = 0.f;
    for (int k = t; k < 8192; k += 256) {
        int n = k >> 3, l = k & 7;
        float v = X[(size_t)n * 928 + c * 8 + l];
        s += v; s2 += v * v;
    }
    __shared__ float rs[256], rs2[256];
    rs[t] = s; rs2[t] = s2; __syncthreads();
    for (int off = 128; off > 0; off >>= 1) {
        if (t < off) { rs[t] += rs[t + off]; rs2[t] += rs2[t + off]; }
        __syncthreads();
    }
    __shared__ float sm, sr;
    if (t == 0) {
        float mean = rs[0] / 8192.f;
        float var = rs2[0] / 8192.f - mean * mean;
        sm = mean; sr = 1.f / sqrtf(var + EPSBN);
    }
    __syncthreads();
    float mean = sm, rstd = sr, gg = g[c], bb = bta[c];
    for (int k = t; k < 8192; k += 256) {
        int n = k >> 3, l = k & 7;
        size_t idx = (size_t)n * 928 + c * 8 + l;
        out[idx] = (X[idx] - mean) * rstd * gg + bb;
    }
}

// ---------------------------------------------------------------------------
extern "C" void kernel_launch(void* const* d_in, const int* in_sizes, int n_in,
                              void* d_out, int out_size, void* d_ws, size_t ws_size,
                              hipStream_t stream)
{
    const float* x        = (const float*)d_in[0];
    const float* pseudo   = (const float*)d_in[1];
    const int*   ages     = (const int*)d_in[2];
    const int*   genders  = (const int*)d_in[3];
    const int*   site     = (const int*)d_in[4];
    const float* fc_p_w   = (const float*)d_in[5];
    const float* fc_p_b   = (const float*)d_in[6];
    const float* proj_w1  = (const float*)d_in[7];
    const float* proj_b1  = (const float*)d_in[8];
    const float* proj_w2  = (const float*)d_in[9];
    const float* proj_b2  = (const float*)d_in[10];
    const float* gcn_w1   = (const float*)d_in[11];
    const float* gcn_b1   = (const float*)d_in[12];
    const float* gcn_w2   = (const float*)d_in[13];
    const float* gcn_b2   = (const float*)d_in[14];
    const float* gcn1_w   = (const float*)d_in[15];
    const float* gcn1_b   = (const float*)d_in[16];
    const float* gcn2_w1  = (const float*)d_in[17];
    const float* gcn2_b1  = (const float*)d_in[18];
    const float* gcn2_w2  = (const float*)d_in[19];
    const float* gcn2_b2  = (const float*)d_in[20];
    const float* bn1_g    = (const float*)d_in[21];
    const float* bn1_b    = (const float*)d_in[22];
    const float* bn2_g    = (const float*)d_in[23];
    const float* bn2_b    = (const float*)d_in[24];
    const float* bn3_g    = (const float*)d_in[25];
    const float* bn3_b    = (const float*)d_in[26];
    float* dout = (float*)d_out;

    char* w = (char*)d_ws;
    size_t off = 0;
    auto carve = [&](size_t bytes) { char* p = w + off; off = (off + bytes + 255) & ~(size_t)255; return p; };
    float* xf     = (float*)carve((size_t)NROWS * ROIN * 4);   // 55.1 MB
    float* hA     = (float*)carve((size_t)NROWS * ROIN * 4);   // 55.1 MB
    float* hB     = (float*)carve((size_t)NROWS * ROIN * 4);   // 55.1 MB
    float* G      = (float*)carve(1048576u * 4);
    float* simb   = (float*)carve(1048576u * 4);
    float* t1     = (float*)carve((size_t)NBZ * ROIN * 4);
    float* pbuf   = (float*)carve((size_t)NBZ * ROIN * 4);
    float* sq     = (float*)carve(4096);
    float* rsq    = (float*)carve((size_t)NROWS * 4);          // per-M-row sumsq
    int*   labels = (int*)carve(4096);
    int*   rowcnt = (int*)carve(4096);
    int*   rowoff = (int*)carve(4096);
    int*   iscal  = (int*)carve(256);
    float* fscal  = (float*)carve(256);
    float* posval = (float*)carve(524288u * 4);
    float* negval = (float*)carve(524288u * 4);
    float* lpart  = (float*)carve(4096);
    float* mmpart = (float*)carve(4096);
    float* topv   = (float*)carve(32768);
    int*   topi   = (int*)carve(32768);
    float* statp  = (float*)carve((size_t)232 * GX * 4);       // 1.72 MB
    float* sbA    = (float*)carve(512);
    float* tbA    = (float*)carve(512);
    float* sbB    = (float*)carve(512);
    float* tbB    = (float*)carve(512);
    short* wt1_hi = (short*)carve((size_t)128 * W1LD * 2);     // 3.67 MB
    short* wt1_lo = (short*)carve((size_t)128 * W1LD * 2);
    short* wts    = (short*)carve((size_t)7 * 2 * 16384 * 2);
    // aliases into dead phases:
    float* ppart  = hA;            // proj1 partials (14.7 MB), dead after proj_reduce
    float* gpart  = hA;            // Gram packed-tri partials (35.6 MB), after ppart dead
    short* xfh    = (short*)hB;    // bf16 xf (27.5 MB), dead before gcn_w1 writes hB

    auto wt_hi = [&](int i) { return wts + (size_t)i * 2 * 16384; };
    auto wt_lo = [&](int i) { return wts + (size_t)i * 2 * 16384 + 16384; };

    // 0. weight pretranspose + hi/lo split
    wt1_conv<<<(128 * W1LD) / 256, 256, 0, stream>>>(proj_w1, wt1_hi, wt1_lo);
    wt_conv<<<64, 256, 0, stream>>>(fc_p_w,   wt_hi(0), wt_lo(0), 116, 116);
    wt_conv<<<64, 256, 0, stream>>>(proj_w2,  wt_hi(1), wt_lo(1), 116, 116);
    wt_conv<<<64, 256, 0, stream>>>(gcn_w1,   wt_hi(2), wt_lo(2), 116, 116);
    wt_conv<<<64, 256, 0, stream>>>(gcn_w2,   wt_hi(3), wt_lo(3), 116, 116);
    wt_conv<<<64, 256, 0, stream>>>(gcn1_w,   wt_hi(4), wt_lo(4), 116, 116);
    wt_conv<<<64, 256, 0, stream>>>(gcn2_w1,  wt_hi(5), wt_lo(5), 116, 64);
    wt_conv<<<64, 256, 0, stream>>>(gcn2_w2,  wt_hi(6), wt_lo(6), 64, 8);

    // 1. xf = x + leaky(pseudo @ fc_p_w + b); also emit bf16 xfh + row-sumsq partials
    mfma_gemm<4, 8, 1><<<GX, 256, 0, stream>>>(pseudo, wt_hi(0), wt_lo(0), fc_p_b, x, xf,
                                               xfh, rsq, nullptr, NROWS, ROIN, ROIN);
    sq_reduce<<<4, 256, 0, stream>>>(rsq, sq);

    // 2. proj head
    mfma_proj1<<<dim3(16, 1, PZ), 256, 0, stream>>>(xf, wt1_hi, wt1_lo, ppart);
    proj_reduce<<<(NBZ * ROIN + 255) / 256, 256, 0, stream>>>(ppart, proj_b1, t1);
    mfma_gemm<1, 8, 0><<<16, 256, 0, stream>>>(t1, wt_hi(1), wt_lo(1), proj_b2, nullptr, pbuf,
                                               nullptr, nullptr, nullptr, NBZ, ROIN, ROIN);
    rownorm<<<NBZ, 128, 0, stream>>>(pbuf);

    // 3. sim = (pn @ pn^T) / TEMP
    gemm_nt_sym<<<dim3(16, 16, 1), 256, 0, stream>>>(pbuf, simb, NBZ, ROIN, 1.f / 0.07f);

    // 4. contrastive loss
    labels_k<<<4, 256, 0, stream>>>(site, labels);
    rowcnt_k<<<4, 256, 0, stream>>>(labels, rowcnt);
    scan_k<<<1, 1024, 0, stream>>>(rowcnt, rowoff, iscal);
    pair_scatter<<<NBZ, 256, 0, stream>>>(labels, rowoff, iscal, simb, posval, negval);
    loss_part<<<1024, 256, 0, stream>>>(posval, negval, iscal, lpart);
    loss_final<<<1, 256, 0, stream>>>(lpart, iscal, dout + (size_t)NBZ * ROIN * 8);

    // 5. sim min/max, Gram, dist, top-k
    minmax_part<<<512, 256, 0, stream>>>(simb, mmpart);
    minmax_final<<<1, 512, 0, stream>>>(mmpart, fscal);
    gram_mfma<<<dim3(16, 16, GRAMZ), 256, 0, stream>>>(xfh, gpart);
    gram_reduce_p<<<NTRI, 256, 0, stream>>>(gpart, G);
    dist_k<<<4096, 256, 0, stream>>>(G, simb, sq, ages, genders, fscal);
    topk8<<<NBZ, 256, 0, stream>>>(G, topv, topi);

    // 6. GCN stack (adj@X as 8-sparse gathers; BN stats fused into GEMMs,
    //    BN apply folded into the following gather)
    adj_gather<0><<<NBZ, 256, 0, stream>>>(topv, topi, xf, nullptr, nullptr, hA);
    mfma_gemm<3, 8, 0><<<GX, 256, 0, stream>>>(hA, wt_hi(2), wt_lo(2), gcn_b1, nullptr, hB,
                                               nullptr, nullptr, nullptr, NROWS, ROIN, ROIN);
    mfma_gemm<1, 8, 2><<<GX, 256, 0, stream>>>(hB, wt_hi(3), wt_lo(3), gcn_b2, nullptr, hA,
                                               nullptr, nullptr, statp, NROWS, ROIN, ROIN);
    bn_final_st<<<116, 256, 0, stream>>>(statp, bn1_g, bn1_b, sbA, tbA);

    adj_gather<1><<<NBZ, 256, 0, stream>>>(topv, topi, hA, sbA, tbA, hB);
    mfma_gemm<3, 8, 2><<<GX, 256, 0, stream>>>(hB, wt_hi(4), wt_lo(4), gcn1_b, nullptr, hA,
                                               nullptr, nullptr, statp, NROWS, ROIN, ROIN);
    bn_final_st<<<116, 256, 0, stream>>>(statp, bn2_g, bn2_b, sbB, tbB);

    adj_gather<1><<<NBZ, 256, 0, stream>>>(topv, topi, hA, sbB, tbB, hB);
    mfma_gemm<3, 4, 0><<<GX, 256, 0, stream>>>(hB, wt_hi(5), wt_lo(5), gcn2_b1, nullptr, hA,
                                               nullptr, nullptr, nullptr, NROWS, 64, ROIN);
    mfma_gemm<3, 1, 0><<<GX, 256, 0, stream>>>(hA, wt_hi(6), wt_lo(6), gcn2_b2, nullptr, hB,
                                               nullptr, nullptr, nullptr, NROWS, 8, 64);

    // 7. bn3 -> d_out
    bn3_k<<<116, 256, 0, stream>>>(hB, bn3_g, bn3_b, dout);
}

// Round 5
// 880.846 us; speedup vs baseline: 2.3466x; 1.1000x over previous
//
#include <hip/hip_runtime.h>
#include <math.h>

#define ROIN 116
#define NBZ 1024
#define FLATN 13456
#define NROWS (NBZ*ROIN)   // 118784
#define ALPHA 0.1f
#define ACOEF 0.9f
#define BETAC 2
#define EPSBN 1e-5f
#define PZ 31              // proj1 split-K chunks
#define PCH 448            // proj1 K-chunk
#define W1LD 14336         // padded K for transposed proj_w1
#define GX 1856            // NROWS/64
#define GRAMZ 20
#define GRAMKS 680
#define NTRI 36            // upper-tri 128x128 tiles of 8x8 grid

typedef __attribute__((ext_vector_type(8))) short bf16x8;
typedef __attribute__((ext_vector_type(4))) float f32x4;

__device__ __forceinline__ float leakyf(float v){ return v >= 0.f ? v : 0.2f*v; }

__device__ __forceinline__ short f2bf(float f){
    unsigned u = __builtin_bit_cast(unsigned, f);
    unsigned r = u + 0x7fffu + ((u >> 16) & 1u);   // RNE
    return (short)(r >> 16);
}
__device__ __forceinline__ float bf2f(short h){
    unsigned u = ((unsigned)(unsigned short)h) << 16;
    return __builtin_bit_cast(float, u);
}

// ---------------------------------------------------------------------------
// Weight pretranspose + bf16 hi/lo split. Small weights -> WT[128][128].
// ---------------------------------------------------------------------------
__global__ void wt_conv(const float* __restrict__ W, short* __restrict__ hi,
                        short* __restrict__ lo, int K, int N)
{
    int idx = blockIdx.x * 256 + threadIdx.x;   // 16384
    int n = idx >> 7, k = idx & 127;
    float v = (n < N && k < K) ? W[(size_t)k * N + n] : 0.f;
    short h = f2bf(v);
    hi[idx] = h;
    lo[idx] = f2bf(v - bf2f(h));
}

// proj_w1 [13456,116] -> WT1[128][14336] hi/lo
__global__ void wt1_conv(const float* __restrict__ W, short* __restrict__ hi,
                         short* __restrict__ lo)
{
    int idx = blockIdx.x * 256 + threadIdx.x;
    int n = idx / W1LD, k = idx - n * W1LD;
    float v = (n < ROIN && k < FLATN) ? W[(size_t)k * ROIN + n] : 0.f;
    short h = f2bf(v);
    hi[idx] = h;
    lo[idx] = f2bf(v - bf2f(h));
}

// ---------------------------------------------------------------------------
// bf16x2 MFMA GEMM (K<=128): C[M,N] = epi(A[M,K]fp32 @ W)
// EPI: 1 bias, 3 leaky(bias), 4 X + leaky(bias)
// XTRA: 0 none; 1 also write bf16 C + per-row sumsq partials;
//       2 also write per-block BN column stats (sum, sumsq)
// ---------------------------------------------------------------------------
template<int EPI, int NF, int XTRA>
__global__ __launch_bounds__(256) void mfma_gemm(
    const float* __restrict__ A, const short* __restrict__ wt_hi,
    const short* __restrict__ wt_lo, const float* __restrict__ bias,
    const float* __restrict__ X, float* __restrict__ C,
    short* __restrict__ bfout, float* __restrict__ rsq, float* __restrict__ statp,
    int M, int N, int K)
{
    __shared__ float st[4][2][128];
    const int wave = threadIdx.x >> 6, lane = threadIdx.x & 63;
    const int m0 = blockIdx.x * 64 + wave * 16;
    const int rl = lane & 15, g = lane >> 4;
    const float* Arow = A + (size_t)(m0 + rl) * K;
    f32x4 acc[NF];
    #pragma unroll
    for (int nf = 0; nf < NF; ++nf) acc[nf] = (f32x4){0.f,0.f,0.f,0.f};
    const int ksteps = (K + 31) / 32;
    for (int s = 0; s < ksteps; ++s) {
        const int kk = s * 32 + g * 8;
        float av[8];
        if (kk + 8 <= K) {
            float4 p = *(const float4*)(Arow + kk);
            float4 q = *(const float4*)(Arow + kk + 4);
            av[0]=p.x; av[1]=p.y; av[2]=p.z; av[3]=p.w;
            av[4]=q.x; av[5]=q.y; av[6]=q.z; av[7]=q.w;
        } else if (kk + 4 <= K) {
            float4 p = *(const float4*)(Arow + kk);
            av[0]=p.x; av[1]=p.y; av[2]=p.z; av[3]=p.w;
            av[4]=0.f; av[5]=0.f; av[6]=0.f; av[7]=0.f;
        } else {
            #pragma unroll
            for (int j = 0; j < 8; ++j) av[j] = 0.f;
        }
        bf16x8 ah, al;
        #pragma unroll
        for (int j = 0; j < 8; ++j) {
            short h = f2bf(av[j]); ah[j] = h;
            al[j] = f2bf(av[j] - bf2f(h));
        }
        #pragma unroll
        for (int nf = 0; nf < NF; ++nf) {
            size_t boff = (size_t)(nf * 16 + rl) * 128 + kk;
            bf16x8 bh = *(const bf16x8*)(wt_hi + boff);
            bf16x8 bl = *(const bf16x8*)(wt_lo + boff);
            acc[nf] = __builtin_amdgcn_mfma_f32_16x16x32_bf16(ah, bh, acc[nf], 0, 0, 0);
            acc[nf] = __builtin_amdgcn_mfma_f32_16x16x32_bf16(al, bh, acc[nf], 0, 0, 0);
            acc[nf] = __builtin_amdgcn_mfma_f32_16x16x32_bf16(ah, bl, acc[nf], 0, 0, 0);
        }
    }
    const int cm = g * 4;
    float rq[4] = {0.f, 0.f, 0.f, 0.f};
    #pragma unroll
    for (int nf = 0; nf < NF; ++nf) {
        int n = nf * 16 + rl;
        float c1 = 0.f, c2 = 0.f;
        if (n < N) {
            float bb = bias[n];
            #pragma unroll
            for (int j = 0; j < 4; ++j) {
                int m = m0 + cm + j;
                size_t idx = (size_t)m * N + n;
                float v = acc[nf][j] + bb;
                if (EPI == 3) v = leakyf(v);
                else if (EPI == 4) v = X[idx] + leakyf(v);
                C[idx] = v;
                if (XTRA == 1) { bfout[idx] = f2bf(v); rq[j] += v * v; }
                if (XTRA == 2) { c1 += v; c2 += v * v; }
            }
        }
        if (XTRA == 2) {
            c1 += __shfl_xor(c1, 16); c1 += __shfl_xor(c1, 32);
            c2 += __shfl_xor(c2, 16); c2 += __shfl_xor(c2, 32);
            if (lane < 16) { st[wave][0][n & 127] = c1; st[wave][1][n & 127] = c2; }
        }
    }
    if (XTRA == 1) {
        #pragma unroll
        for (int j = 0; j < 4; ++j) {
            rq[j] += __shfl_xor(rq[j], 1);
            rq[j] += __shfl_xor(rq[j], 2);
            rq[j] += __shfl_xor(rq[j], 4);
            rq[j] += __shfl_xor(rq[j], 8);
        }
        if (rl == 0) {
            #pragma unroll
            for (int j = 0; j < 4; ++j) rsq[m0 + cm + j] = rq[j];
        }
    }
    if (XTRA == 2) {
        __syncthreads();
        int tid = threadIdx.x;
        if (tid < 232) {
            int sel = tid < 116 ? 0 : 1;
            int c = sel ? tid - 116 : tid;
            float s = st[0][sel][c] + st[1][sel][c] + st[2][sel][c] + st[3][sel][c];
            statp[(size_t)(sel * 116 + c) * GX + blockIdx.x] = s;
        }
    }
}

// ---------------------------------------------------------------------------
// Fused pair: C = (leaky(A@W2+b2)) @ W3 + b3, + BN column stats.
// Phase-1 result staged per-wave in LDS (fp32), re-fragmented for phase 2.
// ---------------------------------------------------------------------------
__global__ __launch_bounds__(256) void mfma_gemm2(
    const float* __restrict__ A,
    const short* __restrict__ w2h, const short* __restrict__ w2l,
    const float* __restrict__ b2,
    const short* __restrict__ w3h, const short* __restrict__ w3l,
    const float* __restrict__ b3,
    float* __restrict__ C, float* __restrict__ statp)
{
    __shared__ float c1s[4][16][120];
    __shared__ float st[4][2][128];
    const int wave = threadIdx.x >> 6, lane = threadIdx.x & 63;
    const int m0 = blockIdx.x * 64 + wave * 16;
    const int rl = lane & 15, g = lane >> 4;
    const float* Arow = A + (size_t)(m0 + rl) * ROIN;
    f32x4 acc[8];
    #pragma unroll
    for (int nf = 0; nf < 8; ++nf) acc[nf] = (f32x4){0.f,0.f,0.f,0.f};
    // phase 1: A[64x116] @ W2 -> leaky -> LDS
    for (int s = 0; s < 4; ++s) {
        const int kk = s * 32 + g * 8;
        float av[8];
        if (kk + 8 <= ROIN) {
            float4 p = *(const float4*)(Arow + kk);
            float4 q = *(const float4*)(Arow + kk + 4);
            av[0]=p.x; av[1]=p.y; av[2]=p.z; av[3]=p.w;
            av[4]=q.x; av[5]=q.y; av[6]=q.z; av[7]=q.w;
        } else if (kk + 4 <= ROIN) {
            float4 p = *(const float4*)(Arow + kk);
            av[0]=p.x; av[1]=p.y; av[2]=p.z; av[3]=p.w;
            av[4]=0.f; av[5]=0.f; av[6]=0.f; av[7]=0.f;
        } else {
            #pragma unroll
            for (int j = 0; j < 8; ++j) av[j] = 0.f;
        }
        bf16x8 ah, al;
        #pragma unroll
        for (int j = 0; j < 8; ++j) {
            short h = f2bf(av[j]); ah[j] = h;
            al[j] = f2bf(av[j] - bf2f(h));
        }
        #pragma unroll
        for (int nf = 0; nf < 8; ++nf) {
            size_t boff = (size_t)(nf * 16 + rl) * 128 + kk;
            bf16x8 bh = *(const bf16x8*)(w2h + boff);
            bf16x8 bl = *(const bf16x8*)(w2l + boff);
            acc[nf] = __builtin_amdgcn_mfma_f32_16x16x32_bf16(ah, bh, acc[nf], 0, 0, 0);
            acc[nf] = __builtin_amdgcn_mfma_f32_16x16x32_bf16(al, bh, acc[nf], 0, 0, 0);
            acc[nf] = __builtin_amdgcn_mfma_f32_16x16x32_bf16(ah, bl, acc[nf], 0, 0, 0);
        }
    }
    const int cm = g * 4;
    #pragma unroll
    for (int nf = 0; nf < 8; ++nf) {
        int n = nf * 16 + rl;
        if (n < ROIN) {
            float bb = b2[n];
            #pragma unroll
            for (int j = 0; j < 4; ++j)
                c1s[wave][cm + j][n] = leakyf(acc[nf][j] + bb);
        }
    }
    c1s[wave][rl][116 + g] = 0.f;   // zero pad cols 116..119 (wave-local)
    // phase 2: (LDS tile)[16x116+pad] @ W3  (wave-local rows; lgkmcnt ordering)
    f32x4 acc2[8];
    #pragma unroll
    for (int nf = 0; nf < 8; ++nf) acc2[nf] = (f32x4){0.f,0.f,0.f,0.f};
    for (int s = 0; s < 4; ++s) {
        const int kk = s * 32 + g * 8;
        float av[8];
        if (kk + 8 <= 120) {
            float4 p = *(const float4*)(&c1s[wave][rl][kk]);
            float4 q = *(const float4*)(&c1s[wave][rl][kk + 4]);
            av[0]=p.x; av[1]=p.y; av[2]=p.z; av[3]=p.w;
            av[4]=q.x; av[5]=q.y; av[6]=q.z; av[7]=q.w;
        } else {
            #pragma unroll
            for (int j = 0; j < 8; ++j) av[j] = 0.f;
        }
        bf16x8 ah, al;
        #pragma unroll
        for (int j = 0; j < 8; ++j) {
            short h = f2bf(av[j]); ah[j] = h;
            al[j] = f2bf(av[j] - bf2f(h));
        }
        #pragma unroll
        for (int nf = 0; nf < 8; ++nf) {
            size_t boff = (size_t)(nf * 16 + rl) * 128 + kk;
            bf16x8 bh = *(const bf16x8*)(w3h + boff);
            bf16x8 bl = *(const bf16x8*)(w3l + boff);
            acc2[nf] = __builtin_amdgcn_mfma_f32_16x16x32_bf16(ah, bh, acc2[nf], 0, 0, 0);
            acc2[nf] = __builtin_amdgcn_mfma_f32_16x16x32_bf16(al, bh, acc2[nf], 0, 0, 0);
            acc2[nf] = __builtin_amdgcn_mfma_f32_16x16x32_bf16(ah, bl, acc2[nf], 0, 0, 0);
        }
    }
    #pragma unroll
    for (int nf = 0; nf < 8; ++nf) {
        int n = nf * 16 + rl;
        float s1 = 0.f, s2 = 0.f;
        if (n < ROIN) {
            float bb = b3[n];
            #pragma unroll
            for (int j = 0; j < 4; ++j) {
                float v = acc2[nf][j] + bb;
                C[(size_t)(m0 + cm + j) * ROIN + n] = v;
                s1 += v; s2 += v * v;
            }
        }
        s1 += __shfl_xor(s1, 16); s1 += __shfl_xor(s1, 32);
        s2 += __shfl_xor(s2, 16); s2 += __shfl_xor(s2, 32);
        if (lane < 16) { st[wave][0][n & 127] = s1; st[wave][1][n & 127] = s2; }
    }
    __syncthreads();
    int tid = threadIdx.x;
    if (tid < 232) {
        int sel = tid < 116 ? 0 : 1;
        int c = sel ? tid - 116 : tid;
        float s = st[0][sel][c] + st[1][sel][c] + st[2][sel][c] + st[3][sel][c];
        statp[(size_t)(sel * 116 + c) * GX + blockIdx.x] = s;
    }
}

// ---------------------------------------------------------------------------
// Fused pair: C[NROWS][8] = leaky( leaky(A@W5+b5) @ W6 + b6 )
// ---------------------------------------------------------------------------
__global__ __launch_bounds__(256) void mfma_gemm45(
    const float* __restrict__ A,
    const short* __restrict__ w5h, const short* __restrict__ w5l,
    const float* __restrict__ b5,
    const short* __restrict__ w6h, const short* __restrict__ w6l,
    const float* __restrict__ b6,
    float* __restrict__ C)
{
    __shared__ float c1s[4][16][72];
    const int wave = threadIdx.x >> 6, lane = threadIdx.x & 63;
    const int m0 = blockIdx.x * 64 + wave * 16;
    const int rl = lane & 15, g = lane >> 4;
    const float* Arow = A + (size_t)(m0 + rl) * ROIN;
    f32x4 acc[4];
    #pragma unroll
    for (int nf = 0; nf < 4; ++nf) acc[nf] = (f32x4){0.f,0.f,0.f,0.f};
    for (int s = 0; s < 4; ++s) {
        const int kk = s * 32 + g * 8;
        float av[8];
        if (kk + 8 <= ROIN) {
            float4 p = *(const float4*)(Arow + kk);
            float4 q = *(const float4*)(Arow + kk + 4);
            av[0]=p.x; av[1]=p.y; av[2]=p.z; av[3]=p.w;
            av[4]=q.x; av[5]=q.y; av[6]=q.z; av[7]=q.w;
        } else if (kk + 4 <= ROIN) {
            float4 p = *(const float4*)(Arow + kk);
            av[0]=p.x; av[1]=p.y; av[2]=p.z; av[3]=p.w;
            av[4]=0.f; av[5]=0.f; av[6]=0.f; av[7]=0.f;
        } else {
            #pragma unroll
            for (int j = 0; j < 8; ++j) av[j] = 0.f;
        }
        bf16x8 ah, al;
        #pragma unroll
        for (int j = 0; j < 8; ++j) {
            short h = f2bf(av[j]); ah[j] = h;
            al[j] = f2bf(av[j] - bf2f(h));
        }
        #pragma unroll
        for (int nf = 0; nf < 4; ++nf) {
            size_t boff = (size_t)(nf * 16 + rl) * 128 + kk;
            bf16x8 bh = *(const bf16x8*)(w5h + boff);
            bf16x8 bl = *(const bf16x8*)(w5l + boff);
            acc[nf] = __builtin_amdgcn_mfma_f32_16x16x32_bf16(ah, bh, acc[nf], 0, 0, 0);
            acc[nf] = __builtin_amdgcn_mfma_f32_16x16x32_bf16(al, bh, acc[nf], 0, 0, 0);
            acc[nf] = __builtin_amdgcn_mfma_f32_16x16x32_bf16(ah, bl, acc[nf], 0, 0, 0);
        }
    }
    const int cm = g * 4;
    #pragma unroll
    for (int nf = 0; nf < 4; ++nf) {
        int n = nf * 16 + rl;   // < 64
        float bb = b5[n];
        #pragma unroll
        for (int j = 0; j < 4; ++j)
            c1s[wave][cm + j][n] = leakyf(acc[nf][j] + bb);
    }
    // phase 2: K=64, N=8
    f32x4 acc2 = {0.f,0.f,0.f,0.f};
    for (int s = 0; s < 2; ++s) {
        const int kk = s * 32 + g * 8;   // <= 56, +8 <= 64
        float4 p = *(const float4*)(&c1s[wave][rl][kk]);
        float4 q = *(const float4*)(&c1s[wave][rl][kk + 4]);
        float av[8] = {p.x, p.y, p.z, p.w, q.x, q.y, q.z, q.w};
        bf16x8 ah, al;
        #pragma unroll
        for (int j = 0; j < 8; ++j) {
            short h = f2bf(av[j]); ah[j] = h;
            al[j] = f2bf(av[j] - bf2f(h));
        }
        size_t boff = (size_t)rl * 128 + kk;
        bf16x8 bh = *(const bf16x8*)(w6h + boff);
        bf16x8 bl = *(const bf16x8*)(w6l + boff);
        acc2 = __builtin_amdgcn_mfma_f32_16x16x32_bf16(ah, bh, acc2, 0, 0, 0);
        acc2 = __builtin_amdgcn_mfma_f32_16x16x32_bf16(al, bh, acc2, 0, 0, 0);
        acc2 = __builtin_amdgcn_mfma_f32_16x16x32_bf16(ah, bl, acc2, 0, 0, 0);
    }
    if (rl < 8) {
        float bb = b6[rl];
        #pragma unroll
        for (int j = 0; j < 4; ++j) {
            float v = leakyf(acc2[j] + bb);
            C[(size_t)(m0 + cm + j) * 8 + rl] = v;
        }
    }
}

// BN finalize -> s=rstd*g, t=b-mean*rstd*g
__global__ void bn_final_st(const float* __restrict__ statp, const float* __restrict__ g,
                            const float* __restrict__ bta, float* __restrict__ sb,
                            float* __restrict__ tb)
{
    int c = blockIdx.x, tid = threadIdx.x;   // 116 x 256
    float a1 = 0.f, a2 = 0.f;
    for (int i = tid; i < GX; i += 256) {
        a1 += statp[(size_t)c * GX + i];
        a2 += statp[(size_t)(116 + c) * GX + i];
    }
    __shared__ float r1[256], r2[256];
    r1[tid] = a1; r2[tid] = a2; __syncthreads();
    for (int off = 128; off > 0; off >>= 1) {
        if (tid < off) { r1[tid] += r1[tid + off]; r2[tid] += r2[tid + off]; }
        __syncthreads();
    }
    if (tid == 0) {
        float mean = r1[0] / (float)NROWS;
        float var = r2[0] / (float)NROWS - mean * mean;
        float rstd = 1.f / sqrtf(var + EPSBN);
        float s = rstd * g[c];
        sb[c] = s;
        tb[c] = bta[c] - mean * s;
    }
}

// sq[bz] = sum of 116 per-M-row sumsq partials
__global__ void sq_reduce(const float* __restrict__ rsq, float* __restrict__ sq)
{
    int i = blockIdx.x * 256 + threadIdx.x;
    if (i >= NBZ) return;
    const float* p = rsq + (size_t)i * ROIN;
    float s = 0.f;
    #pragma unroll 4
    for (int r = 0; r < ROIN; ++r) s += p[r];
    sq[i] = s;
}

// ---------------------------------------------------------------------------
// proj1 via bf16x2 MFMA, split-K
// ---------------------------------------------------------------------------
__global__ __launch_bounds__(256) void mfma_proj1(
    const float* __restrict__ A, const short* __restrict__ wt_hi,
    const short* __restrict__ wt_lo, float* __restrict__ part)
{
    const int wave = threadIdx.x >> 6, lane = threadIdx.x & 63;
    const int m0 = blockIdx.x * 64 + wave * 16;
    const int rl = lane & 15, g = lane >> 4;
    const int kbase = blockIdx.z * PCH;
    const float* Arow = A + (size_t)(m0 + rl) * FLATN;
    f32x4 acc[8];
    #pragma unroll
    for (int nf = 0; nf < 8; ++nf) acc[nf] = (f32x4){0.f,0.f,0.f,0.f};
    for (int s = 0; s < 14; ++s) {
        const int kk = kbase + s * 32 + g * 8;
        float av[8];
        if (kk + 8 <= FLATN) {
            float4 p = *(const float4*)(Arow + kk);
            float4 q = *(const float4*)(Arow + kk + 4);
            av[0]=p.x; av[1]=p.y; av[2]=p.z; av[3]=p.w;
            av[4]=q.x; av[5]=q.y; av[6]=q.z; av[7]=q.w;
        } else {
            #pragma unroll
            for (int j = 0; j < 8; ++j) av[j] = 0.f;
        }
        bf16x8 ah, al;
        #pragma unroll
        for (int j = 0; j < 8; ++j) {
            short h = f2bf(av[j]); ah[j] = h;
            al[j] = f2bf(av[j] - bf2f(h));
        }
        #pragma unroll
        for (int nf = 0; nf < 8; ++nf) {
            size_t boff = (size_t)(nf * 16 + rl) * W1LD + kk;
            bf16x8 bh = *(const bf16x8*)(wt_hi + boff);
            bf16x8 bl = *(const bf16x8*)(wt_lo + boff);
            acc[nf] = __builtin_amdgcn_mfma_f32_16x16x32_bf16(ah, bh, acc[nf], 0, 0, 0);
            acc[nf] = __builtin_amdgcn_mfma_f32_16x16x32_bf16(al, bh, acc[nf], 0, 0, 0);
            acc[nf] = __builtin_amdgcn_mfma_f32_16x16x32_bf16(ah, bl, acc[nf], 0, 0, 0);
        }
    }
    float* Cb = part + (size_t)blockIdx.z * NBZ * ROIN;
    const int cm = g * 4;
    #pragma unroll
    for (int nf = 0; nf < 8; ++nf) {
        int n = nf * 16 + rl;
        if (n < ROIN) {
            #pragma unroll
            for (int j = 0; j < 4; ++j)
                Cb[(size_t)(m0 + cm + j) * ROIN + n] = acc[nf][j];
        }
    }
}

// split-K reduce for proj1 (+bias +relu)
__global__ void proj_reduce(const float* __restrict__ ppart,
                            const float* __restrict__ bias, float* __restrict__ t1)
{
    int e = blockIdx.x * 256 + threadIdx.x;
    if (e >= NBZ * ROIN) return;
    int n = e % ROIN;
    float s = 0.f;
    for (int z = 0; z < PZ; ++z) s += ppart[(size_t)z * NBZ * ROIN + e];
    t1[e] = fmaxf(s + bias[n], 0.f);
}

// ---------------------------------------------------------------------------
// fp32 GEMM NT (sim = pn @ pn^T, K=116), symmetric mirror write
// ---------------------------------------------------------------------------
__global__ __launch_bounds__(256) void gemm_nt_sym(
    const float* __restrict__ A, float* __restrict__ C, int M, int K, float scale)
{
    if ((int)blockIdx.y < (int)blockIdx.x) return;
    __shared__ float As[16][65];
    __shared__ float Bs[16][65];
    const int tid = threadIdx.x;
    const int m0 = blockIdx.x * 64;
    const int n0 = blockIdx.y * 64;
    const int tm4 = (tid >> 4) * 4;
    const int tn4 = (tid & 15) * 4;
    const int rA  = tid >> 2;
    const int kbA = (tid & 3) * 4;
    float acc[4][4] = {};
    for (int kt = 0; kt < K; kt += 16) {
        int kg = kt + kbA;
        if (kg + 4 <= K) {
            float4 va = *(const float4*)(A + (size_t)(m0 + rA) * K + kg);
            As[kbA + 0][rA] = va.x; As[kbA + 1][rA] = va.y;
            As[kbA + 2][rA] = va.z; As[kbA + 3][rA] = va.w;
            float4 vb = *(const float4*)(A + (size_t)(n0 + rA) * K + kg);
            Bs[kbA + 0][rA] = vb.x; Bs[kbA + 1][rA] = vb.y;
            Bs[kbA + 2][rA] = vb.z; Bs[kbA + 3][rA] = vb.w;
        } else {
            #pragma unroll
            for (int kk = 0; kk < 4; ++kk) {
                int kgg = kg + kk;
                As[kbA + kk][rA] = (kgg < K) ? A[(size_t)(m0 + rA) * K + kgg] : 0.f;
                Bs[kbA + kk][rA] = (kgg < K) ? A[(size_t)(n0 + rA) * K + kgg] : 0.f;
            }
        }
        __syncthreads();
        #pragma unroll
        for (int k = 0; k < 16; ++k) {
            float a[4], b[4];
            #pragma unroll
            for (int i = 0; i < 4; ++i) a[i] = As[k][tm4 + i];
            #pragma unroll
            for (int j = 0; j < 4; ++j) b[j] = Bs[k][tn4 + j];
            #pragma unroll
            for (int i = 0; i < 4; ++i)
                #pragma unroll
                for (int j = 0; j < 4; ++j)
                    acc[i][j] = fmaf(a[i], b[j], acc[i][j]);
        }
        __syncthreads();
    }
    #pragma unroll
    for (int i = 0; i < 4; ++i) {
        int m = m0 + tm4 + i;
        #pragma unroll
        for (int j = 0; j < 4; ++j) {
            int n = n0 + tn4 + j;
            float v = acc[i][j] * scale;
            C[(size_t)m * M + n] = v;
            C[(size_t)n * M + m] = v;
        }
    }
}

// ---------------------------------------------------------------------------
// Gram via bf16 MFMA: 128x128 tile, 4 waves each owning a 64x64 quadrant
// (16 independent MFMAs / k-step, prefetch next k-step's fragments).
// ---------------------------------------------------------------------------
__global__ __launch_bounds__(256) void gram_mfma(
    const short* __restrict__ Xh, float* __restrict__ gpart)
{
    const int bx = blockIdx.x, by = blockIdx.y;
    if (by < bx) return;
    const int tri = bx * 8 - (bx * (bx - 1)) / 2 + (by - bx);
    const int k0 = blockIdx.z * GRAMKS;
    const int k1 = min(FLATN, k0 + GRAMKS);
    const int wave = threadIdx.x >> 6, lane = threadIdx.x & 63;
    const int wr = wave >> 1, wc = wave & 1;
    const int row = lane & 15, koff = (lane >> 4) * 8;
    const short* Ap[4]; const short* Bp[4];
    #pragma unroll
    for (int i = 0; i < 4; ++i) {
        Ap[i] = Xh + (size_t)(bx * 128 + wr * 64 + i * 16 + row) * FLATN;
        Bp[i] = Xh + (size_t)(by * 128 + wc * 64 + i * 16 + row) * FLATN;
    }
    f32x4 acc[4][4];
    #pragma unroll
    for (int i = 0; i < 4; ++i)
        #pragma unroll
        for (int j = 0; j < 4; ++j) acc[i][j] = (f32x4){0.f,0.f,0.f,0.f};
    const bf16x8 zf = {0,0,0,0,0,0,0,0};
    bf16x8 a[4], b[4];
    {
        int kk = k0 + koff;
        bool ok = (kk + 8 <= k1);
        #pragma unroll
        for (int i = 0; i < 4; ++i) {
            a[i] = ok ? *(const bf16x8*)(Ap[i] + kk) : zf;
            b[i] = ok ? *(const bf16x8*)(Bp[i] + kk) : zf;
        }
    }
    for (int k = k0 + 32; k < k1; k += 32) {
        bf16x8 an[4], bn[4];
        int kk = k + koff;
        bool ok = (kk + 8 <= k1);
        #pragma unroll
        for (int i = 0; i < 4; ++i) {
            an[i] = ok ? *(const bf16x8*)(Ap[i] + kk) : zf;
            bn[i] = ok ? *(const bf16x8*)(Bp[i] + kk) : zf;
        }
        #pragma unroll
        for (int i = 0; i < 4; ++i)
            #pragma unroll
            for (int j = 0; j < 4; ++j)
                acc[i][j] = __builtin_amdgcn_mfma_f32_16x16x32_bf16(a[i], b[j], acc[i][j], 0, 0, 0);
        #pragma unroll
        for (int i = 0; i < 4; ++i) { a[i] = an[i]; b[i] = bn[i]; }
    }
    #pragma unroll
    for (int i = 0; i < 4; ++i)
        #pragma unroll
        for (int j = 0; j < 4; ++j)
            acc[i][j] = __builtin_amdgcn_mfma_f32_16x16x32_bf16(a[i], b[j], acc[i][j], 0, 0, 0);
    float* Cb = gpart + ((size_t)blockIdx.z * NTRI + tri) * 16384;
    const int crow = (lane >> 4) * 4;
    const int ccol = lane & 15;
    #pragma unroll
    for (int i = 0; i < 4; ++i) {
        #pragma unroll
        for (int j = 0; j < 4; ++j) {
            int cl = wc * 64 + j * 16 + ccol;
            #pragma unroll
            for (int jj = 0; jj < 4; ++jj) {
                int rl2 = wr * 64 + i * 16 + crow + jj;
                Cb[(size_t)rl2 * 128 + cl] = acc[i][j][jj];
            }
        }
    }
}

// reduce GRAMZ packed-tri partials -> G (with mirror)
__global__ void gram_reduce_p(const float* __restrict__ gpart, float* __restrict__ G)
{
    const int t = blockIdx.x;   // 0..35
    int bx = 0;
    #pragma unroll
    for (int b = 1; b < 8; ++b) {
        int base = b * 8 - (b * (b - 1)) / 2;
        if (base <= t) bx = b;
    }
    const int by = t - (bx * 8 - (bx * (bx - 1)) / 2) + bx;
    int e = blockIdx.y * 1024 + threadIdx.x * 4;
    float sx = 0.f, sy = 0.f, sz = 0.f, sw = 0.f;
    for (int z = 0; z < GRAMZ; ++z) {
        float4 v = *(const float4*)(gpart + ((size_t)z * NTRI + t) * 16384 + e);
        sx += v.x; sy += v.y; sz += v.z; sw += v.w;
    }
    int i = bx * 128 + (e >> 7), j = by * 128 + (e & 127);
    float4 o = {sx, sy, sz, sw};
    *(float4*)(G + ((size_t)i << 10) + j) = o;
    G[((size_t)(j + 0) << 10) + i] = sx;
    G[((size_t)(j + 1) << 10) + i] = sy;
    G[((size_t)(j + 2) << 10) + i] = sz;
    G[((size_t)(j + 3) << 10) + i] = sw;
}

// p[1024,116] -> row L2-normalize in place
__global__ void rownorm(float* __restrict__ p)
{
    int row = blockIdx.x, t = threadIdx.x;   // 128 threads
    __shared__ float red[128];
    float x = 0.f, v = 0.f;
    if (t < ROIN) { x = p[row * ROIN + t]; v = x * x; }
    red[t] = v; __syncthreads();
    for (int off = 64; off > 0; off >>= 1) { if (t < off) red[t] += red[t + off]; __syncthreads(); }
    float inv = 1.f / sqrtf(red[0]);
    if (t < ROIN) p[row * ROIN + t] = x * inv;
}

// global min/max of sim
__global__ void minmax_part(const float* __restrict__ sim, float* __restrict__ mm)
{
    int t = threadIdx.x, b = blockIdx.x;   // 512 x 256
    float mn = 1e30f, mx = -1e30f;
    for (size_t i = (size_t)b * 256 + t; i < 1048576u; i += 512u * 256u) {
        float v = sim[i]; mn = fminf(mn, v); mx = fmaxf(mx, v);
    }
    __shared__ float smn[256], smx[256];
    smn[t] = mn; smx[t] = mx; __syncthreads();
    for (int off = 128; off > 0; off >>= 1) {
        if (t < off) { smn[t] = fminf(smn[t], smn[t + off]); smx[t] = fmaxf(smx[t], smx[t + off]); }
        __syncthreads();
    }
    if (t == 0) { mm[b] = smn[0]; mm[512 + b] = smx[0]; }
}
__global__ void minmax_final(const float* __restrict__ mm, float* __restrict__ fscal)
{
    int t = threadIdx.x;   // 512 threads
    __shared__ float smn[512], smx[512];
    smn[t] = mm[t]; smx[t] = mm[512 + t]; __syncthreads();
    for (int off = 256; off > 0; off >>= 1) {
        if (t < off) { smn[t] = fminf(smn[t], smn[t + off]); smx[t] = fmaxf(smx[t], smx[t + off]); }
        __syncthreads();
    }
    if (t == 0) { fscal[0] = smn[0]; fscal[1] = smx[0]; }
}

// labels[i] = argmax(site[i,0..3]) (first max)
__global__ void labels_k(const int* __restrict__ site, int* __restrict__ labels)
{
    int i = blockIdx.x * 256 + threadIdx.x;
    if (i >= NBZ) return;
    int best = site[4 * i], bi = 0;
    #pragma unroll
    for (int k = 1; k < 4; ++k) { int v = site[4 * i + k]; if (v > best) { best = v; bi = k; } }
    labels[i] = bi;
}

__global__ void rowcnt_k(const int* __restrict__ labels, int* __restrict__ rowcnt)
{
    int i = blockIdx.x * 256 + threadIdx.x;
    if (i >= NBZ) return;
    int li = labels[i], c = 0;
    for (int j = 0; j < NBZ; ++j) c += (labels[j] == li);
    rowcnt[i] = c;
}

// exclusive scan of per-row positive counts; iscal[0]=npos, iscal[1]=m
__global__ __launch_bounds__(1024) void scan_k(const int* __restrict__ rowcnt,
                                               int* __restrict__ rowoff, int* __restrict__ iscal)
{
    __shared__ int s[1024];
    int t = threadIdx.x;
    int c = rowcnt[t];
    s[t] = c; __syncthreads();
    for (int off = 1; off < 1024; off <<= 1) {
        int v = (t >= off) ? s[t - off] : 0;
        __syncthreads();
        s[t] += v;
        __syncthreads();
    }
    rowoff[t] = s[t] - c;
    if (t == 1023) {
        int npos = s[1023];
        int nneg = 1024 * 1024 - npos;
        iscal[0] = npos;
        iscal[1] = (npos < nneg) ? npos : nneg;
    }
}

// scatter sim values to rank-paired pos/neg arrays
__global__ void pair_scatter(const int* __restrict__ labels, const int* __restrict__ rowoff,
                             const int* __restrict__ iscal, const float* __restrict__ sim,
                             float* __restrict__ posval, float* __restrict__ negval)
{
    int row = blockIdx.x, t = threadIdx.x;
    int m = iscal[1];
    int li = labels[row];
    int j0 = t * 4;
    int eq[4]; int c = 0;
    #pragma unroll
    for (int kk = 0; kk < 4; ++kk) { eq[kk] = (labels[j0 + kk] == li); c += eq[kk]; }
    __shared__ int s[256];
    s[t] = c; __syncthreads();
    for (int off = 1; off < 256; off <<= 1) {
        int v = (t >= off) ? s[t - off] : 0;
        __syncthreads();
        s[t] += v;
        __syncthreads();
    }
    int r = rowoff[row] + s[t] - c;
    size_t base = (size_t)row * 1024;
    #pragma unroll
    for (int kk = 0; kk < 4; ++kk) {
        size_t f = base + j0 + kk;
        float v = sim[f];
        if (eq[kk]) { if (r < m) posval[r] = v; r++; }
        else { long nr = (long)f - r; if (nr < m) negval[nr] = v; }
    }
}

__global__ void loss_part(const float* __restrict__ posval, const float* __restrict__ negval,
                          const int* __restrict__ iscal, float* __restrict__ lp)
{
    int m = iscal[1];
    int t = threadIdx.x, b = blockIdx.x;   // 1024 x 256
    float s = 0.f;
    for (int k = b * 256 + t; k < m; k += 1024 * 256) {
        float d = negval[k] - posval[k];
        s += fmaxf(d, 0.f) + log1pf(expf(-fabsf(d)));
    }
    __shared__ float red[256];
    red[t] = s; __syncthreads();
    for (int off = 128; off > 0; off >>= 1) { if (t < off) red[t] += red[t + off]; __syncthreads(); }
    if (t == 0) lp[b] = red[0];
}

__global__ void loss_final(const float* __restrict__ lp, const int* __restrict__ iscal,
                           float* __restrict__ outp)
{
    int t = threadIdx.x;   // 256
    double s = 0.0;
    for (int k = t; k < 1024; k += 256) s += (double)lp[k];
    __shared__ double red[256];
    red[t] = s; __syncthreads();
    for (int off = 128; off > 0; off >>= 1) { if (t < off) red[t] += red[t + off]; __syncthreads(); }
    if (t == 0) {
        int m = iscal[1]; if (m < 1) m = 1;
        outp[0] = (float)(red[0] / (double)m);
    }
}

// dist (in place over G): total * (cond ? 0.9 : 0.1)
__global__ void dist_k(float* __restrict__ G, const float* __restrict__ sim,
                       const float* __restrict__ sq, const int* __restrict__ ages,
                       const int* __restrict__ genders, const float* __restrict__ fscal)
{
    size_t e = (size_t)blockIdx.x * 256 + threadIdx.x;
    int i = (int)(e >> 10), j = (int)(e & 1023);
    float smin = fscal[0], smax = fscal[1];
    float sn = (sim[e] - smin) / (smax - smin);
    float d2 = fmaxf(sq[i] + sq[j] - 2.f * G[e], 0.f);
    float fs = expf(-ALPHA * sqrtf(d2));
    float total = fs * (1.f - sn) + sn;
    int da = ages[i] - ages[j]; if (da < 0) da = -da;
    bool cond = (da <= BETAC) && (genders[i] == genders[j]);
    G[e] = total * (cond ? ACOEF : 1.f - ACOEF);
}

// row-wise top-8 (ties -> lower index)
__global__ void topk8(const float* __restrict__ dist, float* __restrict__ topv, int* __restrict__ topi)
{
    int row = blockIdx.x, t = threadIdx.x;
    __shared__ float sv[1024];
    __shared__ float rv[256];
    __shared__ int   ri[256];
    for (int j = t; j < 1024; j += 256) sv[j] = dist[(size_t)row * 1024 + j];
    __syncthreads();
    for (int k = 0; k < 8; ++k) {
        float bv = -1e30f; int bi = 1 << 20;
        for (int j = t; j < 1024; j += 256) {
            float x = sv[j];
            if (x > bv || (x == bv && j < bi)) { bv = x; bi = j; }
        }
        rv[t] = bv; ri[t] = bi;
        __syncthreads();
        for (int s = 128; s > 0; s >>= 1) {
            if (t < s) {
                float ov = rv[t + s]; int oi = ri[t + s];
                if (ov > rv[t] || (ov == rv[t] && oi < ri[t])) { rv[t] = ov; ri[t] = oi; }
            }
            __syncthreads();
        }
        if (t == 0) { topv[row * 8 + k] = rv[0]; topi[row * 8 + k] = ri[0]; sv[ri[0]] = -1e30f; }
        __syncthreads();
    }
}

// out[row,:] = sum_k vals[row,k] * feat[idx[row,k], :]
// FOLD: apply per-column BN affine on the fly: out = s_c * acc + wsum * t_c
template<int FOLD>
__global__ void adj_gather(const float* __restrict__ vals, const int* __restrict__ idxs,
                           const float* __restrict__ feat, const float* __restrict__ sb,
                           const float* __restrict__ tb, float* __restrict__ out)
{
    int row = blockIdx.x, t = threadIdx.x;
    __shared__ float v[8]; __shared__ int ix[8];
    if (t < 8) { v[t] = vals[row * 8 + t]; ix[t] = idxs[row * 8 + t]; }
    __syncthreads();
    float vv[8]; const float4* fp[8];
    #pragma unroll
    for (int k = 0; k < 8; ++k) { vv[k] = v[k]; fp[k] = (const float4*)(feat + (size_t)ix[k] * FLATN); }
    float wsum = 0.f;
    if (FOLD) {
        #pragma unroll
        for (int k = 0; k < 8; ++k) wsum += vv[k];
    }
    float4* op = (float4*)(out + (size_t)row * FLATN);
    for (int c = t; c < FLATN / 4; c += 256) {
        float4 acc = {0.f, 0.f, 0.f, 0.f};
        #pragma unroll
        for (int k = 0; k < 8; ++k) {
            float4 x = fp[k][c];
            acc.x = fmaf(vv[k], x.x, acc.x);
            acc.y = fmaf(vv[k], x.y, acc.y);
            acc.z = fmaf(vv[k], x.z, acc.z);
            acc.w = fmaf(vv[k], x.w, acc.w);
        }
        if (FOLD) {
            int cb = (c * 4) % ROIN;
            acc.x = sb[cb]     * acc.x + wsum * tb[cb];
            acc.y = sb[cb + 1] * acc.y + wsum * tb[cb + 1];
            acc.z = sb[cb + 2] * acc.z + wsum * tb[cb + 2];
            acc.w = sb[cb + 3] * acc.w + wsum * tb[cb + 3];
        }
        op[c] = acc;
    }
}

// bn3: per-ROI-channel stats over (N=1024, L=8); writes final output
__global__ void bn3_k(const float* __restrict__ X, const float* __restrict__ g,
                      const float* __restrict__ bta, float* __restrict__ out)
{
    int c = blockIdx.x, t = threadIdx.x;   // 116 x 256
    float s = 0.f, s2 = 0.f;
    for (int k = t; k < 8192; k += 256) {
        int n = k >> 3, l = k & 7;
        float v = X[(size_t)n * 928 + c * 8 + l];
        s += v; s2 += v * v;
    }
    __shared__ float rs[256], rs2[256];
    rs[t] = s; rs2[t] = s2; __syncthreads();
    for (int off = 128; off > 0; off >>= 1) {
        if (t < off) { rs[t] += rs[t + off]; rs2[t] += rs2[t + off]; }
        __syncthreads();
    }
    __shared__ float sm, sr;
    if (t == 0) {
        float mean = rs[0] / 8192.f;
        float var = rs2[0] / 8192.f - mean * mean;
        sm = mean; sr = 1.f / sqrtf(var + EPSBN);
    }
    __syncthreads();
    float mean = sm, rstd = sr, gg = g[c], bb = bta[c];
    for (int k = t; k < 8192; k += 256) {
        int n = k >> 3, l = k & 7;
        size_t idx = (size_t)n * 928 + c * 8 + l;
        out[idx] = (X[idx] - mean) * rstd * gg + bb;
    }
}

// ---------------------------------------------------------------------------
extern "C" void kernel_launch(void* const* d_in, const int* in_sizes, int n_in,
                              void* d_out, int out_size, void* d_ws, size_t ws_size,
                              hipStream_t stream)
{
    const float* x        = (const float*)d_in[0];
    const float* pseudo   = (const float*)d_in[1];
    const int*   ages     = (const int*)d_in[2];
    const int*   genders  = (const int*)d_in[3];
    const int*   site     = (const int*)d_in[4];
    const float* fc_p_w   = (const float*)d_in[5];
    const float* fc_p_b   = (const float*)d_in[6];
    const float* proj_w1  = (const float*)d_in[7];
    const float* proj_b1  = (const float*)d_in[8];
    const float* proj_w2  = (const float*)d_in[9];
    const float* proj_b2  = (const float*)d_in[10];
    const float* gcn_w1   = (const float*)d_in[11];
    const float* gcn_b1   = (const float*)d_in[12];
    const float* gcn_w2   = (const float*)d_in[13];
    const float* gcn_b2   = (const float*)d_in[14];
    const float* gcn1_w   = (const float*)d_in[15];
    const float* gcn1_b   = (const float*)d_in[16];
    const float* gcn2_w1  = (const float*)d_in[17];
    const float* gcn2_b1  = (const float*)d_in[18];
    const float* gcn2_w2  = (const float*)d_in[19];
    const float* gcn2_b2  = (const float*)d_in[20];
    const float* bn1_g    = (const float*)d_in[21];
    const float* bn1_b    = (const float*)d_in[22];
    const float* bn2_g    = (const float*)d_in[23];
    const float* bn2_b    = (const float*)d_in[24];
    const float* bn3_g    = (const float*)d_in[25];
    const float* bn3_b    = (const float*)d_in[26];
    float* dout = (float*)d_out;

    char* w = (char*)d_ws;
    size_t off = 0;
    auto carve = [&](size_t bytes) { char* p = w + off; off = (off + bytes + 255) & ~(size_t)255; return p; };
    float* xf     = (float*)carve((size_t)NROWS * ROIN * 4);   // 55.1 MB
    float* hA     = (float*)carve((size_t)NROWS * ROIN * 4);   // 55.1 MB
    float* hB     = (float*)carve((size_t)NROWS * ROIN * 4);   // 55.1 MB
    float* G      = (float*)carve(1048576u * 4);
    float* simb   = (float*)carve(1048576u * 4);
    float* t1     = (float*)carve((size_t)NBZ * ROIN * 4);
    float* pbuf   = (float*)carve((size_t)NBZ * ROIN * 4);
    float* sq     = (float*)carve(4096);
    float* rsq    = (float*)carve((size_t)NROWS * 4);
    int*   labels = (int*)carve(4096);
    int*   rowcnt = (int*)carve(4096);
    int*   rowoff = (int*)carve(4096);
    int*   iscal  = (int*)carve(256);
    float* fscal  = (float*)carve(256);
    float* posval = (float*)carve(524288u * 4);
    float* negval = (float*)carve(524288u * 4);
    float* lpart  = (float*)carve(4096);
    float* mmpart = (float*)carve(4096);
    float* topv   = (float*)carve(32768);
    int*   topi   = (int*)carve(32768);
    float* statp  = (float*)carve((size_t)232 * GX * 4);
    float* sbA    = (float*)carve(512);
    float* tbA    = (float*)carve(512);
    float* sbB    = (float*)carve(512);
    float* tbB    = (float*)carve(512);
    short* wt1_hi = (short*)carve((size_t)128 * W1LD * 2);
    short* wt1_lo = (short*)carve((size_t)128 * W1LD * 2);
    short* wts    = (short*)carve((size_t)7 * 2 * 16384 * 2);
    // aliases into dead phases:
    float* ppart  = hA;            // proj1 partials (14.7 MB), dead after proj_reduce
    float* gpart  = hA;            // Gram packed-tri partials (20*36*64KB = 47.2 MB)
    short* xfh    = (short*)hB;    // bf16 xf (27.5 MB), dead before mfma_gemm2 writes hB

    auto wt_hi = [&](int i) { return wts + (size_t)i * 2 * 16384; };
    auto wt_lo = [&](int i) { return wts + (size_t)i * 2 * 16384 + 16384; };

    // 0. weight pretranspose + hi/lo split
    wt1_conv<<<(128 * W1LD) / 256, 256, 0, stream>>>(proj_w1, wt1_hi, wt1_lo);
    wt_conv<<<64, 256, 0, stream>>>(fc_p_w,   wt_hi(0), wt_lo(0), 116, 116);
    wt_conv<<<64, 256, 0, stream>>>(proj_w2,  wt_hi(1), wt_lo(1), 116, 116);
    wt_conv<<<64, 256, 0, stream>>>(gcn_w1,   wt_hi(2), wt_lo(2), 116, 116);
    wt_conv<<<64, 256, 0, stream>>>(gcn_w2,   wt_hi(3), wt_lo(3), 116, 116);
    wt_conv<<<64, 256, 0, stream>>>(gcn1_w,   wt_hi(4), wt_lo(4), 116, 116);
    wt_conv<<<64, 256, 0, stream>>>(gcn2_w1,  wt_hi(5), wt_lo(5), 116, 64);
    wt_conv<<<64, 256, 0, stream>>>(gcn2_w2,  wt_hi(6), wt_lo(6), 64, 8);

    // 1. xf = x + leaky(pseudo @ fc_p_w + b); also emit bf16 xfh + row-sumsq partials
    mfma_gemm<4, 8, 1><<<GX, 256, 0, stream>>>(pseudo, wt_hi(0), wt_lo(0), fc_p_b, x, xf,
                                               xfh, rsq, nullptr, NROWS, ROIN, ROIN);
    sq_reduce<<<4, 256, 0, stream>>>(rsq, sq);

    // 2. proj head
    mfma_proj1<<<dim3(16, 1, PZ), 256, 0, stream>>>(xf, wt1_hi, wt1_lo, ppart);
    proj_reduce<<<(NBZ * ROIN + 255) / 256, 256, 0, stream>>>(ppart, proj_b1, t1);
    mfma_gemm<1, 8, 0><<<16, 256, 0, stream>>>(t1, wt_hi(1), wt_lo(1), proj_b2, nullptr, pbuf,
                                               nullptr, nullptr, nullptr, NBZ, ROIN, ROIN);
    rownorm<<<NBZ, 128, 0, stream>>>(pbuf);

    // 3. sim = (pn @ pn^T) / TEMP
    gemm_nt_sym<<<dim3(16, 16, 1), 256, 0, stream>>>(pbuf, simb, NBZ, ROIN, 1.f / 0.07f);

    // 4. contrastive loss
    labels_k<<<4, 256, 0, stream>>>(site, labels);
    rowcnt_k<<<4, 256, 0, stream>>>(labels, rowcnt);
    scan_k<<<1, 1024, 0, stream>>>(rowcnt, rowoff, iscal);
    pair_scatter<<<NBZ, 256, 0, stream>>>(labels, rowoff, iscal, simb, posval, negval);
    loss_part<<<1024, 256, 0, stream>>>(posval, negval, iscal, lpart);
    loss_final<<<1, 256, 0, stream>>>(lpart, iscal, dout + (size_t)NBZ * ROIN * 8);

    // 5. sim min/max, Gram, dist, top-k
    minmax_part<<<512, 256, 0, stream>>>(simb, mmpart);
    minmax_final<<<1, 512, 0, stream>>>(mmpart, fscal);
    gram_mfma<<<dim3(8, 8, GRAMZ), 256, 0, stream>>>(xfh, gpart);
    gram_reduce_p<<<dim3(NTRI, 16), 256, 0, stream>>>(gpart, G);
    dist_k<<<4096, 256, 0, stream>>>(G, simb, sq, ages, genders, fscal);
    topk8<<<NBZ, 256, 0, stream>>>(G, topv, topi);

    // 6. GCN stack (gathers + fused GEMM pairs; BN stats fused, apply folded)
    adj_gather<0><<<NBZ, 256, 0, stream>>>(topv, topi, xf, nullptr, nullptr, hA);
    mfma_gemm2<<<GX, 256, 0, stream>>>(hA, wt_hi(2), wt_lo(2), gcn_b1,
                                       wt_hi(3), wt_lo(3), gcn_b2, hB, statp);
    bn_final_st<<<116, 256, 0, stream>>>(statp, bn1_g, bn1_b, sbA, tbA);

    adj_gather<1><<<NBZ, 256, 0, stream>>>(topv, topi, hB, sbA, tbA, hA);
    mfma_gemm<3, 8, 2><<<GX, 256, 0, stream>>>(hA, wt_hi(4), wt_lo(4), gcn1_b, nullptr, hB,
                                               nullptr, nullptr, statp, NROWS, ROIN, ROIN);
    bn_final_st<<<116, 256, 0, stream>>>(statp, bn2_g, bn2_b, sbB, tbB);

    adj_gather<1><<<NBZ, 256, 0, stream>>>(topv, topi, hB, sbB, tbB, hA);
    mfma_gemm45<<<GX, 256, 0, stream>>>(hA, wt_hi(5), wt_lo(5), gcn2_b1,
                                        wt_hi(6), wt_lo(6), gcn2_b2, hB);

    // 7. bn3 -> d_out
    bn3_k<<<116, 256, 0, stream>>>(hB, bn3_g, bn3_b, dout);
}

// Round 6
// 761.921 us; speedup vs baseline: 2.7129x; 1.1561x over previous
//
#include <hip/hip_runtime.h>
#include <math.h>

#define ROIN 116
#define NBZ 1024
#define FLATN 13456
#define NROWS (NBZ*ROIN)   // 118784
#define ALPHA 0.1f
#define ACOEF 0.9f
#define BETAC 2
#define EPSBN 1e-5f
#define PZ 31              // proj1 split-K chunks
#define PCH 448            // proj1 K-chunk
#define W1LD 14336         // padded K for transposed proj_w1
#define GX 1856            // NROWS/64
#define GRAMZ 20
#define GRAMKS 680
#define NTRI 36            // upper-tri 128x128 tiles of 8x8 grid

typedef __attribute__((ext_vector_type(8))) short bf16x8;
typedef __attribute__((ext_vector_type(4))) float f32x4;

__device__ __forceinline__ float leakyf(float v){ return v >= 0.f ? v : 0.2f*v; }

__device__ __forceinline__ short f2bf(float f){
    unsigned u = __builtin_bit_cast(unsigned, f);
    unsigned r = u + 0x7fffu + ((u >> 16) & 1u);   // RNE
    return (short)(r >> 16);
}
__device__ __forceinline__ float bf2f(short h){
    unsigned u = ((unsigned)(unsigned short)h) << 16;
    return __builtin_bit_cast(float, u);
}

// ---------------------------------------------------------------------------
// Weight pretranspose + bf16 hi/lo split. Small weights -> WT[128][128].
// ---------------------------------------------------------------------------
__global__ void wt_conv(const float* __restrict__ W, short* __restrict__ hi,
                        short* __restrict__ lo, int K, int N)
{
    int idx = blockIdx.x * 256 + threadIdx.x;   // 16384
    int n = idx >> 7, k = idx & 127;
    float v = (n < N && k < K) ? W[(size_t)k * N + n] : 0.f;
    short h = f2bf(v);
    hi[idx] = h;
    lo[idx] = f2bf(v - bf2f(h));
}

// proj_w1 [13456,116] -> WT1[128][14336] hi/lo
__global__ void wt1_conv(const float* __restrict__ W, short* __restrict__ hi,
                         short* __restrict__ lo)
{
    int idx = blockIdx.x * 256 + threadIdx.x;
    int n = idx / W1LD, k = idx - n * W1LD;
    float v = (n < ROIN && k < FLATN) ? W[(size_t)k * ROIN + n] : 0.f;
    short h = f2bf(v);
    hi[idx] = h;
    lo[idx] = f2bf(v - bf2f(h));
}

// ---------------------------------------------------------------------------
// bf16x2 MFMA GEMM, K in (96,128] (always 116 here), LDS-staged weights.
// whi/wlo padded to [128][136] so ds_read_b128 frag reads are bank-conflict-
// free (8 consecutive lanes -> start-bank stride 4, distinct).
// EPI: 1 bias, 3 leaky(bias), 4 X + leaky(bias)
// XTRA: 0 none; 1 also bf16 C + per-row sumsq partials; 2 BN column stats
// ---------------------------------------------------------------------------
template<int EPI, int NF, int XTRA>
__global__ __launch_bounds__(256) void mfma_gemm_w(
    const float* __restrict__ A, const short* __restrict__ wt_hi,
    const short* __restrict__ wt_lo, const float* __restrict__ bias,
    const float* __restrict__ X, float* __restrict__ C,
    short* __restrict__ bfout, float* __restrict__ rsq, float* __restrict__ statp,
    int M, int N, int K)
{
    __shared__ short whi[128][136];
    __shared__ short wlo[128][136];
    __shared__ float st[(XTRA == 2) ? 4 : 1][2][128];
    const int tid = threadIdx.x;
    {   // stage weights: thread t copies half-row (64 shorts) of row t>>1
        int r = tid >> 1, h = tid & 1;
        const short* sh = wt_hi + r * 128 + h * 64;
        const short* sl = wt_lo + r * 128 + h * 64;
        #pragma unroll
        for (int i = 0; i < 8; ++i) {
            *(bf16x8*)(&whi[r][h * 64 + i * 8]) = *(const bf16x8*)(sh + i * 8);
            *(bf16x8*)(&wlo[r][h * 64 + i * 8]) = *(const bf16x8*)(sl + i * 8);
        }
    }
    __syncthreads();
    const int wave = tid >> 6, lane = tid & 63;
    const int m0 = blockIdx.x * 64 + wave * 16;
    const int rl = lane & 15, g = lane >> 4;
    const float* Arow = A + (size_t)(m0 + rl) * K;
    // preload the lane's full A segment (4 k-steps x 8 floats), all in flight
    float av[4][8];
    #pragma unroll
    for (int s = 0; s < 4; ++s) {
        const int kk = s * 32 + g * 8;
        if (kk + 8 <= K) {
            float4 p = *(const float4*)(Arow + kk);
            float4 q = *(const float4*)(Arow + kk + 4);
            av[s][0]=p.x; av[s][1]=p.y; av[s][2]=p.z; av[s][3]=p.w;
            av[s][4]=q.x; av[s][5]=q.y; av[s][6]=q.z; av[s][7]=q.w;
        } else if (kk + 4 <= K) {
            float4 p = *(const float4*)(Arow + kk);
            av[s][0]=p.x; av[s][1]=p.y; av[s][2]=p.z; av[s][3]=p.w;
            av[s][4]=0.f; av[s][5]=0.f; av[s][6]=0.f; av[s][7]=0.f;
        } else {
            #pragma unroll
            for (int j = 0; j < 8; ++j) av[s][j] = 0.f;
        }
    }
    f32x4 acc[NF];
    #pragma unroll
    for (int nf = 0; nf < NF; ++nf) acc[nf] = (f32x4){0.f,0.f,0.f,0.f};
    #pragma unroll
    for (int s = 0; s < 4; ++s) {
        const int kk = s * 32 + g * 8;
        bf16x8 ah, al;
        #pragma unroll
        for (int j = 0; j < 8; ++j) {
            short h = f2bf(av[s][j]); ah[j] = h;
            al[j] = f2bf(av[s][j] - bf2f(h));
        }
        #pragma unroll
        for (int nf = 0; nf < NF; ++nf) {
            const bf16x8 bh = *(const bf16x8*)(&whi[nf * 16 + rl][kk]);
            const bf16x8 bl = *(const bf16x8*)(&wlo[nf * 16 + rl][kk]);
            acc[nf] = __builtin_amdgcn_mfma_f32_16x16x32_bf16(ah, bh, acc[nf], 0, 0, 0);
            acc[nf] = __builtin_amdgcn_mfma_f32_16x16x32_bf16(al, bh, acc[nf], 0, 0, 0);
            acc[nf] = __builtin_amdgcn_mfma_f32_16x16x32_bf16(ah, bl, acc[nf], 0, 0, 0);
        }
    }
    const int cm = g * 4;
    float rq[4] = {0.f, 0.f, 0.f, 0.f};
    #pragma unroll
    for (int nf = 0; nf < NF; ++nf) {
        int n = nf * 16 + rl;
        float c1 = 0.f, c2 = 0.f;
        if (n < N) {
            float bb = bias[n];
            #pragma unroll
            for (int j = 0; j < 4; ++j) {
                int m = m0 + cm + j;
                size_t idx = (size_t)m * N + n;
                float v = acc[nf][j] + bb;
                if (EPI == 3) v = leakyf(v);
                else if (EPI == 4) v = X[idx] + leakyf(v);
                C[idx] = v;
                if (XTRA == 1) { bfout[idx] = f2bf(v); rq[j] += v * v; }
                if (XTRA == 2) { c1 += v; c2 += v * v; }
            }
        }
        if (XTRA == 2) {
            c1 += __shfl_xor(c1, 16); c1 += __shfl_xor(c1, 32);
            c2 += __shfl_xor(c2, 16); c2 += __shfl_xor(c2, 32);
            if (lane < 16) { st[wave][0][n & 127] = c1; st[wave][1][n & 127] = c2; }
        }
    }
    if (XTRA == 1) {
        #pragma unroll
        for (int j = 0; j < 4; ++j) {
            rq[j] += __shfl_xor(rq[j], 1);
            rq[j] += __shfl_xor(rq[j], 2);
            rq[j] += __shfl_xor(rq[j], 4);
            rq[j] += __shfl_xor(rq[j], 8);
        }
        if (rl == 0) {
            #pragma unroll
            for (int j = 0; j < 4; ++j) rsq[m0 + cm + j] = rq[j];
        }
    }
    if (XTRA == 2) {
        __syncthreads();
        if (tid < 232) {
            int sel = tid < 116 ? 0 : 1;
            int c = sel ? tid - 116 : tid;
            float s = st[0][sel][c] + st[1][sel][c] + st[2][sel][c] + st[3][sel][c];
            statp[(size_t)(sel * 116 + c) * GX + blockIdx.x] = s;
        }
    }
}

// ---------------------------------------------------------------------------
// Fused pair (LDS weights): C[NROWS][8] = leaky( leaky(A@W5+b5) @ W6 + b6 )
// w5 N=64 -> only rows 0..63 staged; w6 rows 0..15.
// ---------------------------------------------------------------------------
__global__ __launch_bounds__(256) void mfma_gemm45_w(
    const float* __restrict__ A,
    const short* __restrict__ w5h, const short* __restrict__ w5l,
    const float* __restrict__ b5,
    const short* __restrict__ w6h, const short* __restrict__ w6l,
    const float* __restrict__ b6,
    float* __restrict__ C)
{
    __shared__ short s5h[64][136], s5l[64][136];
    __shared__ short s6h[16][136], s6l[16][136];
    __shared__ float c1s[4][16][76];
    const int tid = threadIdx.x;
    {
        int r = tid >> 2, q = tid & 3;   // 64 rows x 4 quarters (32 shorts)
        const short* sh = w5h + r * 128 + q * 32;
        const short* sl = w5l + r * 128 + q * 32;
        #pragma unroll
        for (int i = 0; i < 4; ++i) {
            *(bf16x8*)(&s5h[r][q * 32 + i * 8]) = *(const bf16x8*)(sh + i * 8);
            *(bf16x8*)(&s5l[r][q * 32 + i * 8]) = *(const bf16x8*)(sl + i * 8);
        }
        if (tid < 64) {
            int r6 = tid >> 2, q6 = tid & 3;
            const short* sh6 = w6h + r6 * 128 + q6 * 32;
            const short* sl6 = w6l + r6 * 128 + q6 * 32;
            #pragma unroll
            for (int i = 0; i < 4; ++i) {
                *(bf16x8*)(&s6h[r6][q6 * 32 + i * 8]) = *(const bf16x8*)(sh6 + i * 8);
                *(bf16x8*)(&s6l[r6][q6 * 32 + i * 8]) = *(const bf16x8*)(sl6 + i * 8);
            }
        }
    }
    __syncthreads();
    const int wave = tid >> 6, lane = tid & 63;
    const int m0 = blockIdx.x * 64 + wave * 16;
    const int rl = lane & 15, g = lane >> 4;
    const float* Arow = A + (size_t)(m0 + rl) * ROIN;
    float av[4][8];
    #pragma unroll
    for (int s = 0; s < 4; ++s) {
        const int kk = s * 32 + g * 8;
        if (kk + 8 <= ROIN) {
            float4 p = *(const float4*)(Arow + kk);
            float4 q = *(const float4*)(Arow + kk + 4);
            av[s][0]=p.x; av[s][1]=p.y; av[s][2]=p.z; av[s][3]=p.w;
            av[s][4]=q.x; av[s][5]=q.y; av[s][6]=q.z; av[s][7]=q.w;
        } else if (kk + 4 <= ROIN) {
            float4 p = *(const float4*)(Arow + kk);
            av[s][0]=p.x; av[s][1]=p.y; av[s][2]=p.z; av[s][3]=p.w;
            av[s][4]=0.f; av[s][5]=0.f; av[s][6]=0.f; av[s][7]=0.f;
        } else {
            #pragma unroll
            for (int j = 0; j < 8; ++j) av[s][j] = 0.f;
        }
    }
    f32x4 acc[4];
    #pragma unroll
    for (int nf = 0; nf < 4; ++nf) acc[nf] = (f32x4){0.f,0.f,0.f,0.f};
    #pragma unroll
    for (int s = 0; s < 4; ++s) {
        const int kk = s * 32 + g * 8;
        bf16x8 ah, al;
        #pragma unroll
        for (int j = 0; j < 8; ++j) {
            short h = f2bf(av[s][j]); ah[j] = h;
            al[j] = f2bf(av[s][j] - bf2f(h));
        }
        #pragma unroll
        for (int nf = 0; nf < 4; ++nf) {
            const bf16x8 bh = *(const bf16x8*)(&s5h[nf * 16 + rl][kk]);
            const bf16x8 bl = *(const bf16x8*)(&s5l[nf * 16 + rl][kk]);
            acc[nf] = __builtin_amdgcn_mfma_f32_16x16x32_bf16(ah, bh, acc[nf], 0, 0, 0);
            acc[nf] = __builtin_amdgcn_mfma_f32_16x16x32_bf16(al, bh, acc[nf], 0, 0, 0);
            acc[nf] = __builtin_amdgcn_mfma_f32_16x16x32_bf16(ah, bl, acc[nf], 0, 0, 0);
        }
    }
    const int cm = g * 4;
    #pragma unroll
    for (int nf = 0; nf < 4; ++nf) {
        int n = nf * 16 + rl;   // < 64
        float bb = b5[n];
        #pragma unroll
        for (int j = 0; j < 4; ++j)
            c1s[wave][cm + j][n] = leakyf(acc[nf][j] + bb);
    }
    // phase 2: K=64, N=8 (wave-local LDS; compiler orders via lgkmcnt)
    f32x4 acc2 = {0.f,0.f,0.f,0.f};
    #pragma unroll
    for (int s = 0; s < 2; ++s) {
        const int kk = s * 32 + g * 8;
        float4 p = *(const float4*)(&c1s[wave][rl][kk]);
        float4 q = *(const float4*)(&c1s[wave][rl][kk + 4]);
        float a2[8] = {p.x, p.y, p.z, p.w, q.x, q.y, q.z, q.w};
        bf16x8 ah, al;
        #pragma unroll
        for (int j = 0; j < 8; ++j) {
            short h = f2bf(a2[j]); ah[j] = h;
            al[j] = f2bf(a2[j] - bf2f(h));
        }
        const bf16x8 bh = *(const bf16x8*)(&s6h[rl][kk]);
        const bf16x8 bl = *(const bf16x8*)(&s6l[rl][kk]);
        acc2 = __builtin_amdgcn_mfma_f32_16x16x32_bf16(ah, bh, acc2, 0, 0, 0);
        acc2 = __builtin_amdgcn_mfma_f32_16x16x32_bf16(al, bh, acc2, 0, 0, 0);
        acc2 = __builtin_amdgcn_mfma_f32_16x16x32_bf16(ah, bl, acc2, 0, 0, 0);
    }
    if (rl < 8) {
        float bb = b6[rl];
        #pragma unroll
        for (int j = 0; j < 4; ++j) {
            float v = leakyf(acc2[j] + bb);
            C[(size_t)(m0 + cm + j) * 8 + rl] = v;
        }
    }
}

// BN finalize -> s=rstd*g, t=b-mean*rstd*g
__global__ void bn_final_st(const float* __restrict__ statp, const float* __restrict__ g,
                            const float* __restrict__ bta, float* __restrict__ sb,
                            float* __restrict__ tb)
{
    int c = blockIdx.x, tid = threadIdx.x;   // 116 x 256
    float a1 = 0.f, a2 = 0.f;
    for (int i = tid; i < GX; i += 256) {
        a1 += statp[(size_t)c * GX + i];
        a2 += statp[(size_t)(116 + c) * GX + i];
    }
    __shared__ float r1[256], r2[256];
    r1[tid] = a1; r2[tid] = a2; __syncthreads();
    for (int off = 128; off > 0; off >>= 1) {
        if (tid < off) { r1[tid] += r1[tid + off]; r2[tid] += r2[tid + off]; }
        __syncthreads();
    }
    if (tid == 0) {
        float mean = r1[0] / (float)NROWS;
        float var = r2[0] / (float)NROWS - mean * mean;
        float rstd = 1.f / sqrtf(var + EPSBN);
        float s = rstd * g[c];
        sb[c] = s;
        tb[c] = bta[c] - mean * s;
    }
}

// sq[bz] = sum of 116 per-M-row sumsq partials
__global__ void sq_reduce(const float* __restrict__ rsq, float* __restrict__ sq)
{
    int i = blockIdx.x * 256 + threadIdx.x;
    if (i >= NBZ) return;
    const float* p = rsq + (size_t)i * ROIN;
    float s = 0.f;
    #pragma unroll 4
    for (int r = 0; r < ROIN; ++r) s += p[r];
    sq[i] = s;
}

// ---------------------------------------------------------------------------
// proj1 via bf16x2 MFMA, split-K
// ---------------------------------------------------------------------------
__global__ __launch_bounds__(256) void mfma_proj1(
    const float* __restrict__ A, const short* __restrict__ wt_hi,
    const short* __restrict__ wt_lo, float* __restrict__ part)
{
    const int wave = threadIdx.x >> 6, lane = threadIdx.x & 63;
    const int m0 = blockIdx.x * 64 + wave * 16;
    const int rl = lane & 15, g = lane >> 4;
    const int kbase = blockIdx.z * PCH;
    const float* Arow = A + (size_t)(m0 + rl) * FLATN;
    f32x4 acc[8];
    #pragma unroll
    for (int nf = 0; nf < 8; ++nf) acc[nf] = (f32x4){0.f,0.f,0.f,0.f};
    for (int s = 0; s < 14; ++s) {
        const int kk = kbase + s * 32 + g * 8;
        float av[8];
        if (kk + 8 <= FLATN) {
            float4 p = *(const float4*)(Arow + kk);
            float4 q = *(const float4*)(Arow + kk + 4);
            av[0]=p.x; av[1]=p.y; av[2]=p.z; av[3]=p.w;
            av[4]=q.x; av[5]=q.y; av[6]=q.z; av[7]=q.w;
        } else {
            #pragma unroll
            for (int j = 0; j < 8; ++j) av[j] = 0.f;
        }
        bf16x8 ah, al;
        #pragma unroll
        for (int j = 0; j < 8; ++j) {
            short h = f2bf(av[j]); ah[j] = h;
            al[j] = f2bf(av[j] - bf2f(h));
        }
        #pragma unroll
        for (int nf = 0; nf < 8; ++nf) {
            size_t boff = (size_t)(nf * 16 + rl) * W1LD + kk;
            bf16x8 bh = *(const bf16x8*)(wt_hi + boff);
            bf16x8 bl = *(const bf16x8*)(wt_lo + boff);
            acc[nf] = __builtin_amdgcn_mfma_f32_16x16x32_bf16(ah, bh, acc[nf], 0, 0, 0);
            acc[nf] = __builtin_amdgcn_mfma_f32_16x16x32_bf16(al, bh, acc[nf], 0, 0, 0);
            acc[nf] = __builtin_amdgcn_mfma_f32_16x16x32_bf16(ah, bl, acc[nf], 0, 0, 0);
        }
    }
    float* Cb = part + (size_t)blockIdx.z * NBZ * ROIN;
    const int cm = g * 4;
    #pragma unroll
    for (int nf = 0; nf < 8; ++nf) {
        int n = nf * 16 + rl;
        if (n < ROIN) {
            #pragma unroll
            for (int j = 0; j < 4; ++j)
                Cb[(size_t)(m0 + cm + j) * ROIN + n] = acc[nf][j];
        }
    }
}

// split-K reduce for proj1 (+bias +relu)
__global__ void proj_reduce(const float* __restrict__ ppart,
                            const float* __restrict__ bias, float* __restrict__ t1)
{
    int e = blockIdx.x * 256 + threadIdx.x;
    if (e >= NBZ * ROIN) return;
    int n = e % ROIN;
    float s = 0.f;
    for (int z = 0; z < PZ; ++z) s += ppart[(size_t)z * NBZ * ROIN + e];
    t1[e] = fmaxf(s + bias[n], 0.f);
}

// ---------------------------------------------------------------------------
// fp32 GEMM NT (sim = pn @ pn^T, K=116), symmetric mirror write
// ---------------------------------------------------------------------------
__global__ __launch_bounds__(256) void gemm_nt_sym(
    const float* __restrict__ A, float* __restrict__ C, int M, int K, float scale)
{
    if ((int)blockIdx.y < (int)blockIdx.x) return;
    __shared__ float As[16][65];
    __shared__ float Bs[16][65];
    const int tid = threadIdx.x;
    const int m0 = blockIdx.x * 64;
    const int n0 = blockIdx.y * 64;
    const int tm4 = (tid >> 4) * 4;
    const int tn4 = (tid & 15) * 4;
    const int rA  = tid >> 2;
    const int kbA = (tid & 3) * 4;
    float acc[4][4] = {};
    for (int kt = 0; kt < K; kt += 16) {
        int kg = kt + kbA;
        if (kg + 4 <= K) {
            float4 va = *(const float4*)(A + (size_t)(m0 + rA) * K + kg);
            As[kbA + 0][rA] = va.x; As[kbA + 1][rA] = va.y;
            As[kbA + 2][rA] = va.z; As[kbA + 3][rA] = va.w;
            float4 vb = *(const float4*)(A + (size_t)(n0 + rA) * K + kg);
            Bs[kbA + 0][rA] = vb.x; Bs[kbA + 1][rA] = vb.y;
            Bs[kbA + 2][rA] = vb.z; Bs[kbA + 3][rA] = vb.w;
        } else {
            #pragma unroll
            for (int kk = 0; kk < 4; ++kk) {
                int kgg = kg + kk;
                As[kbA + kk][rA] = (kgg < K) ? A[(size_t)(m0 + rA) * K + kgg] : 0.f;
                Bs[kbA + kk][rA] = (kgg < K) ? A[(size_t)(n0 + rA) * K + kgg] : 0.f;
            }
        }
        __syncthreads();
        #pragma unroll
        for (int k = 0; k < 16; ++k) {
            float a[4], b[4];
            #pragma unroll
            for (int i = 0; i < 4; ++i) a[i] = As[k][tm4 + i];
            #pragma unroll
            for (int j = 0; j < 4; ++j) b[j] = Bs[k][tn4 + j];
            #pragma unroll
            for (int i = 0; i < 4; ++i)
                #pragma unroll
                for (int j = 0; j < 4; ++j)
                    acc[i][j] = fmaf(a[i], b[j], acc[i][j]);
        }
        __syncthreads();
    }
    #pragma unroll
    for (int i = 0; i < 4; ++i) {
        int m = m0 + tm4 + i;
        #pragma unroll
        for (int j = 0; j < 4; ++j) {
            int n = n0 + tn4 + j;
            float v = acc[i][j] * scale;
            C[(size_t)m * M + n] = v;
            C[(size_t)n * M + m] = v;
        }
    }
}

// ---------------------------------------------------------------------------
// Gram via bf16 MFMA: 128x128 tile, 4 waves each owning a 64x64 quadrant
// ---------------------------------------------------------------------------
__global__ __launch_bounds__(256) void gram_mfma(
    const short* __restrict__ Xh, float* __restrict__ gpart)
{
    const int bx = blockIdx.x, by = blockIdx.y;
    if (by < bx) return;
    const int tri = bx * 8 - (bx * (bx - 1)) / 2 + (by - bx);
    const int k0 = blockIdx.z * GRAMKS;
    const int k1 = min(FLATN, k0 + GRAMKS);
    const int wave = threadIdx.x >> 6, lane = threadIdx.x & 63;
    const int wr = wave >> 1, wc = wave & 1;
    const int row = lane & 15, koff = (lane >> 4) * 8;
    const short* Ap[4]; const short* Bp[4];
    #pragma unroll
    for (int i = 0; i < 4; ++i) {
        Ap[i] = Xh + (size_t)(bx * 128 + wr * 64 + i * 16 + row) * FLATN;
        Bp[i] = Xh + (size_t)(by * 128 + wc * 64 + i * 16 + row) * FLATN;
    }
    f32x4 acc[4][4];
    #pragma unroll
    for (int i = 0; i < 4; ++i)
        #pragma unroll
        for (int j = 0; j < 4; ++j) acc[i][j] = (f32x4){0.f,0.f,0.f,0.f};
    const bf16x8 zf = {0,0,0,0,0,0,0,0};
    bf16x8 a[4], b[4];
    {
        int kk = k0 + koff;
        bool ok = (kk + 8 <= k1);
        #pragma unroll
        for (int i = 0; i < 4; ++i) {
            a[i] = ok ? *(const bf16x8*)(Ap[i] + kk) : zf;
            b[i] = ok ? *(const bf16x8*)(Bp[i] + kk) : zf;
        }
    }
    for (int k = k0 + 32; k < k1; k += 32) {
        bf16x8 an[4], bn[4];
        int kk = k + koff;
        bool ok = (kk + 8 <= k1);
        #pragma unroll
        for (int i = 0; i < 4; ++i) {
            an[i] = ok ? *(const bf16x8*)(Ap[i] + kk) : zf;
            bn[i] = ok ? *(const bf16x8*)(Bp[i] + kk) : zf;
        }
        #pragma unroll
        for (int i = 0; i < 4; ++i)
            #pragma unroll
            for (int j = 0; j < 4; ++j)
                acc[i][j] = __builtin_amdgcn_mfma_f32_16x16x32_bf16(a[i], b[j], acc[i][j], 0, 0, 0);
        #pragma unroll
        for (int i = 0; i < 4; ++i) { a[i] = an[i]; b[i] = bn[i]; }
    }
    #pragma unroll
    for (int i = 0; i < 4; ++i)
        #pragma unroll
        for (int j = 0; j < 4; ++j)
            acc[i][j] = __builtin_amdgcn_mfma_f32_16x16x32_bf16(a[i], b[j], acc[i][j], 0, 0, 0);
    float* Cb = gpart + ((size_t)blockIdx.z * NTRI + tri) * 16384;
    const int crow = (lane >> 4) * 4;
    const int ccol = lane & 15;
    #pragma unroll
    for (int i = 0; i < 4; ++i) {
        #pragma unroll
        for (int j = 0; j < 4; ++j) {
            int cl = wc * 64 + j * 16 + ccol;
            #pragma unroll
            for (int jj = 0; jj < 4; ++jj) {
                int rl2 = wr * 64 + i * 16 + crow + jj;
                Cb[(size_t)rl2 * 128 + cl] = acc[i][j][jj];
            }
        }
    }
}

// reduce GRAMZ packed-tri partials -> G (with mirror)
__global__ void gram_reduce_p(const float* __restrict__ gpart, float* __restrict__ G)
{
    const int t = blockIdx.x;   // 0..35
    int bx = 0;
    #pragma unroll
    for (int b = 1; b < 8; ++b) {
        int base = b * 8 - (b * (b - 1)) / 2;
        if (base <= t) bx = b;
    }
    const int by = t - (bx * 8 - (bx * (bx - 1)) / 2) + bx;
    int e = blockIdx.y * 1024 + threadIdx.x * 4;
    float sx = 0.f, sy = 0.f, sz = 0.f, sw = 0.f;
    for (int z = 0; z < GRAMZ; ++z) {
        float4 v = *(const float4*)(gpart + ((size_t)z * NTRI + t) * 16384 + e);
        sx += v.x; sy += v.y; sz += v.z; sw += v.w;
    }
    int i = bx * 128 + (e >> 7), j = by * 128 + (e & 127);
    float4 o = {sx, sy, sz, sw};
    *(float4*)(G + ((size_t)i << 10) + j) = o;
    G[((size_t)(j + 0) << 10) + i] = sx;
    G[((size_t)(j + 1) << 10) + i] = sy;
    G[((size_t)(j + 2) << 10) + i] = sz;
    G[((size_t)(j + 3) << 10) + i] = sw;
}

// p[1024,116] -> row L2-normalize in place
__global__ void rownorm(float* __restrict__ p)
{
    int row = blockIdx.x, t = threadIdx.x;   // 128 threads
    __shared__ float red[128];
    float x = 0.f, v = 0.f;
    if (t < ROIN) { x = p[row * ROIN + t]; v = x * x; }
    red[t] = v; __syncthreads();
    for (int off = 64; off > 0; off >>= 1) { if (t < off) red[t] += red[t + off]; __syncthreads(); }
    float inv = 1.f / sqrtf(red[0]);
    if (t < ROIN) p[row * ROIN + t] = x * inv;
}

// global min/max of sim
__global__ void minmax_part(const float* __restrict__ sim, float* __restrict__ mm)
{
    int t = threadIdx.x, b = blockIdx.x;   // 512 x 256
    float mn = 1e30f, mx = -1e30f;
    for (size_t i = (size_t)b * 256 + t; i < 1048576u; i += 512u * 256u) {
        float v = sim[i]; mn = fminf(mn, v); mx = fmaxf(mx, v);
    }
    __shared__ float smn[256], smx[256];
    smn[t] = mn; smx[t] = mx; __syncthreads();
    for (int off = 128; off > 0; off >>= 1) {
        if (t < off) { smn[t] = fminf(smn[t], smn[t + off]); smx[t] = fmaxf(smx[t], smx[t + off]); }
        __syncthreads();
    }
    if (t == 0) { mm[b] = smn[0]; mm[512 + b] = smx[0]; }
}
__global__ void minmax_final(const float* __restrict__ mm, float* __restrict__ fscal)
{
    int t = threadIdx.x;   // 512 threads
    __shared__ float smn[512], smx[512];
    smn[t] = mm[t]; smx[t] = mm[512 + t]; __syncthreads();
    for (int off = 256; off > 0; off >>= 1) {
        if (t < off) { smn[t] = fminf(smn[t], smn[t + off]); smx[t] = fmaxf(smx[t], smx[t + off]); }
        __syncthreads();
    }
    if (t == 0) { fscal[0] = smn[0]; fscal[1] = smx[0]; }
}

// labels[i] = argmax(site[i,0..3]) (first max)
__global__ void labels_k(const int* __restrict__ site, int* __restrict__ labels)
{
    int i = blockIdx.x * 256 + threadIdx.x;
    if (i >= NBZ) return;
    int best = site[4 * i], bi = 0;
    #pragma unroll
    for (int k = 1; k < 4; ++k) { int v = site[4 * i + k]; if (v > best) { best = v; bi = k; } }
    labels[i] = bi;
}

__global__ void rowcnt_k(const int* __restrict__ labels, int* __restrict__ rowcnt)
{
    int i = blockIdx.x * 256 + threadIdx.x;
    if (i >= NBZ) return;
    int li = labels[i], c = 0;
    for (int j = 0; j < NBZ; ++j) c += (labels[j] == li);
    rowcnt[i] = c;
}

// exclusive scan of per-row positive counts; iscal[0]=npos, iscal[1]=m
__global__ __launch_bounds__(1024) void scan_k(const int* __restrict__ rowcnt,
                                               int* __restrict__ rowoff, int* __restrict__ iscal)
{
    __shared__ int s[1024];
    int t = threadIdx.x;
    int c = rowcnt[t];
    s[t] = c; __syncthreads();
    for (int off = 1; off < 1024; off <<= 1) {
        int v = (t >= off) ? s[t - off] : 0;
        __syncthreads();
        s[t] += v;
        __syncthreads();
    }
    rowoff[t] = s[t] - c;
    if (t == 1023) {
        int npos = s[1023];
        int nneg = 1024 * 1024 - npos;
        iscal[0] = npos;
        iscal[1] = (npos < nneg) ? npos : nneg;
    }
}

// scatter sim values to rank-paired pos/neg arrays
__global__ void pair_scatter(const int* __restrict__ labels, const int* __restrict__ rowoff,
                             const int* __restrict__ iscal, const float* __restrict__ sim,
                             float* __restrict__ posval, float* __restrict__ negval)
{
    int row = blockIdx.x, t = threadIdx.x;
    int m = iscal[1];
    int li = labels[row];
    int j0 = t * 4;
    int eq[4]; int c = 0;
    #pragma unroll
    for (int kk = 0; kk < 4; ++kk) { eq[kk] = (labels[j0 + kk] == li); c += eq[kk]; }
    __shared__ int s[256];
    s[t] = c; __syncthreads();
    for (int off = 1; off < 256; off <<= 1) {
        int v = (t >= off) ? s[t - off] : 0;
        __syncthreads();
        s[t] += v;
        __syncthreads();
    }
    int r = rowoff[row] + s[t] - c;
    size_t base = (size_t)row * 1024;
    #pragma unroll
    for (int kk = 0; kk < 4; ++kk) {
        size_t f = base + j0 + kk;
        float v = sim[f];
        if (eq[kk]) { if (r < m) posval[r] = v; r++; }
        else { long nr = (long)f - r; if (nr < m) negval[nr] = v; }
    }
}

__global__ void loss_part(const float* __restrict__ posval, const float* __restrict__ negval,
                          const int* __restrict__ iscal, float* __restrict__ lp)
{
    int m = iscal[1];
    int t = threadIdx.x, b = blockIdx.x;   // 1024 x 256
    float s = 0.f;
    for (int k = b * 256 + t; k < m; k += 1024 * 256) {
        float d = negval[k] - posval[k];
        s += fmaxf(d, 0.f) + log1pf(expf(-fabsf(d)));
    }
    __shared__ float red[256];
    red[t] = s; __syncthreads();
    for (int off = 128; off > 0; off >>= 1) { if (t < off) red[t] += red[t + off]; __syncthreads(); }
    if (t == 0) lp[b] = red[0];
}

__global__ void loss_final(const float* __restrict__ lp, const int* __restrict__ iscal,
                           float* __restrict__ outp)
{
    int t = threadIdx.x;   // 256
    double s = 0.0;
    for (int k = t; k < 1024; k += 256) s += (double)lp[k];
    __shared__ double red[256];
    red[t] = s; __syncthreads();
    for (int off = 128; off > 0; off >>= 1) { if (t < off) red[t] += red[t + off]; __syncthreads(); }
    if (t == 0) {
        int m = iscal[1]; if (m < 1) m = 1;
        outp[0] = (float)(red[0] / (double)m);
    }
}

// dist (in place over G): total * (cond ? 0.9 : 0.1)
__global__ void dist_k(float* __restrict__ G, const float* __restrict__ sim,
                       const float* __restrict__ sq, const int* __restrict__ ages,
                       const int* __restrict__ genders, const float* __restrict__ fscal)
{
    size_t e = (size_t)blockIdx.x * 256 + threadIdx.x;
    int i = (int)(e >> 10), j = (int)(e & 1023);
    float smin = fscal[0], smax = fscal[1];
    float sn = (sim[e] - smin) / (smax - smin);
    float d2 = fmaxf(sq[i] + sq[j] - 2.f * G[e], 0.f);
    float fs = expf(-ALPHA * sqrtf(d2));
    float total = fs * (1.f - sn) + sn;
    int da = ages[i] - ages[j]; if (da < 0) da = -da;
    bool cond = (da <= BETAC) && (genders[i] == genders[j]);
    G[e] = total * (cond ? ACOEF : 1.f - ACOEF);
}

// row-wise top-8 (ties -> lower index)
__global__ void topk8(const float* __restrict__ dist, float* __restrict__ topv, int* __restrict__ topi)
{
    int row = blockIdx.x, t = threadIdx.x;
    __shared__ float sv[1024];
    __shared__ float rv[256];
    __shared__ int   ri[256];
    for (int j = t; j < 1024; j += 256) sv[j] = dist[(size_t)row * 1024 + j];
    __syncthreads();
    for (int k = 0; k < 8; ++k) {
        float bv = -1e30f; int bi = 1 << 20;
        for (int j = t; j < 1024; j += 256) {
            float x = sv[j];
            if (x > bv || (x == bv && j < bi)) { bv = x; bi = j; }
        }
        rv[t] = bv; ri[t] = bi;
        __syncthreads();
        for (int s = 128; s > 0; s >>= 1) {
            if (t < s) {
                float ov = rv[t + s]; int oi = ri[t + s];
                if (ov > rv[t] || (ov == rv[t] && oi < ri[t])) { rv[t] = ov; ri[t] = oi; }
            }
            __syncthreads();
        }
        if (t == 0) { topv[row * 8 + k] = rv[0]; topi[row * 8 + k] = ri[0]; sv[ri[0]] = -1e30f; }
        __syncthreads();
    }
}

// out[row,:] = sum_k vals[row,k] * feat[idx[row,k], :]
// FOLD: apply per-column BN affine on the fly: out = s_c * acc + wsum * t_c
template<int FOLD>
__global__ void adj_gather(const float* __restrict__ vals, const int* __restrict__ idxs,
                           const float* __restrict__ feat, const float* __restrict__ sb,
                           const float* __restrict__ tb, float* __restrict__ out)
{
    int row = blockIdx.x, t = threadIdx.x;
    __shared__ float v[8]; __shared__ int ix[8];
    if (t < 8) { v[t] = vals[row * 8 + t]; ix[t] = idxs[row * 8 + t]; }
    __syncthreads();
    float vv[8]; const float4* fp[8];
    #pragma unroll
    for (int k = 0; k < 8; ++k) { vv[k] = v[k]; fp[k] = (const float4*)(feat + (size_t)ix[k] * FLATN); }
    float wsum = 0.f;
    if (FOLD) {
        #pragma unroll
        for (int k = 0; k < 8; ++k) wsum += vv[k];
    }
    float4* op = (float4*)(out + (size_t)row * FLATN);
    for (int c = t; c < FLATN / 4; c += 256) {
        float4 acc = {0.f, 0.f, 0.f, 0.f};
        #pragma unroll
        for (int k = 0; k < 8; ++k) {
            float4 x = fp[k][c];
            acc.x = fmaf(vv[k], x.x, acc.x);
            acc.y = fmaf(vv[k], x.y, acc.y);
            acc.z = fmaf(vv[k], x.z, acc.z);
            acc.w = fmaf(vv[k], x.w, acc.w);
        }
        if (FOLD) {
            int cb = (c * 4) % ROIN;
            acc.x = sb[cb]     * acc.x + wsum * tb[cb];
            acc.y = sb[cb + 1] * acc.y + wsum * tb[cb + 1];
            acc.z = sb[cb + 2] * acc.z + wsum * tb[cb + 2];
            acc.w = sb[cb + 3] * acc.w + wsum * tb[cb + 3];
        }
        op[c] = acc;
    }
}

// bn3: per-ROI-channel stats over (N=1024, L=8); writes final output
__global__ void bn3_k(const float* __restrict__ X, const float* __restrict__ g,
                      const float* __restrict__ bta, float* __restrict__ out)
{
    int c = blockIdx.x, t = threadIdx.x;   // 116 x 256
    float s = 0.f, s2 = 0.f;
    for (int k = t; k < 8192; k += 256) {
        int n = k >> 3, l = k & 7;
        float v = X[(size_t)n * 928 + c * 8 + l];
        s += v; s2 += v * v;
    }
    __shared__ float rs[256], rs2[256];
    rs[t] = s; rs2[t] = s2; __syncthreads();
    for (int off = 128; off > 0; off >>= 1) {
        if (t < off) { rs[t] += rs[t + off]; rs2[t] += rs2[t + off]; }
        __syncthreads();
    }
    __shared__ float sm, sr;
    if (t == 0) {
        float mean = rs[0] / 8192.f;
        float var = rs2[0] / 8192.f - mean * mean;
        sm = mean; sr = 1.f / sqrtf(var + EPSBN);
    }
    __syncthreads();
    float mean = sm, rstd = sr, gg = g[c], bb = bta[c];
    for (int k = t; k < 8192; k += 256) {
        int n = k >> 3, l = k & 7;
        size_t idx = (size_t)n * 928 + c * 8 + l;
        out[idx] = (X[idx] - mean) * rstd * gg + bb;
    }
}

// ---------------------------------------------------------------------------
extern "C" void kernel_launch(void* const* d_in, const int* in_sizes, int n_in,
                              void* d_out, int out_size, void* d_ws, size_t ws_size,
                              hipStream_t stream)
{
    const float* x        = (const float*)d_in[0];
    const float* pseudo   = (const float*)d_in[1];
    const int*   ages     = (const int*)d_in[2];
    const int*   genders  = (const int*)d_in[3];
    const int*   site     = (const int*)d_in[4];
    const float* fc_p_w   = (const float*)d_in[5];
    const float* fc_p_b   = (const float*)d_in[6];
    const float* proj_w1  = (const float*)d_in[7];
    const float* proj_b1  = (const float*)d_in[8];
    const float* proj_w2  = (const float*)d_in[9];
    const float* proj_b2  = (const float*)d_in[10];
    const float* gcn_w1   = (const float*)d_in[11];
    const float* gcn_b1   = (const float*)d_in[12];
    const float* gcn_w2   = (const float*)d_in[13];
    const float* gcn_b2   = (const float*)d_in[14];
    const float* gcn1_w   = (const float*)d_in[15];
    const float* gcn1_b   = (const float*)d_in[16];
    const float* gcn2_w1  = (const float*)d_in[17];
    const float* gcn2_b1  = (const float*)d_in[18];
    const float* gcn2_w2  = (const float*)d_in[19];
    const float* gcn2_b2  = (const float*)d_in[20];
    const float* bn1_g    = (const float*)d_in[21];
    const float* bn1_b    = (const float*)d_in[22];
    const float* bn2_g    = (const float*)d_in[23];
    const float* bn2_b    = (const float*)d_in[24];
    const float* bn3_g    = (const float*)d_in[25];
    const float* bn3_b    = (const float*)d_in[26];
    float* dout = (float*)d_out;

    char* w = (char*)d_ws;
    size_t off = 0;
    auto carve = [&](size_t bytes) { char* p = w + off; off = (off + bytes + 255) & ~(size_t)255; return p; };
    float* xf     = (float*)carve((size_t)NROWS * ROIN * 4);   // 55.1 MB
    float* hA     = (float*)carve((size_t)NROWS * ROIN * 4);   // 55.1 MB
    float* hB     = (float*)carve((size_t)NROWS * ROIN * 4);   // 55.1 MB
    float* G      = (float*)carve(1048576u * 4);
    float* simb   = (float*)carve(1048576u * 4);
    float* t1     = (float*)carve((size_t)NBZ * ROIN * 4);
    float* pbuf   = (float*)carve((size_t)NBZ * ROIN * 4);
    float* sq     = (float*)carve(4096);
    float* rsq    = (float*)carve((size_t)NROWS * 4);
    int*   labels = (int*)carve(4096);
    int*   rowcnt = (int*)carve(4096);
    int*   rowoff = (int*)carve(4096);
    int*   iscal  = (int*)carve(256);
    float* fscal  = (float*)carve(256);
    float* posval = (float*)carve(524288u * 4);
    float* negval = (float*)carve(524288u * 4);
    float* lpart  = (float*)carve(4096);
    float* mmpart = (float*)carve(4096);
    float* topv   = (float*)carve(32768);
    int*   topi   = (int*)carve(32768);
    float* statp  = (float*)carve((size_t)232 * GX * 4);
    float* sbA    = (float*)carve(512);
    float* tbA    = (float*)carve(512);
    float* sbB    = (float*)carve(512);
    float* tbB    = (float*)carve(512);
    short* wt1_hi = (short*)carve((size_t)128 * W1LD * 2);
    short* wt1_lo = (short*)carve((size_t)128 * W1LD * 2);
    short* wts    = (short*)carve((size_t)7 * 2 * 16384 * 2);
    // aliases into dead phases:
    float* ppart  = hA;            // proj1 partials (14.7 MB), dead after proj_reduce
    float* gpart  = hA;            // Gram packed-tri partials (47.2 MB)
    short* xfh    = (short*)hB;    // bf16 xf (27.5 MB), dead before gcn_w1 writes hB

    auto wt_hi = [&](int i) { return wts + (size_t)i * 2 * 16384; };
    auto wt_lo = [&](int i) { return wts + (size_t)i * 2 * 16384 + 16384; };

    // 0. weight pretranspose + hi/lo split
    wt1_conv<<<(128 * W1LD) / 256, 256, 0, stream>>>(proj_w1, wt1_hi, wt1_lo);
    wt_conv<<<64, 256, 0, stream>>>(fc_p_w,   wt_hi(0), wt_lo(0), 116, 116);
    wt_conv<<<64, 256, 0, stream>>>(proj_w2,  wt_hi(1), wt_lo(1), 116, 116);
    wt_conv<<<64, 256, 0, stream>>>(gcn_w1,   wt_hi(2), wt_lo(2), 116, 116);
    wt_conv<<<64, 256, 0, stream>>>(gcn_w2,   wt_hi(3), wt_lo(3), 116, 116);
    wt_conv<<<64, 256, 0, stream>>>(gcn1_w,   wt_hi(4), wt_lo(4), 116, 116);
    wt_conv<<<64, 256, 0, stream>>>(gcn2_w1,  wt_hi(5), wt_lo(5), 116, 64);
    wt_conv<<<64, 256, 0, stream>>>(gcn2_w2,  wt_hi(6), wt_lo(6), 64, 8);

    // 1. xf = x + leaky(pseudo @ fc_p_w + b); also emit bf16 xfh + row-sumsq partials
    mfma_gemm_w<4, 8, 1><<<GX, 256, 0, stream>>>(pseudo, wt_hi(0), wt_lo(0), fc_p_b, x, xf,
                                                 xfh, rsq, nullptr, NROWS, ROIN, ROIN);
    sq_reduce<<<4, 256, 0, stream>>>(rsq, sq);

    // 2. proj head
    mfma_proj1<<<dim3(16, 1, PZ), 256, 0, stream>>>(xf, wt1_hi, wt1_lo, ppart);
    proj_reduce<<<(NBZ * ROIN + 255) / 256, 256, 0, stream>>>(ppart, proj_b1, t1);
    mfma_gemm_w<1, 8, 0><<<16, 256, 0, stream>>>(t1, wt_hi(1), wt_lo(1), proj_b2, nullptr, pbuf,
                                                 nullptr, nullptr, nullptr, NBZ, ROIN, ROIN);
    rownorm<<<NBZ, 128, 0, stream>>>(pbuf);

    // 3. sim = (pn @ pn^T) / TEMP
    gemm_nt_sym<<<dim3(16, 16, 1), 256, 0, stream>>>(pbuf, simb, NBZ, ROIN, 1.f / 0.07f);

    // 4. contrastive loss
    labels_k<<<4, 256, 0, stream>>>(site, labels);
    rowcnt_k<<<4, 256, 0, stream>>>(labels, rowcnt);
    scan_k<<<1, 1024, 0, stream>>>(rowcnt, rowoff, iscal);
    pair_scatter<<<NBZ, 256, 0, stream>>>(labels, rowoff, iscal, simb, posval, negval);
    loss_part<<<1024, 256, 0, stream>>>(posval, negval, iscal, lpart);
    loss_final<<<1, 256, 0, stream>>>(lpart, iscal, dout + (size_t)NBZ * ROIN * 8);

    // 5. sim min/max, Gram, dist, top-k
    minmax_part<<<512, 256, 0, stream>>>(simb, mmpart);
    minmax_final<<<1, 512, 0, stream>>>(mmpart, fscal);
    gram_mfma<<<dim3(8, 8, GRAMZ), 256, 0, stream>>>(xfh, gpart);
    gram_reduce_p<<<dim3(NTRI, 16), 256, 0, stream>>>(gpart, G);
    dist_k<<<4096, 256, 0, stream>>>(G, simb, sq, ages, genders, fscal);
    topk8<<<NBZ, 256, 0, stream>>>(G, topv, topi);

    // 6. GCN stack (gathers; LDS-weight GEMMs; BN stats fused, apply folded)
    adj_gather<0><<<NBZ, 256, 0, stream>>>(topv, topi, xf, nullptr, nullptr, hA);
    mfma_gemm_w<3, 8, 0><<<GX, 256, 0, stream>>>(hA, wt_hi(2), wt_lo(2), gcn_b1, nullptr, hB,
                                                 nullptr, nullptr, nullptr, NROWS, ROIN, ROIN);
    mfma_gemm_w<1, 8, 2><<<GX, 256, 0, stream>>>(hB, wt_hi(3), wt_lo(3), gcn_b2, nullptr, hA,
                                                 nullptr, nullptr, statp, NROWS, ROIN, ROIN);
    bn_final_st<<<116, 256, 0, stream>>>(statp, bn1_g, bn1_b, sbA, tbA);

    adj_gather<1><<<NBZ, 256, 0, stream>>>(topv, topi, hA, sbA, tbA, hB);
    mfma_gemm_w<3, 8, 2><<<GX, 256, 0, stream>>>(hB, wt_hi(4), wt_lo(4), gcn1_b, nullptr, hA,
                                                 nullptr, nullptr, statp, NROWS, ROIN, ROIN);
    bn_final_st<<<116, 256, 0, stream>>>(statp, bn2_g, bn2_b, sbB, tbB);

    adj_gather<1><<<NBZ, 256, 0, stream>>>(topv, topi, hA, sbB, tbB, hB);
    mfma_gemm45_w<<<GX, 256, 0, stream>>>(hB, wt_hi(5), wt_lo(5), gcn2_b1,
                                          wt_hi(6), wt_lo(6), gcn2_b2, hA);

    // 7. bn3 -> d_out
    bn3_k<<<116, 256, 0, stream>>>(hA, bn3_g, bn3_b, dout);
}

// Round 8
// 752.425 us; speedup vs baseline: 2.7471x; 1.0126x over previous
//
#include <hip/hip_runtime.h>
#include <math.h>

#define ROIN 116
#define NBZ 1024
#define LDF 128            // padded ROI-row length (floats / bf16)
#define SROW (ROIN*LDF)    // 14848: padded per-sample flat row
#define NROWS (NBZ*ROIN)   // 118784
#define ALPHA 0.1f
#define ACOEF 0.9f
#define BETAC 2
#define EPSBN 1e-5f
#define PZ 29              // proj1 split-K chunks (29*512 = 14848)
#define PCH 512
#define W1LD SROW
#define GX2 928            // NROWS/128 (512-thread GEMM blocks)
#define GX45 1856          // NROWS/64 (gemm45 blocks)
#define GRAMZ 29
#define GRAMKS 512
#define NTRI 36            // upper-tri 128x128 tiles of 8x8 grid

typedef __attribute__((ext_vector_type(8))) short bf16x8;
typedef __attribute__((ext_vector_type(4))) float f32x4;

__device__ __forceinline__ float leakyf(float v){ return v >= 0.f ? v : 0.2f*v; }

__device__ __forceinline__ short f2bf(float f){
    unsigned u = __builtin_bit_cast(unsigned, f);
    unsigned r = u + 0x7fffu + ((u >> 16) & 1u);   // RNE
    return (short)(r >> 16);
}
__device__ __forceinline__ float bf2f(short h){
    unsigned u = ((unsigned)(unsigned short)h) << 16;
    return __builtin_bit_cast(float, u);
}

// ---------------------------------------------------------------------------
// Weight pretranspose + bf16 hi/lo split. Small weights -> WT[128][128].
// ---------------------------------------------------------------------------
__global__ void wt_conv(const float* __restrict__ W, short* __restrict__ hi,
                        short* __restrict__ lo, int K, int N)
{
    int idx = blockIdx.x * 256 + threadIdx.x;   // 16384
    int n = idx >> 7, k = idx & 127;
    float v = (n < N && k < K) ? W[(size_t)k * N + n] : 0.f;
    short h = f2bf(v);
    hi[idx] = h;
    lo[idx] = f2bf(v - bf2f(h));
}

// proj_w1 [13456,116] -> WT1[128][14848] hi/lo (padded-K indexing: k'=r*128+d)
__global__ void wt1_conv(const float* __restrict__ W, short* __restrict__ hi,
                         short* __restrict__ lo)
{
    int idx = blockIdx.x * 256 + threadIdx.x;   // 128*14848
    int n = idx / W1LD, k = idx - n * W1LD;
    int r = k >> 7, d = k & 127;
    float v = (n < ROIN && d < ROIN) ? W[(size_t)(r * ROIN + d) * ROIN + n] : 0.f;
    short h = f2bf(v);
    hi[idx] = h;
    lo[idx] = f2bf(v - bf2f(h));
}

// ---------------------------------------------------------------------------
// bf16x2 MFMA GEMM, 512 threads, 128 rows/block, LDS-staged weights.
// A [M][LDA] fp32 (PADK: LDA=128, zero pads, no k-guards), C [M][LDC].
// Pad cols (n>=116) written as 0 ONLY when LDC > n (i.e. padded buffers).
// EPI: 1 bias, 3 leaky(bias), 4 X + leaky(bias)   (X stride = LDA)
// XTRA: 0 none; 1 bf16 C (permuted cols: col'=rl*8+nf) + row sumsq; 2 BN stats
// ---------------------------------------------------------------------------
template<int EPI, int XTRA, bool PADK>
__global__ __launch_bounds__(512) void mfma_gemm_w(
    const float* __restrict__ A, const short* __restrict__ wt_hi,
    const short* __restrict__ wt_lo, const float* __restrict__ bias,
    const float* __restrict__ X, float* __restrict__ C,
    short* __restrict__ bfout, float* __restrict__ rsq, float* __restrict__ statp,
    int LDA, int LDC)
{
    __shared__ short whi[128][136];
    __shared__ short wlo[128][136];
    __shared__ float st[(XTRA == 2) ? 8 : 1][2][128];
    const int tid = threadIdx.x;
    {   // stage weights: thread t copies 32 shorts of row t>>2, quarter t&3
        int r = tid >> 2, q = tid & 3;
        const short* sh = wt_hi + r * 128 + q * 32;
        const short* sl = wt_lo + r * 128 + q * 32;
        #pragma unroll
        for (int i = 0; i < 4; ++i) {
            *(bf16x8*)(&whi[r][q * 32 + i * 8]) = *(const bf16x8*)(sh + i * 8);
            *(bf16x8*)(&wlo[r][q * 32 + i * 8]) = *(const bf16x8*)(sl + i * 8);
        }
    }
    __syncthreads();
    const int wave = tid >> 6, lane = tid & 63;
    const int m0 = blockIdx.x * 128 + wave * 16;
    const int rl = lane & 15, g = lane >> 4;
    const float* Arow = A + (size_t)(m0 + rl) * LDA;
    float av[4][8];
    #pragma unroll
    for (int s = 0; s < 4; ++s) {
        const int kk = s * 32 + g * 8;
        if (PADK || kk + 8 <= ROIN) {
            float4 p = *(const float4*)(Arow + kk);
            float4 q = *(const float4*)(Arow + kk + 4);
            av[s][0]=p.x; av[s][1]=p.y; av[s][2]=p.z; av[s][3]=p.w;
            av[s][4]=q.x; av[s][5]=q.y; av[s][6]=q.z; av[s][7]=q.w;
        } else if (kk + 4 <= ROIN) {
            float4 p = *(const float4*)(Arow + kk);
            av[s][0]=p.x; av[s][1]=p.y; av[s][2]=p.z; av[s][3]=p.w;
            av[s][4]=0.f; av[s][5]=0.f; av[s][6]=0.f; av[s][7]=0.f;
        } else {
            #pragma unroll
            for (int j = 0; j < 8; ++j) av[s][j] = 0.f;
        }
    }
    f32x4 acc[8];
    #pragma unroll
    for (int nf = 0; nf < 8; ++nf) acc[nf] = (f32x4){0.f,0.f,0.f,0.f};
    #pragma unroll
    for (int s = 0; s < 4; ++s) {
        const int kk = s * 32 + g * 8;
        bf16x8 ah, al;
        #pragma unroll
        for (int j = 0; j < 8; ++j) {
            short h = f2bf(av[s][j]); ah[j] = h;
            al[j] = f2bf(av[s][j] - bf2f(h));
        }
        #pragma unroll
        for (int nf = 0; nf < 8; ++nf) {
            const bf16x8 bh = *(const bf16x8*)(&whi[nf * 16 + rl][kk]);
            const bf16x8 bl = *(const bf16x8*)(&wlo[nf * 16 + rl][kk]);
            acc[nf] = __builtin_amdgcn_mfma_f32_16x16x32_bf16(ah, bh, acc[nf], 0, 0, 0);
            acc[nf] = __builtin_amdgcn_mfma_f32_16x16x32_bf16(al, bh, acc[nf], 0, 0, 0);
            acc[nf] = __builtin_amdgcn_mfma_f32_16x16x32_bf16(ah, bl, acc[nf], 0, 0, 0);
        }
    }
    const int cm = g * 4;
    float rq[4] = {0.f, 0.f, 0.f, 0.f};
    bf16x8 bfv[4];
    #pragma unroll
    for (int nf = 0; nf < 8; ++nf) {
        int n = nf * 16 + rl;
        float c1 = 0.f, c2 = 0.f;
        float bb = (n < ROIN) ? bias[n] : 0.f;
        #pragma unroll
        for (int j = 0; j < 4; ++j) {
            int m = m0 + cm + j;
            size_t idx = (size_t)m * LDC + n;
            float v = 0.f;
            if (n < ROIN) {
                v = acc[nf][j] + bb;
                if (EPI == 3) v = leakyf(v);
                else if (EPI == 4) v = X[(size_t)m * LDA + n] + leakyf(v);
            }
            if (n < LDC) C[idx] = v;   // FIX: no pad writes into tight (LDC=116) buffers
            if (XTRA == 1) { bfv[j][nf] = f2bf(v); rq[j] += v * v; }
            if (XTRA == 2) { c1 += v; c2 += v * v; }
        }
        if (XTRA == 2) {
            c1 += __shfl_xor(c1, 16); c1 += __shfl_xor(c1, 32);
            c2 += __shfl_xor(c2, 16); c2 += __shfl_xor(c2, 32);
            if (lane < 16) { st[wave][0][n & 127] = c1; st[wave][1][n & 127] = c2; }
        }
    }
    if (XTRA == 1) {
        // coalesced permuted bf16 store: row (m0+cm+j), cols' rl*8..rl*8+7
        #pragma unroll
        for (int j = 0; j < 4; ++j)
            *(bf16x8*)(&bfout[(size_t)(m0 + cm + j) * LDF + rl * 8]) = bfv[j];
        #pragma unroll
        for (int j = 0; j < 4; ++j) {
            rq[j] += __shfl_xor(rq[j], 1);
            rq[j] += __shfl_xor(rq[j], 2);
            rq[j] += __shfl_xor(rq[j], 4);
            rq[j] += __shfl_xor(rq[j], 8);
        }
        if (rl == 0) {
            #pragma unroll
            for (int j = 0; j < 4; ++j) rsq[m0 + cm + j] = rq[j];
        }
    }
    if (XTRA == 2) {
        __syncthreads();
        if (tid < 232) {
            int sel = tid < 116 ? 0 : 1;
            int c = sel ? tid - 116 : tid;
            float s = 0.f;
            #pragma unroll
            for (int wv = 0; wv < 8; ++wv) s += st[wv][sel][c];
            statp[(size_t)(sel * 116 + c) * GX2 + blockIdx.x] = s;
        }
    }
}

// ---------------------------------------------------------------------------
// Fused pair (LDS weights): C[NROWS][8] = leaky( leaky(A@W5+b5) @ W6 + b6 )
// A padded LDA=128 (zero pads).
// ---------------------------------------------------------------------------
__global__ __launch_bounds__(256) void mfma_gemm45_w(
    const float* __restrict__ A,
    const short* __restrict__ w5h, const short* __restrict__ w5l,
    const float* __restrict__ b5,
    const short* __restrict__ w6h, const short* __restrict__ w6l,
    const float* __restrict__ b6,
    float* __restrict__ C)
{
    __shared__ short s5h[64][136], s5l[64][136];
    __shared__ short s6h[16][136], s6l[16][136];
    __shared__ float c1s[4][16][76];
    const int tid = threadIdx.x;
    {
        int r = tid >> 2, q = tid & 3;   // 64 rows x 4 quarters (32 shorts)
        const short* sh = w5h + r * 128 + q * 32;
        const short* sl = w5l + r * 128 + q * 32;
        #pragma unroll
        for (int i = 0; i < 4; ++i) {
            *(bf16x8*)(&s5h[r][q * 32 + i * 8]) = *(const bf16x8*)(sh + i * 8);
            *(bf16x8*)(&s5l[r][q * 32 + i * 8]) = *(const bf16x8*)(sl + i * 8);
        }
        if (tid < 64) {
            int r6 = tid >> 2, q6 = tid & 3;
            const short* sh6 = w6h + r6 * 128 + q6 * 32;
            const short* sl6 = w6l + r6 * 128 + q6 * 32;
            #pragma unroll
            for (int i = 0; i < 4; ++i) {
                *(bf16x8*)(&s6h[r6][q6 * 32 + i * 8]) = *(const bf16x8*)(sh6 + i * 8);
                *(bf16x8*)(&s6l[r6][q6 * 32 + i * 8]) = *(const bf16x8*)(sl6 + i * 8);
            }
        }
    }
    __syncthreads();
    const int wave = tid >> 6, lane = tid & 63;
    const int m0 = blockIdx.x * 64 + wave * 16;
    const int rl = lane & 15, g = lane >> 4;
    const float* Arow = A + (size_t)(m0 + rl) * LDF;
    float av[4][8];
    #pragma unroll
    for (int s = 0; s < 4; ++s) {
        const int kk = s * 32 + g * 8;
        float4 p = *(const float4*)(Arow + kk);
        float4 q = *(const float4*)(Arow + kk + 4);
        av[s][0]=p.x; av[s][1]=p.y; av[s][2]=p.z; av[s][3]=p.w;
        av[s][4]=q.x; av[s][5]=q.y; av[s][6]=q.z; av[s][7]=q.w;
    }
    f32x4 acc[4];
    #pragma unroll
    for (int nf = 0; nf < 4; ++nf) acc[nf] = (f32x4){0.f,0.f,0.f,0.f};
    #pragma unroll
    for (int s = 0; s < 4; ++s) {
        const int kk = s * 32 + g * 8;
        bf16x8 ah, al;
        #pragma unroll
        for (int j = 0; j < 8; ++j) {
            short h = f2bf(av[s][j]); ah[j] = h;
            al[j] = f2bf(av[s][j] - bf2f(h));
        }
        #pragma unroll
        for (int nf = 0; nf < 4; ++nf) {
            const bf16x8 bh = *(const bf16x8*)(&s5h[nf * 16 + rl][kk]);
            const bf16x8 bl = *(const bf16x8*)(&s5l[nf * 16 + rl][kk]);
            acc[nf] = __builtin_amdgcn_mfma_f32_16x16x32_bf16(ah, bh, acc[nf], 0, 0, 0);
            acc[nf] = __builtin_amdgcn_mfma_f32_16x16x32_bf16(al, bh, acc[nf], 0, 0, 0);
            acc[nf] = __builtin_amdgcn_mfma_f32_16x16x32_bf16(ah, bl, acc[nf], 0, 0, 0);
        }
    }
    const int cm = g * 4;
    #pragma unroll
    for (int nf = 0; nf < 4; ++nf) {
        int n = nf * 16 + rl;   // < 64
        float bb = b5[n];
        #pragma unroll
        for (int j = 0; j < 4; ++j)
            c1s[wave][cm + j][n] = leakyf(acc[nf][j] + bb);
    }
    // phase 2: K=64, N=8 (wave-local LDS; compiler orders via lgkmcnt)
    f32x4 acc2 = {0.f,0.f,0.f,0.f};
    #pragma unroll
    for (int s = 0; s < 2; ++s) {
        const int kk = s * 32 + g * 8;
        float4 p = *(const float4*)(&c1s[wave][rl][kk]);
        float4 q = *(const float4*)(&c1s[wave][rl][kk + 4]);
        float a2[8] = {p.x, p.y, p.z, p.w, q.x, q.y, q.z, q.w};
        bf16x8 ah, al;
        #pragma unroll
        for (int j = 0; j < 8; ++j) {
            short h = f2bf(a2[j]); ah[j] = h;
            al[j] = f2bf(a2[j] - bf2f(h));
        }
        const bf16x8 bh = *(const bf16x8*)(&s6h[rl][kk]);
        const bf16x8 bl = *(const bf16x8*)(&s6l[rl][kk]);
        acc2 = __builtin_amdgcn_mfma_f32_16x16x32_bf16(ah, bh, acc2, 0, 0, 0);
        acc2 = __builtin_amdgcn_mfma_f32_16x16x32_bf16(al, bh, acc2, 0, 0, 0);
        acc2 = __builtin_amdgcn_mfma_f32_16x16x32_bf16(ah, bl, acc2, 0, 0, 0);
    }
    if (rl < 8) {
        float bb = b6[rl];
        #pragma unroll
        for (int j = 0; j < 4; ++j) {
            float v = leakyf(acc2[j] + bb);
            C[(size_t)(m0 + cm + j) * 8 + rl] = v;
        }
    }
}

// BN finalize -> s=rstd*g, t=b-mean*rstd*g
__global__ void bn_final_st(const float* __restrict__ statp, const float* __restrict__ g,
                            const float* __restrict__ bta, float* __restrict__ sb,
                            float* __restrict__ tb)
{
    int c = blockIdx.x, tid = threadIdx.x;   // 116 x 256
    float a1 = 0.f, a2 = 0.f;
    for (int i = tid; i < GX2; i += 256) {
        a1 += statp[(size_t)c * GX2 + i];
        a2 += statp[(size_t)(116 + c) * GX2 + i];
    }
    __shared__ float r1[256], r2[256];
    r1[tid] = a1; r2[tid] = a2; __syncthreads();
    for (int off = 128; off > 0; off >>= 1) {
        if (tid < off) { r1[tid] += r1[tid + off]; r2[tid] += r2[tid + off]; }
        __syncthreads();
    }
    if (tid == 0) {
        float mean = r1[0] / (float)NROWS;
        float var = r2[0] / (float)NROWS - mean * mean;
        float rstd = 1.f / sqrtf(var + EPSBN);
        float s = rstd * g[c];
        sb[c] = s;
        tb[c] = bta[c] - mean * s;
    }
}

// sq[bz] = sum of 116 per-M-row sumsq partials
__global__ void sq_reduce(const float* __restrict__ rsq, float* __restrict__ sq)
{
    int i = blockIdx.x * 256 + threadIdx.x;
    if (i >= NBZ) return;
    const float* p = rsq + (size_t)i * ROIN;
    float s = 0.f;
    #pragma unroll 4
    for (int r = 0; r < ROIN; ++r) s += p[r];
    sq[i] = s;
}

// ---------------------------------------------------------------------------
// proj1 via bf16x2 MFMA, split-K over padded xf [1024][14848]
// ---------------------------------------------------------------------------
__global__ __launch_bounds__(256) void mfma_proj1(
    const float* __restrict__ A, const short* __restrict__ wt_hi,
    const short* __restrict__ wt_lo, float* __restrict__ part)
{
    const int wave = threadIdx.x >> 6, lane = threadIdx.x & 63;
    const int m0 = blockIdx.x * 64 + wave * 16;
    const int rl = lane & 15, g = lane >> 4;
    const int kbase = blockIdx.z * PCH;
    const float* Arow = A + (size_t)(m0 + rl) * SROW;
    f32x4 acc[8];
    #pragma unroll
    for (int nf = 0; nf < 8; ++nf) acc[nf] = (f32x4){0.f,0.f,0.f,0.f};
    for (int s = 0; s < 16; ++s) {
        const int kk = kbase + s * 32 + g * 8;
        float4 p = *(const float4*)(Arow + kk);
        float4 q = *(const float4*)(Arow + kk + 4);
        float av[8] = {p.x, p.y, p.z, p.w, q.x, q.y, q.z, q.w};
        bf16x8 ah, al;
        #pragma unroll
        for (int j = 0; j < 8; ++j) {
            short h = f2bf(av[j]); ah[j] = h;
            al[j] = f2bf(av[j] - bf2f(h));
        }
        #pragma unroll
        for (int nf = 0; nf < 8; ++nf) {
            size_t boff = (size_t)(nf * 16 + rl) * W1LD + kk;
            bf16x8 bh = *(const bf16x8*)(wt_hi + boff);
            bf16x8 bl = *(const bf16x8*)(wt_lo + boff);
            acc[nf] = __builtin_amdgcn_mfma_f32_16x16x32_bf16(ah, bh, acc[nf], 0, 0, 0);
            acc[nf] = __builtin_amdgcn_mfma_f32_16x16x32_bf16(al, bh, acc[nf], 0, 0, 0);
            acc[nf] = __builtin_amdgcn_mfma_f32_16x16x32_bf16(ah, bl, acc[nf], 0, 0, 0);
        }
    }
    float* Cb = part + (size_t)blockIdx.z * NBZ * ROIN;
    const int cm = g * 4;
    #pragma unroll
    for (int nf = 0; nf < 8; ++nf) {
        int n = nf * 16 + rl;
        if (n < ROIN) {
            #pragma unroll
            for (int j = 0; j < 4; ++j)
                Cb[(size_t)(m0 + cm + j) * ROIN + n] = acc[nf][j];
        }
    }
}

// split-K reduce for proj1 (+bias +relu)
__global__ void proj_reduce(const float* __restrict__ ppart,
                            const float* __restrict__ bias, float* __restrict__ t1)
{
    int e = blockIdx.x * 256 + threadIdx.x;
    if (e >= NBZ * ROIN) return;
    int n = e % ROIN;
    float s = 0.f;
    for (int z = 0; z < PZ; ++z) s += ppart[(size_t)z * NBZ * ROIN + e];
    t1[e] = fmaxf(s + bias[n], 0.f);
}

// ---------------------------------------------------------------------------
// fp32 GEMM NT (sim = pn @ pn^T, K=116), symmetric mirror write
// ---------------------------------------------------------------------------
__global__ __launch_bounds__(256) void gemm_nt_sym(
    const float* __restrict__ A, float* __restrict__ C, int M, int K, float scale)
{
    if ((int)blockIdx.y < (int)blockIdx.x) return;
    __shared__ float As[16][65];
    __shared__ float Bs[16][65];
    const int tid = threadIdx.x;
    const int m0 = blockIdx.x * 64;
    const int n0 = blockIdx.y * 64;
    const int tm4 = (tid >> 4) * 4;
    const int tn4 = (tid & 15) * 4;
    const int rA  = tid >> 2;
    const int kbA = (tid & 3) * 4;
    float acc[4][4] = {};
    for (int kt = 0; kt < K; kt += 16) {
        int kg = kt + kbA;
        if (kg + 4 <= K) {
            float4 va = *(const float4*)(A + (size_t)(m0 + rA) * K + kg);
            As[kbA + 0][rA] = va.x; As[kbA + 1][rA] = va.y;
            As[kbA + 2][rA] = va.z; As[kbA + 3][rA] = va.w;
            float4 vb = *(const float4*)(A + (size_t)(n0 + rA) * K + kg);
            Bs[kbA + 0][rA] = vb.x; Bs[kbA + 1][rA] = vb.y;
            Bs[kbA + 2][rA] = vb.z; Bs[kbA + 3][rA] = vb.w;
        } else {
            #pragma unroll
            for (int kk = 0; kk < 4; ++kk) {
                int kgg = kg + kk;
                As[kbA + kk][rA] = (kgg < K) ? A[(size_t)(m0 + rA) * K + kgg] : 0.f;
                Bs[kbA + kk][rA] = (kgg < K) ? A[(size_t)(n0 + rA) * K + kgg] : 0.f;
            }
        }
        __syncthreads();
        #pragma unroll
        for (int k = 0; k < 16; ++k) {
            float a[4], b[4];
            #pragma unroll
            for (int i = 0; i < 4; ++i) a[i] = As[k][tm4 + i];
            #pragma unroll
            for (int j = 0; j < 4; ++j) b[j] = Bs[k][tn4 + j];
            #pragma unroll
            for (int i = 0; i < 4; ++i)
                #pragma unroll
                for (int j = 0; j < 4; ++j)
                    acc[i][j] = fmaf(a[i], b[j], acc[i][j]);
        }
        __syncthreads();
    }
    #pragma unroll
    for (int i = 0; i < 4; ++i) {
        int m = m0 + tm4 + i;
        #pragma unroll
        for (int j = 0; j < 4; ++j) {
            int n = n0 + tn4 + j;
            float v = acc[i][j] * scale;
            C[(size_t)m * M + n] = v;
            C[(size_t)n * M + m] = v;
        }
    }
}

// ---------------------------------------------------------------------------
// Gram via bf16 MFMA over padded/permuted xfh [1024][14848] (dot preserved:
// same column permutation on both operands; pads are zero).
// 128x128 tile, 4 waves each owning a 64x64 quadrant; 29-way split-K.
// ---------------------------------------------------------------------------
__global__ __launch_bounds__(256) void gram_mfma(
    const short* __restrict__ Xh, float* __restrict__ gpart)
{
    const int bx = blockIdx.x, by = blockIdx.y;
    if (by < bx) return;
    const int tri = bx * 8 - (bx * (bx - 1)) / 2 + (by - bx);
    const int k0 = blockIdx.z * GRAMKS;
    const int wave = threadIdx.x >> 6, lane = threadIdx.x & 63;
    const int wr = wave >> 1, wc = wave & 1;
    const int row = lane & 15, koff = (lane >> 4) * 8;
    const short* Ap[4]; const short* Bp[4];
    #pragma unroll
    for (int i = 0; i < 4; ++i) {
        Ap[i] = Xh + (size_t)(bx * 128 + wr * 64 + i * 16 + row) * SROW;
        Bp[i] = Xh + (size_t)(by * 128 + wc * 64 + i * 16 + row) * SROW;
    }
    f32x4 acc[4][4];
    #pragma unroll
    for (int i = 0; i < 4; ++i)
        #pragma unroll
        for (int j = 0; j < 4; ++j) acc[i][j] = (f32x4){0.f,0.f,0.f,0.f};
    bf16x8 a[4], b[4];
    {
        int kk = k0 + koff;
        #pragma unroll
        for (int i = 0; i < 4; ++i) {
            a[i] = *(const bf16x8*)(Ap[i] + kk);
            b[i] = *(const bf16x8*)(Bp[i] + kk);
        }
    }
    for (int k = k0 + 32; k < k0 + GRAMKS; k += 32) {
        bf16x8 an[4], bn[4];
        int kk = k + koff;
        #pragma unroll
        for (int i = 0; i < 4; ++i) {
            an[i] = *(const bf16x8*)(Ap[i] + kk);
            bn[i] = *(const bf16x8*)(Bp[i] + kk);
        }
        #pragma unroll
        for (int i = 0; i < 4; ++i)
            #pragma unroll
            for (int j = 0; j < 4; ++j)
                acc[i][j] = __builtin_amdgcn_mfma_f32_16x16x32_bf16(a[i], b[j], acc[i][j], 0, 0, 0);
        #pragma unroll
        for (int i = 0; i < 4; ++i) { a[i] = an[i]; b[i] = bn[i]; }
    }
    #pragma unroll
    for (int i = 0; i < 4; ++i)
        #pragma unroll
        for (int j = 0; j < 4; ++j)
            acc[i][j] = __builtin_amdgcn_mfma_f32_16x16x32_bf16(a[i], b[j], acc[i][j], 0, 0, 0);
    float* Cb = gpart + ((size_t)blockIdx.z * NTRI + tri) * 16384;
    const int crow = (lane >> 4) * 4;
    const int ccol = lane & 15;
    #pragma unroll
    for (int i = 0; i < 4; ++i) {
        #pragma unroll
        for (int j = 0; j < 4; ++j) {
            int cl = wc * 64 + j * 16 + ccol;
            #pragma unroll
            for (int jj = 0; jj < 4; ++jj) {
                int rl2 = wr * 64 + i * 16 + crow + jj;
                Cb[(size_t)rl2 * 128 + cl] = acc[i][j][jj];
            }
        }
    }
}

// reduce GRAMZ packed-tri partials -> G (with mirror)
__global__ void gram_reduce_p(const float* __restrict__ gpart, float* __restrict__ G)
{
    const int t = blockIdx.x;   // 0..35
    int bx = 0;
    #pragma unroll
    for (int b = 1; b < 8; ++b) {
        int base = b * 8 - (b * (b - 1)) / 2;
        if (base <= t) bx = b;
    }
    const int by = t - (bx * 8 - (bx * (bx - 1)) / 2) + bx;
    int e = blockIdx.y * 1024 + threadIdx.x * 4;
    float sx = 0.f, sy = 0.f, sz = 0.f, sw = 0.f;
    for (int z = 0; z < GRAMZ; ++z) {
        float4 v = *(const float4*)(gpart + ((size_t)z * NTRI + t) * 16384 + e);
        sx += v.x; sy += v.y; sz += v.z; sw += v.w;
    }
    int i = bx * 128 + (e >> 7), j = by * 128 + (e & 127);
    float4 o = {sx, sy, sz, sw};
    *(float4*)(G + ((size_t)i << 10) + j) = o;
    G[((size_t)(j + 0) << 10) + i] = sx;
    G[((size_t)(j + 1) << 10) + i] = sy;
    G[((size_t)(j + 2) << 10) + i] = sz;
    G[((size_t)(j + 3) << 10) + i] = sw;
}

// p[1024,116] -> row L2-normalize in place
__global__ void rownorm(float* __restrict__ p)
{
    int row = blockIdx.x, t = threadIdx.x;   // 128 threads
    __shared__ float red[128];
    float x = 0.f, v = 0.f;
    if (t < ROIN) { x = p[row * ROIN + t]; v = x * x; }
    red[t] = v; __syncthreads();
    for (int off = 64; off > 0; off >>= 1) { if (t < off) red[t] += red[t + off]; __syncthreads(); }
    float inv = 1.f / sqrtf(red[0]);
    if (t < ROIN) p[row * ROIN + t] = x * inv;
}

// global min/max of sim
__global__ void minmax_part(const float* __restrict__ sim, float* __restrict__ mm)
{
    int t = threadIdx.x, b = blockIdx.x;   // 512 x 256
    float mn = 1e30f, mx = -1e30f;
    for (size_t i = (size_t)b * 256 + t; i < 1048576u; i += 512u * 256u) {
        float v = sim[i]; mn = fminf(mn, v); mx = fmaxf(mx, v);
    }
    __shared__ float smn[256], smx[256];
    smn[t] = mn; smx[t] = mx; __syncthreads();
    for (int off = 128; off > 0; off >>= 1) {
        if (t < off) { smn[t] = fminf(smn[t], smn[t + off]); smx[t] = fmaxf(smx[t], smx[t + off]); }
        __syncthreads();
    }
    if (t == 0) { mm[b] = smn[0]; mm[512 + b] = smx[0]; }
}
__global__ void minmax_final(const float* __restrict__ mm, float* __restrict__ fscal)
{
    int t = threadIdx.x;   // 512 threads
    __shared__ float smn[512], smx[512];
    smn[t] = mm[t]; smx[t] = mm[512 + t]; __syncthreads();
    for (int off = 256; off > 0; off >>= 1) {
        if (t < off) { smn[t] = fminf(smn[t], smn[t + off]); smx[t] = fmaxf(smx[t], smx[t + off]); }
        __syncthreads();
    }
    if (t == 0) { fscal[0] = smn[0]; fscal[1] = smx[0]; }
}

// labels[i] = argmax(site[i,0..3]) (first max)
__global__ void labels_k(const int* __restrict__ site, int* __restrict__ labels)
{
    int i = blockIdx.x * 256 + threadIdx.x;
    if (i >= NBZ) return;
    int best = site[4 * i], bi = 0;
    #pragma unroll
    for (int k = 1; k < 4; ++k) { int v = site[4 * i + k]; if (v > best) { best = v; bi = k; } }
    labels[i] = bi;
}

__global__ void rowcnt_k(const int* __restrict__ labels, int* __restrict__ rowcnt)
{
    int i = blockIdx.x * 256 + threadIdx.x;
    if (i >= NBZ) return;
    int li = labels[i], c = 0;
    for (int j = 0; j < NBZ; ++j) c += (labels[j] == li);
    rowcnt[i] = c;
}

// exclusive scan of per-row positive counts; iscal[0]=npos, iscal[1]=m
__global__ __launch_bounds__(1024) void scan_k(const int* __restrict__ rowcnt,
                                               int* __restrict__ rowoff, int* __restrict__ iscal)
{
    __shared__ int s[1024];
    int t = threadIdx.x;
    int c = rowcnt[t];
    s[t] = c; __syncthreads();
    for (int off = 1; off < 1024; off <<= 1) {
        int v = (t >= off) ? s[t - off] : 0;
        __syncthreads();
        s[t] += v;
        __syncthreads();
    }
    rowoff[t] = s[t] - c;
    if (t == 1023) {
        int npos = s[1023];
        int nneg = 1024 * 1024 - npos;
        iscal[0] = npos;
        iscal[1] = (npos < nneg) ? npos : nneg;
    }
}

// scatter sim values to rank-paired pos/neg arrays
__global__ void pair_scatter(const int* __restrict__ labels, const int* __restrict__ rowoff,
                             const int* __restrict__ iscal, const float* __restrict__ sim,
                             float* __restrict__ posval, float* __restrict__ negval)
{
    int row = blockIdx.x, t = threadIdx.x;
    int m = iscal[1];
    int li = labels[row];
    int j0 = t * 4;
    int eq[4]; int c = 0;
    #pragma unroll
    for (int kk = 0; kk < 4; ++kk) { eq[kk] = (labels[j0 + kk] == li); c += eq[kk]; }
    __shared__ int s[256];
    s[t] = c; __syncthreads();
    for (int off = 1; off < 256; off <<= 1) {
        int v = (t >= off) ? s[t - off] : 0;
        __syncthreads();
        s[t] += v;
        __syncthreads();
    }
    int r = rowoff[row] + s[t] - c;
    size_t base = (size_t)row * 1024;
    #pragma unroll
    for (int kk = 0; kk < 4; ++kk) {
        size_t f = base + j0 + kk;
        float v = sim[f];
        if (eq[kk]) { if (r < m) posval[r] = v; r++; }
        else { long nr = (long)f - r; if (nr < m) negval[nr] = v; }
    }
}

__global__ void loss_part(const float* __restrict__ posval, const float* __restrict__ negval,
                          const int* __restrict__ iscal, float* __restrict__ lp)
{
    int m = iscal[1];
    int t = threadIdx.x, b = blockIdx.x;   // 1024 x 256
    float s = 0.f;
    for (int k = b * 256 + t; k < m; k += 1024 * 256) {
        float d = negval[k] - posval[k];
        s += fmaxf(d, 0.f) + log1pf(expf(-fabsf(d)));
    }
    __shared__ float red[256];
    red[t] = s; __syncthreads();
    for (int off = 128; off > 0; off >>= 1) { if (t < off) red[t] += red[t + off]; __syncthreads(); }
    if (t == 0) lp[b] = red[0];
}

__global__ void loss_final(const float* __restrict__ lp, const int* __restrict__ iscal,
                           float* __restrict__ outp)
{
    int t = threadIdx.x;   // 256
    double s = 0.0;
    for (int k = t; k < 1024; k += 256) s += (double)lp[k];
    __shared__ double red[256];
    red[t] = s; __syncthreads();
    for (int off = 128; off > 0; off >>= 1) { if (t < off) red[t] += red[t + off]; __syncthreads(); }
    if (t == 0) {
        int m = iscal[1]; if (m < 1) m = 1;
        outp[0] = (float)(red[0] / (double)m);
    }
}

// dist (in place over G): total * (cond ? 0.9 : 0.1)
__global__ void dist_k(float* __restrict__ G, const float* __restrict__ sim,
                       const float* __restrict__ sq, const int* __restrict__ ages,
                       const int* __restrict__ genders, const float* __restrict__ fscal)
{
    size_t e = (size_t)blockIdx.x * 256 + threadIdx.x;
    int i = (int)(e >> 10), j = (int)(e & 1023);
    float smin = fscal[0], smax = fscal[1];
    float sn = (sim[e] - smin) / (smax - smin);
    float d2 = fmaxf(sq[i] + sq[j] - 2.f * G[e], 0.f);
    float fs = expf(-ALPHA * sqrtf(d2));
    float total = fs * (1.f - sn) + sn;
    int da = ages[i] - ages[j]; if (da < 0) da = -da;
    bool cond = (da <= BETAC) && (genders[i] == genders[j]);
    G[e] = total * (cond ? ACOEF : 1.f - ACOEF);
}

// row-wise top-8 (ties -> lower index)
__global__ void topk8(const float* __restrict__ dist, float* __restrict__ topv, int* __restrict__ topi)
{
    int row = blockIdx.x, t = threadIdx.x;
    __shared__ float sv[1024];
    __shared__ float rv[256];
    __shared__ int   ri[256];
    for (int j = t; j < 1024; j += 256) sv[j] = dist[(size_t)row * 1024 + j];
    __syncthreads();
    for (int k = 0; k < 8; ++k) {
        float bv = -1e30f; int bi = 1 << 20;
        for (int j = t; j < 1024; j += 256) {
            float x = sv[j];
            if (x > bv || (x == bv && j < bi)) { bv = x; bi = j; }
        }
        rv[t] = bv; ri[t] = bi;
        __syncthreads();
        for (int s = 128; s > 0; s >>= 1) {
            if (t < s) {
                float ov = rv[t + s]; int oi = ri[t + s];
                if (ov > rv[t] || (ov == rv[t] && oi < ri[t])) { rv[t] = ov; ri[t] = oi; }
            }
            __syncthreads();
        }
        if (t == 0) { topv[row * 8 + k] = rv[0]; topi[row * 8 + k] = ri[0]; sv[ri[0]] = -1e30f; }
        __syncthreads();
    }
}

// out[row,:] = sum_k vals[row,k] * feat[idx[row,k], :]  over padded SROW rows
// FOLD: per-column BN affine: out = s_c * acc + wsum * t_c; pad cols -> 0
template<int FOLD>
__global__ void adj_gather(const float* __restrict__ vals, const int* __restrict__ idxs,
                           const float* __restrict__ feat, const float* __restrict__ sb,
                           const float* __restrict__ tb, float* __restrict__ out)
{
    int row = blockIdx.x, t = threadIdx.x;
    __shared__ float v[8]; __shared__ int ix[8];
    if (t < 8) { v[t] = vals[row * 8 + t]; ix[t] = idxs[row * 8 + t]; }
    __syncthreads();
    float vv[8]; const float4* fp[8];
    #pragma unroll
    for (int k = 0; k < 8; ++k) { vv[k] = v[k]; fp[k] = (const float4*)(feat + (size_t)ix[k] * SROW); }
    float wsum = 0.f;
    if (FOLD) {
        #pragma unroll
        for (int k = 0; k < 8; ++k) wsum += vv[k];
    }
    float4* op = (float4*)(out + (size_t)row * SROW);
    for (int c = t; c < SROW / 4; c += 256) {
        float4 acc = {0.f, 0.f, 0.f, 0.f};
        #pragma unroll
        for (int k = 0; k < 8; ++k) {
            float4 x = fp[k][c];
            acc.x = fmaf(vv[k], x.x, acc.x);
            acc.y = fmaf(vv[k], x.y, acc.y);
            acc.z = fmaf(vv[k], x.z, acc.z);
            acc.w = fmaf(vv[k], x.w, acc.w);
        }
        if (FOLD) {
            int cb = (c * 4) & 127;
            if (cb < ROIN) {
                acc.x = sb[cb]     * acc.x + wsum * tb[cb];
                acc.y = sb[cb + 1] * acc.y + wsum * tb[cb + 1];
                acc.z = sb[cb + 2] * acc.z + wsum * tb[cb + 2];
                acc.w = sb[cb + 3] * acc.w + wsum * tb[cb + 3];
            } else {
                acc = (float4){0.f, 0.f, 0.f, 0.f};
            }
        }
        op[c] = acc;
    }
}

// bn3: per-ROI-channel stats over (N=1024, L=8); writes final output
__global__ void bn3_k(const float* __restrict__ X, const float* __restrict__ g,
                      const float* __restrict__ bta, float* __restrict__ out)
{
    int c = blockIdx.x, t = threadIdx.x;   // 116 x 256
    float s = 0.f, s2 = 0.f;
    for (int k = t; k < 8192; k += 256) {
        int n = k >> 3, l = k & 7;
        float v = X[(size_t)n * 928 + c * 8 + l];
        s += v; s2 += v * v;
    }
    __shared__ float rs[256], rs2[256];
    rs[t] = s; rs2[t] = s2; __syncthreads();
    for (int off = 128; off > 0; off >>= 1) {
        if (t < off) { rs[t] += rs[t + off]; rs2[t] += rs2[t + off]; }
        __syncthreads();
    }
    __shared__ float sm, sr;
    if (t == 0) {
        float mean = rs[0] / 8192.f;
        float var = rs2[0] / 8192.f - mean * mean;
        sm = mean; sr = 1.f / sqrtf(var + EPSBN);
    }
    __syncthreads();
    float mean = sm, rstd = sr, gg = g[c], bb = bta[c];
    for (int k = t; k < 8192; k += 256) {
        int n = k >> 3, l = k & 7;
        size_t idx = (size_t)n * 928 + c * 8 + l;
        out[idx] = (X[idx] - mean) * rstd * gg + bb;
    }
}

// ---------------------------------------------------------------------------
extern "C" void kernel_launch(void* const* d_in, const int* in_sizes, int n_in,
                              void* d_out, int out_size, void* d_ws, size_t ws_size,
                              hipStream_t stream)
{
    const float* x        = (const float*)d_in[0];
    const float* pseudo   = (const float*)d_in[1];
    const int*   ages     = (const int*)d_in[2];
    const int*   genders  = (const int*)d_in[3];
    const int*   site     = (const int*)d_in[4];
    const float* fc_p_w   = (const float*)d_in[5];
    const float* fc_p_b   = (const float*)d_in[6];
    const float* proj_w1  = (const float*)d_in[7];
    const float* proj_b1  = (const float*)d_in[8];
    const float* proj_w2  = (const float*)d_in[9];
    const float* proj_b2  = (const float*)d_in[10];
    const float* gcn_w1   = (const float*)d_in[11];
    const float* gcn_b1   = (const float*)d_in[12];
    const float* gcn_w2   = (const float*)d_in[13];
    const float* gcn_b2   = (const float*)d_in[14];
    const float* gcn1_w   = (const float*)d_in[15];
    const float* gcn1_b   = (const float*)d_in[16];
    const float* gcn2_w1  = (const float*)d_in[17];
    const float* gcn2_b1  = (const float*)d_in[18];
    const float* gcn2_w2  = (const float*)d_in[19];
    const float* gcn2_b2  = (const float*)d_in[20];
    const float* bn1_g    = (const float*)d_in[21];
    const float* bn1_b    = (const float*)d_in[22];
    const float* bn2_g    = (const float*)d_in[23];
    const float* bn2_b    = (const float*)d_in[24];
    const float* bn3_g    = (const float*)d_in[25];
    const float* bn3_b    = (const float*)d_in[26];
    float* dout = (float*)d_out;

    char* w = (char*)d_ws;
    size_t off = 0;
    auto carve = [&](size_t bytes) { char* p = w + off; off = (off + bytes + 255) & ~(size_t)255; return p; };
    float* xf     = (float*)carve((size_t)NROWS * LDF * 4);   // 58.0 MB padded
    float* hA     = (float*)carve((size_t)NROWS * LDF * 4);
    float* hB     = (float*)carve((size_t)NROWS * LDF * 4);
    float* G      = (float*)carve(1048576u * 4);
    float* simb   = (float*)carve(1048576u * 4);
    float* t1     = (float*)carve((size_t)NBZ * ROIN * 4);
    float* pbuf   = (float*)carve((size_t)NBZ * ROIN * 4);
    float* sq     = (float*)carve(4096);
    float* rsq    = (float*)carve((size_t)NROWS * 4);
    int*   labels = (int*)carve(4096);
    int*   rowcnt = (int*)carve(4096);
    int*   rowoff = (int*)carve(4096);
    int*   iscal  = (int*)carve(256);
    float* fscal  = (float*)carve(256);
    float* posval = (float*)carve(524288u * 4);
    float* negval = (float*)carve(524288u * 4);
    float* lpart  = (float*)carve(4096);
    float* mmpart = (float*)carve(4096);
    float* topv   = (float*)carve(32768);
    int*   topi   = (int*)carve(32768);
    float* statp  = (float*)carve((size_t)232 * GX2 * 4);
    float* sbA    = (float*)carve(512);
    float* tbA    = (float*)carve(512);
    float* sbB    = (float*)carve(512);
    float* tbB    = (float*)carve(512);
    short* wt1_hi = (short*)carve((size_t)128 * W1LD * 2);    // 3.8 MB
    short* wt1_lo = (short*)carve((size_t)128 * W1LD * 2);
    short* wts    = (short*)carve((size_t)7 * 2 * 16384 * 2);
    // aliases into dead phases:
    float* ppart  = hA;                             // proj1 partials (13.8 MB)
    float* gpart  = hA;                             // Gram partials 68.4 MB: hA (58) + hB[0..7.3MB)
    short* xfh    = (short*)((char*)hB + (16u << 20));  // bf16 xf 30.4 MB at hB+16MB (disjoint from spill)

    auto wt_hi = [&](int i) { return wts + (size_t)i * 2 * 16384; };
    auto wt_lo = [&](int i) { return wts + (size_t)i * 2 * 16384 + 16384; };

    // 0. weight pretranspose + hi/lo split
    wt1_conv<<<(128 * W1LD) / 256, 256, 0, stream>>>(proj_w1, wt1_hi, wt1_lo);
    wt_conv<<<64, 256, 0, stream>>>(fc_p_w,   wt_hi(0), wt_lo(0), 116, 116);
    wt_conv<<<64, 256, 0, stream>>>(proj_w2,  wt_hi(1), wt_lo(1), 116, 116);
    wt_conv<<<64, 256, 0, stream>>>(gcn_w1,   wt_hi(2), wt_lo(2), 116, 116);
    wt_conv<<<64, 256, 0, stream>>>(gcn_w2,   wt_hi(3), wt_lo(3), 116, 116);
    wt_conv<<<64, 256, 0, stream>>>(gcn1_w,   wt_hi(4), wt_lo(4), 116, 116);
    wt_conv<<<64, 256, 0, stream>>>(gcn2_w1,  wt_hi(5), wt_lo(5), 116, 64);
    wt_conv<<<64, 256, 0, stream>>>(gcn2_w2,  wt_hi(6), wt_lo(6), 64, 8);

    // 1. xf = x + leaky(pseudo @ fc_p_w + b) padded; also permuted bf16 xfh + row sumsq
    mfma_gemm_w<4, 1, false><<<GX2, 512, 0, stream>>>(pseudo, wt_hi(0), wt_lo(0), fc_p_b, x, xf,
                                                      xfh, rsq, nullptr, ROIN, LDF);
    sq_reduce<<<4, 256, 0, stream>>>(rsq, sq);

    // 2. proj head
    mfma_proj1<<<dim3(16, 1, PZ), 256, 0, stream>>>(xf, wt1_hi, wt1_lo, ppart);
    proj_reduce<<<(NBZ * ROIN + 255) / 256, 256, 0, stream>>>(ppart, proj_b1, t1);
    mfma_gemm_w<1, 0, false><<<8, 512, 0, stream>>>(t1, wt_hi(1), wt_lo(1), proj_b2, nullptr, pbuf,
                                                    nullptr, nullptr, nullptr, ROIN, ROIN);
    rownorm<<<NBZ, 128, 0, stream>>>(pbuf);

    // 3. sim = (pn @ pn^T) / TEMP
    gemm_nt_sym<<<dim3(16, 16, 1), 256, 0, stream>>>(pbuf, simb, NBZ, ROIN, 1.f / 0.07f);

    // 4. contrastive loss
    labels_k<<<4, 256, 0, stream>>>(site, labels);
    rowcnt_k<<<4, 256, 0, stream>>>(labels, rowcnt);
    scan_k<<<1, 1024, 0, stream>>>(rowcnt, rowoff, iscal);
    pair_scatter<<<NBZ, 256, 0, stream>>>(labels, rowoff, iscal, simb, posval, negval);
    loss_part<<<1024, 256, 0, stream>>>(posval, negval, iscal, lpart);
    loss_final<<<1, 256, 0, stream>>>(lpart, iscal, dout + (size_t)NBZ * ROIN * 8);

    // 5. sim min/max, Gram, dist, top-k
    minmax_part<<<512, 256, 0, stream>>>(simb, mmpart);
    minmax_final<<<1, 512, 0, stream>>>(mmpart, fscal);
    gram_mfma<<<dim3(8, 8, GRAMZ), 256, 0, stream>>>(xfh, gpart);
    gram_reduce_p<<<dim3(NTRI, 16), 256, 0, stream>>>(gpart, G);
    dist_k<<<4096, 256, 0, stream>>>(G, simb, sq, ages, genders, fscal);
    topk8<<<NBZ, 256, 0, stream>>>(G, topv, topi);

    // 6. GCN stack (padded gathers; 512-thread LDS-weight GEMMs; BN fused/folded)
    adj_gather<0><<<NBZ, 256, 0, stream>>>(topv, topi, xf, nullptr, nullptr, hA);
    mfma_gemm_w<3, 0, true><<<GX2, 512, 0, stream>>>(hA, wt_hi(2), wt_lo(2), gcn_b1, nullptr, hB,
                                                     nullptr, nullptr, nullptr, LDF, LDF);
    mfma_gemm_w<1, 2, true><<<GX2, 512, 0, stream>>>(hB, wt_hi(3), wt_lo(3), gcn_b2, nullptr, hA,
                                                     nullptr, nullptr, statp, LDF, LDF);
    bn_final_st<<<116, 256, 0, stream>>>(statp, bn1_g, bn1_b, sbA, tbA);

    adj_gather<1><<<NBZ, 256, 0, stream>>>(topv, topi, hA, sbA, tbA, hB);
    mfma_gemm_w<3, 2, true><<<GX2, 512, 0, stream>>>(hB, wt_hi(4), wt_lo(4), gcn1_b, nullptr, hA,
                                                     nullptr, nullptr, statp, LDF, LDF);
    bn_final_st<<<116, 256, 0, stream>>>(statp, bn2_g, bn2_b, sbB, tbB);

    adj_gather<1><<<NBZ, 256, 0, stream>>>(topv, topi, hA, sbB, tbB, hB);
    mfma_gemm45_w<<<GX45, 256, 0, stream>>>(hB, wt_hi(5), wt_lo(5), gcn2_b1,
                                            wt_hi(6), wt_lo(6), gcn2_b2, hA);

    // 7. bn3 -> d_out
    bn3_k<<<116, 256, 0, stream>>>(hA, bn3_g, bn3_b, dout);
}

// Round 9
// 694.888 us; speedup vs baseline: 2.9746x; 1.0828x over previous
//
#include <hip/hip_runtime.h>
#include <math.h>

#define ROIN 116
#define NBZ 1024
#define LDF 128            // padded ROI-row length (floats / bf16)
#define SROW (ROIN*LDF)    // 14848: padded per-sample flat row
#define NROWS (NBZ*ROIN)   // 118784
#define ALPHA 0.1f
#define ACOEF 0.9f
#define BETAC 2
#define EPSBN 1e-5f
#define PZ 29              // proj1 split-K chunks (29*512 = 14848)
#define PCH 512
#define W1LD SROW
#define GX2 928            // NROWS/128 (512-thread GEMM blocks)
#define GX45 1856          // NROWS/64 (gemm45 blocks)
#define GRAMZ 16
#define GRAMKS 928         // 16*928 = 14848
#define NTRI 36            // upper-tri 128x128 tiles of 8x8 grid

typedef __attribute__((ext_vector_type(8))) short bf16x8;
typedef __attribute__((ext_vector_type(4))) float f32x4;

__device__ __forceinline__ float leakyf(float v){ return v >= 0.f ? v : 0.2f*v; }

__device__ __forceinline__ short f2bf(float f){
    unsigned u = __builtin_bit_cast(unsigned, f);
    unsigned r = u + 0x7fffu + ((u >> 16) & 1u);   // RNE
    return (short)(r >> 16);
}
__device__ __forceinline__ float bf2f(short h){
    unsigned u = ((unsigned)(unsigned short)h) << 16;
    return __builtin_bit_cast(float, u);
}

// ---------------------------------------------------------------------------
// Weight pretranspose + bf16 hi/lo split. Small weights -> WT[128][128].
// ---------------------------------------------------------------------------
__global__ void wt_conv(const float* __restrict__ W, short* __restrict__ hi,
                        short* __restrict__ lo, int K, int N)
{
    int idx = blockIdx.x * 256 + threadIdx.x;   // 16384
    int n = idx >> 7, k = idx & 127;
    float v = (n < N && k < K) ? W[(size_t)k * N + n] : 0.f;
    short h = f2bf(v);
    hi[idx] = h;
    lo[idx] = f2bf(v - bf2f(h));
}

// proj_w1 [13456,116] -> WT1[128][14848] hi/lo (padded-K indexing: k'=r*128+d)
__global__ void wt1_conv(const float* __restrict__ W, short* __restrict__ hi,
                         short* __restrict__ lo)
{
    int idx = blockIdx.x * 256 + threadIdx.x;   // 128*14848
    int n = idx / W1LD, k = idx - n * W1LD;
    int r = k >> 7, d = k & 127;
    float v = (n < ROIN && d < ROIN) ? W[(size_t)(r * ROIN + d) * ROIN + n] : 0.f;
    short h = f2bf(v);
    hi[idx] = h;
    lo[idx] = f2bf(v - bf2f(h));
}

// ---------------------------------------------------------------------------
// bf16x2 MFMA GEMM, 512 threads, 128 rows/block, LDS-staged weights.
// A [M][LDA] fp32 (PADK: LDA=128, zero pads, no k-guards), C [M][LDC].
// EPI: 1 bias, 3 leaky(bias), 4 X + leaky(bias)   (X stride = LDA)
// XTRA: 0 none; 1 bf16 C (permuted cols: col'=rl*8+nf) + row sumsq; 2 BN stats
// ---------------------------------------------------------------------------
template<int EPI, int XTRA, bool PADK>
__global__ __launch_bounds__(512) void mfma_gemm_w(
    const float* __restrict__ A, const short* __restrict__ wt_hi,
    const short* __restrict__ wt_lo, const float* __restrict__ bias,
    const float* __restrict__ X, float* __restrict__ C,
    short* __restrict__ bfout, float* __restrict__ rsq, float* __restrict__ statp,
    int LDA, int LDC)
{
    __shared__ short whi[128][136];
    __shared__ short wlo[128][136];
    __shared__ float st[(XTRA == 2) ? 8 : 1][2][128];
    const int tid = threadIdx.x;
    {
        int r = tid >> 2, q = tid & 3;
        const short* sh = wt_hi + r * 128 + q * 32;
        const short* sl = wt_lo + r * 128 + q * 32;
        #pragma unroll
        for (int i = 0; i < 4; ++i) {
            *(bf16x8*)(&whi[r][q * 32 + i * 8]) = *(const bf16x8*)(sh + i * 8);
            *(bf16x8*)(&wlo[r][q * 32 + i * 8]) = *(const bf16x8*)(sl + i * 8);
        }
    }
    __syncthreads();
    const int wave = tid >> 6, lane = tid & 63;
    const int m0 = blockIdx.x * 128 + wave * 16;
    const int rl = lane & 15, g = lane >> 4;
    const float* Arow = A + (size_t)(m0 + rl) * LDA;
    float av[4][8];
    #pragma unroll
    for (int s = 0; s < 4; ++s) {
        const int kk = s * 32 + g * 8;
        if (PADK || kk + 8 <= ROIN) {
            float4 p = *(const float4*)(Arow + kk);
            float4 q = *(const float4*)(Arow + kk + 4);
            av[s][0]=p.x; av[s][1]=p.y; av[s][2]=p.z; av[s][3]=p.w;
            av[s][4]=q.x; av[s][5]=q.y; av[s][6]=q.z; av[s][7]=q.w;
        } else if (kk + 4 <= ROIN) {
            float4 p = *(const float4*)(Arow + kk);
            av[s][0]=p.x; av[s][1]=p.y; av[s][2]=p.z; av[s][3]=p.w;
            av[s][4]=0.f; av[s][5]=0.f; av[s][6]=0.f; av[s][7]=0.f;
        } else {
            #pragma unroll
            for (int j = 0; j < 8; ++j) av[s][j] = 0.f;
        }
    }
    f32x4 acc[8];
    #pragma unroll
    for (int nf = 0; nf < 8; ++nf) acc[nf] = (f32x4){0.f,0.f,0.f,0.f};
    #pragma unroll
    for (int s = 0; s < 4; ++s) {
        const int kk = s * 32 + g * 8;
        bf16x8 ah, al;
        #pragma unroll
        for (int j = 0; j < 8; ++j) {
            short h = f2bf(av[s][j]); ah[j] = h;
            al[j] = f2bf(av[s][j] - bf2f(h));
        }
        #pragma unroll
        for (int nf = 0; nf < 8; ++nf) {
            const bf16x8 bh = *(const bf16x8*)(&whi[nf * 16 + rl][kk]);
            const bf16x8 bl = *(const bf16x8*)(&wlo[nf * 16 + rl][kk]);
            acc[nf] = __builtin_amdgcn_mfma_f32_16x16x32_bf16(ah, bh, acc[nf], 0, 0, 0);
            acc[nf] = __builtin_amdgcn_mfma_f32_16x16x32_bf16(al, bh, acc[nf], 0, 0, 0);
            acc[nf] = __builtin_amdgcn_mfma_f32_16x16x32_bf16(ah, bl, acc[nf], 0, 0, 0);
        }
    }
    const int cm = g * 4;
    float rq[4] = {0.f, 0.f, 0.f, 0.f};
    bf16x8 bfv[4];
    #pragma unroll
    for (int nf = 0; nf < 8; ++nf) {
        int n = nf * 16 + rl;
        float c1 = 0.f, c2 = 0.f;
        float bb = (n < ROIN) ? bias[n] : 0.f;
        #pragma unroll
        for (int j = 0; j < 4; ++j) {
            int m = m0 + cm + j;
            size_t idx = (size_t)m * LDC + n;
            float v = 0.f;
            if (n < ROIN) {
                v = acc[nf][j] + bb;
                if (EPI == 3) v = leakyf(v);
                else if (EPI == 4) v = X[(size_t)m * LDA + n] + leakyf(v);
            }
            if (n < LDC) C[idx] = v;
            if (XTRA == 1) { bfv[j][nf] = f2bf(v); rq[j] += v * v; }
            if (XTRA == 2) { c1 += v; c2 += v * v; }
        }
        if (XTRA == 2) {
            c1 += __shfl_xor(c1, 16); c1 += __shfl_xor(c1, 32);
            c2 += __shfl_xor(c2, 16); c2 += __shfl_xor(c2, 32);
            if (lane < 16) { st[wave][0][n & 127] = c1; st[wave][1][n & 127] = c2; }
        }
    }
    if (XTRA == 1) {
        #pragma unroll
        for (int j = 0; j < 4; ++j)
            *(bf16x8*)(&bfout[(size_t)(m0 + cm + j) * LDF + rl * 8]) = bfv[j];
        #pragma unroll
        for (int j = 0; j < 4; ++j) {
            rq[j] += __shfl_xor(rq[j], 1);
            rq[j] += __shfl_xor(rq[j], 2);
            rq[j] += __shfl_xor(rq[j], 4);
            rq[j] += __shfl_xor(rq[j], 8);
        }
        if (rl == 0) {
            #pragma unroll
            for (int j = 0; j < 4; ++j) rsq[m0 + cm + j] = rq[j];
        }
    }
    if (XTRA == 2) {
        __syncthreads();
        if (tid < 232) {
            int sel = tid < 116 ? 0 : 1;
            int c = sel ? tid - 116 : tid;
            float s = 0.f;
            #pragma unroll
            for (int wv = 0; wv < 8; ++wv) s += st[wv][sel][c];
            statp[(size_t)(sel * 116 + c) * GX2 + blockIdx.x] = s;
        }
    }
}

// ---------------------------------------------------------------------------
// Gather-fused bf16x2 MFMA GEMM: A-row m = sum_k vals[bz,k]*feat[idx,...]
// with optional BN-affine fold (sb,tb) on the gathered value; then @W.
// bz = m/116; feat rows padded SROW; pad cols zero (guarded when FOLD).
// ---------------------------------------------------------------------------
template<int EPI, int XTRA, bool FOLD>
__global__ __launch_bounds__(512) void mfma_gemm_wg(
    const float* __restrict__ vals, const int* __restrict__ idxs,
    const float* __restrict__ feat, const float* __restrict__ sb,
    const float* __restrict__ tb,
    const short* __restrict__ wt_hi, const short* __restrict__ wt_lo,
    const float* __restrict__ bias, float* __restrict__ C,
    float* __restrict__ statp)
{
    __shared__ short whi[128][136];
    __shared__ short wlo[128][136];
    __shared__ float st[(XTRA == 2) ? 8 : 1][2][128];
    const int tid = threadIdx.x;
    {
        int r = tid >> 2, q = tid & 3;
        const short* sh = wt_hi + r * 128 + q * 32;
        const short* sl = wt_lo + r * 128 + q * 32;
        #pragma unroll
        for (int i = 0; i < 4; ++i) {
            *(bf16x8*)(&whi[r][q * 32 + i * 8]) = *(const bf16x8*)(sh + i * 8);
            *(bf16x8*)(&wlo[r][q * 32 + i * 8]) = *(const bf16x8*)(sl + i * 8);
        }
    }
    __syncthreads();
    const int wave = tid >> 6, lane = tid & 63;
    const int m0 = blockIdx.x * 128 + wave * 16;
    const int rl = lane & 15, g = lane >> 4;
    const int m = m0 + rl;
    const unsigned bz = (unsigned)m / 116u;
    const int r = m - (int)bz * 116;
    float vv[8]; const float4* fp[8];
    #pragma unroll
    for (int k = 0; k < 8; ++k) {
        vv[k] = vals[bz * 8 + k];
        int ixk = idxs[bz * 8 + k];
        fp[k] = (const float4*)(feat + ((size_t)ixk * 116 + r) * 128);
    }
    float wsum = 0.f;
    if (FOLD) {
        #pragma unroll
        for (int k = 0; k < 8; ++k) wsum += vv[k];
    }
    f32x4 acc[8];
    #pragma unroll
    for (int nf = 0; nf < 8; ++nf) acc[nf] = (f32x4){0.f,0.f,0.f,0.f};
    #pragma unroll
    for (int s = 0; s < 4; ++s) {
        const int kk = s * 32 + g * 8;
        float4 P = {0.f,0.f,0.f,0.f}, Q = {0.f,0.f,0.f,0.f};
        #pragma unroll
        for (int k = 0; k < 8; ++k) {
            float4 xp = fp[k][kk >> 2];
            float4 xq = fp[k][(kk >> 2) + 1];
            P.x = fmaf(vv[k], xp.x, P.x); P.y = fmaf(vv[k], xp.y, P.y);
            P.z = fmaf(vv[k], xp.z, P.z); P.w = fmaf(vv[k], xp.w, P.w);
            Q.x = fmaf(vv[k], xq.x, Q.x); Q.y = fmaf(vv[k], xq.y, Q.y);
            Q.z = fmaf(vv[k], xq.z, Q.z); Q.w = fmaf(vv[k], xq.w, Q.w);
        }
        float av[8] = {P.x, P.y, P.z, P.w, Q.x, Q.y, Q.z, Q.w};
        if (FOLD) {
            #pragma unroll
            for (int j = 0; j < 8; ++j) {
                int c = kk + j;
                av[j] = (c < ROIN) ? sb[c] * av[j] + wsum * tb[c] : 0.f;
            }
        }
        bf16x8 ah, al;
        #pragma unroll
        for (int j = 0; j < 8; ++j) {
            short h = f2bf(av[j]); ah[j] = h;
            al[j] = f2bf(av[j] - bf2f(h));
        }
        #pragma unroll
        for (int nf = 0; nf < 8; ++nf) {
            const bf16x8 bh = *(const bf16x8*)(&whi[nf * 16 + rl][kk]);
            const bf16x8 bl = *(const bf16x8*)(&wlo[nf * 16 + rl][kk]);
            acc[nf] = __builtin_amdgcn_mfma_f32_16x16x32_bf16(ah, bh, acc[nf], 0, 0, 0);
            acc[nf] = __builtin_amdgcn_mfma_f32_16x16x32_bf16(al, bh, acc[nf], 0, 0, 0);
            acc[nf] = __builtin_amdgcn_mfma_f32_16x16x32_bf16(ah, bl, acc[nf], 0, 0, 0);
        }
    }
    const int cm = g * 4;
    #pragma unroll
    for (int nf = 0; nf < 8; ++nf) {
        int n = nf * 16 + rl;
        float c1 = 0.f, c2 = 0.f;
        float bb = (n < ROIN) ? bias[n] : 0.f;
        #pragma unroll
        for (int j = 0; j < 4; ++j) {
            int mm = m0 + cm + j;
            float v = 0.f;
            if (n < ROIN) {
                v = acc[nf][j] + bb;
                if (EPI == 3) v = leakyf(v);
            }
            C[(size_t)mm * LDF + n] = v;
            if (XTRA == 2) { c1 += v; c2 += v * v; }
        }
        if (XTRA == 2) {
            c1 += __shfl_xor(c1, 16); c1 += __shfl_xor(c1, 32);
            c2 += __shfl_xor(c2, 16); c2 += __shfl_xor(c2, 32);
            if (lane < 16) { st[wave][0][n & 127] = c1; st[wave][1][n & 127] = c2; }
        }
    }
    if (XTRA == 2) {
        __syncthreads();
        if (tid < 232) {
            int sel = tid < 116 ? 0 : 1;
            int c = sel ? tid - 116 : tid;
            float s = 0.f;
            #pragma unroll
            for (int wv = 0; wv < 8; ++wv) s += st[wv][sel][c];
            statp[(size_t)(sel * 116 + c) * GX2 + blockIdx.x] = s;
        }
    }
}

// ---------------------------------------------------------------------------
// Gather-fused pair: C[NROWS][8] = leaky(leaky(gathA@W5+b5)@W6+b6),
// gathA = BN-affine(sb,tb) of sum_k vals*feat rows.
// ---------------------------------------------------------------------------
__global__ __launch_bounds__(256) void mfma_gemm45_wg(
    const float* __restrict__ vals, const int* __restrict__ idxs,
    const float* __restrict__ feat, const float* __restrict__ sb,
    const float* __restrict__ tb,
    const short* __restrict__ w5h, const short* __restrict__ w5l,
    const float* __restrict__ b5,
    const short* __restrict__ w6h, const short* __restrict__ w6l,
    const float* __restrict__ b6,
    float* __restrict__ C)
{
    __shared__ short s5h[64][136], s5l[64][136];
    __shared__ short s6h[16][136], s6l[16][136];
    __shared__ float c1s[4][16][76];
    const int tid = threadIdx.x;
    {
        int r = tid >> 2, q = tid & 3;
        const short* sh = w5h + r * 128 + q * 32;
        const short* sl = w5l + r * 128 + q * 32;
        #pragma unroll
        for (int i = 0; i < 4; ++i) {
            *(bf16x8*)(&s5h[r][q * 32 + i * 8]) = *(const bf16x8*)(sh + i * 8);
            *(bf16x8*)(&s5l[r][q * 32 + i * 8]) = *(const bf16x8*)(sl + i * 8);
        }
        if (tid < 64) {
            int r6 = tid >> 2, q6 = tid & 3;
            const short* sh6 = w6h + r6 * 128 + q6 * 32;
            const short* sl6 = w6l + r6 * 128 + q6 * 32;
            #pragma unroll
            for (int i = 0; i < 4; ++i) {
                *(bf16x8*)(&s6h[r6][q6 * 32 + i * 8]) = *(const bf16x8*)(sh6 + i * 8);
                *(bf16x8*)(&s6l[r6][q6 * 32 + i * 8]) = *(const bf16x8*)(sl6 + i * 8);
            }
        }
    }
    __syncthreads();
    const int wave = tid >> 6, lane = tid & 63;
    const int m0 = blockIdx.x * 64 + wave * 16;
    const int rl = lane & 15, g = lane >> 4;
    const int m = m0 + rl;
    const unsigned bz = (unsigned)m / 116u;
    const int r = m - (int)bz * 116;
    float vv[8]; const float4* fp[8];
    #pragma unroll
    for (int k = 0; k < 8; ++k) {
        vv[k] = vals[bz * 8 + k];
        int ixk = idxs[bz * 8 + k];
        fp[k] = (const float4*)(feat + ((size_t)ixk * 116 + r) * 128);
    }
    float wsum = 0.f;
    #pragma unroll
    for (int k = 0; k < 8; ++k) wsum += vv[k];
    f32x4 acc[4];
    #pragma unroll
    for (int nf = 0; nf < 4; ++nf) acc[nf] = (f32x4){0.f,0.f,0.f,0.f};
    #pragma unroll
    for (int s = 0; s < 4; ++s) {
        const int kk = s * 32 + g * 8;
        float4 P = {0.f,0.f,0.f,0.f}, Q = {0.f,0.f,0.f,0.f};
        #pragma unroll
        for (int k = 0; k < 8; ++k) {
            float4 xp = fp[k][kk >> 2];
            float4 xq = fp[k][(kk >> 2) + 1];
            P.x = fmaf(vv[k], xp.x, P.x); P.y = fmaf(vv[k], xp.y, P.y);
            P.z = fmaf(vv[k], xp.z, P.z); P.w = fmaf(vv[k], xp.w, P.w);
            Q.x = fmaf(vv[k], xq.x, Q.x); Q.y = fmaf(vv[k], xq.y, Q.y);
            Q.z = fmaf(vv[k], xq.z, Q.z); Q.w = fmaf(vv[k], xq.w, Q.w);
        }
        float av[8] = {P.x, P.y, P.z, P.w, Q.x, Q.y, Q.z, Q.w};
        #pragma unroll
        for (int j = 0; j < 8; ++j) {
            int c = kk + j;
            av[j] = (c < ROIN) ? sb[c] * av[j] + wsum * tb[c] : 0.f;
        }
        bf16x8 ah, al;
        #pragma unroll
        for (int j = 0; j < 8; ++j) {
            short h = f2bf(av[j]); ah[j] = h;
            al[j] = f2bf(av[j] - bf2f(h));
        }
        #pragma unroll
        for (int nf = 0; nf < 4; ++nf) {
            const bf16x8 bh = *(const bf16x8*)(&s5h[nf * 16 + rl][kk]);
            const bf16x8 bl = *(const bf16x8*)(&s5l[nf * 16 + rl][kk]);
            acc[nf] = __builtin_amdgcn_mfma_f32_16x16x32_bf16(ah, bh, acc[nf], 0, 0, 0);
            acc[nf] = __builtin_amdgcn_mfma_f32_16x16x32_bf16(al, bh, acc[nf], 0, 0, 0);
            acc[nf] = __builtin_amdgcn_mfma_f32_16x16x32_bf16(ah, bl, acc[nf], 0, 0, 0);
        }
    }
    const int cm = g * 4;
    #pragma unroll
    for (int nf = 0; nf < 4; ++nf) {
        int n = nf * 16 + rl;   // < 64
        float bb = b5[n];
        #pragma unroll
        for (int j = 0; j < 4; ++j)
            c1s[wave][cm + j][n] = leakyf(acc[nf][j] + bb);
    }
    f32x4 acc2 = {0.f,0.f,0.f,0.f};
    #pragma unroll
    for (int s = 0; s < 2; ++s) {
        const int kk = s * 32 + g * 8;
        float4 p = *(const float4*)(&c1s[wave][rl][kk]);
        float4 q = *(const float4*)(&c1s[wave][rl][kk + 4]);
        float a2[8] = {p.x, p.y, p.z, p.w, q.x, q.y, q.z, q.w};
        bf16x8 ah, al;
        #pragma unroll
        for (int j = 0; j < 8; ++j) {
            short h = f2bf(a2[j]); ah[j] = h;
            al[j] = f2bf(a2[j] - bf2f(h));
        }
        const bf16x8 bh = *(const bf16x8*)(&s6h[rl][kk]);
        const bf16x8 bl = *(const bf16x8*)(&s6l[rl][kk]);
        acc2 = __builtin_amdgcn_mfma_f32_16x16x32_bf16(ah, bh, acc2, 0, 0, 0);
        acc2 = __builtin_amdgcn_mfma_f32_16x16x32_bf16(al, bh, acc2, 0, 0, 0);
        acc2 = __builtin_amdgcn_mfma_f32_16x16x32_bf16(ah, bl, acc2, 0, 0, 0);
    }
    if (rl < 8) {
        float bb = b6[rl];
        #pragma unroll
        for (int j = 0; j < 4; ++j) {
            float v = leakyf(acc2[j] + bb);
            C[(size_t)(m0 + cm + j) * 8 + rl] = v;
        }
    }
}

// BN finalize -> s=rstd*g, t=b-mean*rstd*g
__global__ void bn_final_st(const float* __restrict__ statp, const float* __restrict__ g,
                            const float* __restrict__ bta, float* __restrict__ sb,
                            float* __restrict__ tb)
{
    int c = blockIdx.x, tid = threadIdx.x;   // 116 x 256
    float a1 = 0.f, a2 = 0.f;
    for (int i = tid; i < GX2; i += 256) {
        a1 += statp[(size_t)c * GX2 + i];
        a2 += statp[(size_t)(116 + c) * GX2 + i];
    }
    __shared__ float r1[256], r2[256];
    r1[tid] = a1; r2[tid] = a2; __syncthreads();
    for (int off = 128; off > 0; off >>= 1) {
        if (tid < off) { r1[tid] += r1[tid + off]; r2[tid] += r2[tid + off]; }
        __syncthreads();
    }
    if (tid == 0) {
        float mean = r1[0] / (float)NROWS;
        float var = r2[0] / (float)NROWS - mean * mean;
        float rstd = 1.f / sqrtf(var + EPSBN);
        float s = rstd * g[c];
        sb[c] = s;
        tb[c] = bta[c] - mean * s;
    }
}

// sq[bz] = sum of 116 per-M-row sumsq partials
__global__ void sq_reduce(const float* __restrict__ rsq, float* __restrict__ sq)
{
    int i = blockIdx.x * 256 + threadIdx.x;
    if (i >= NBZ) return;
    const float* p = rsq + (size_t)i * ROIN;
    float s = 0.f;
    #pragma unroll 4
    for (int r = 0; r < ROIN; ++r) s += p[r];
    sq[i] = s;
}

// ---------------------------------------------------------------------------
// proj1 via bf16x2 MFMA, split-K over padded xf [1024][14848]
// ---------------------------------------------------------------------------
__global__ __launch_bounds__(256) void mfma_proj1(
    const float* __restrict__ A, const short* __restrict__ wt_hi,
    const short* __restrict__ wt_lo, float* __restrict__ part)
{
    const int wave = threadIdx.x >> 6, lane = threadIdx.x & 63;
    const int m0 = blockIdx.x * 64 + wave * 16;
    const int rl = lane & 15, g = lane >> 4;
    const int kbase = blockIdx.z * PCH;
    const float* Arow = A + (size_t)(m0 + rl) * SROW;
    f32x4 acc[8];
    #pragma unroll
    for (int nf = 0; nf < 8; ++nf) acc[nf] = (f32x4){0.f,0.f,0.f,0.f};
    for (int s = 0; s < 16; ++s) {
        const int kk = kbase + s * 32 + g * 8;
        float4 p = *(const float4*)(Arow + kk);
        float4 q = *(const float4*)(Arow + kk + 4);
        float av[8] = {p.x, p.y, p.z, p.w, q.x, q.y, q.z, q.w};
        bf16x8 ah, al;
        #pragma unroll
        for (int j = 0; j < 8; ++j) {
            short h = f2bf(av[j]); ah[j] = h;
            al[j] = f2bf(av[j] - bf2f(h));
        }
        #pragma unroll
        for (int nf = 0; nf < 8; ++nf) {
            size_t boff = (size_t)(nf * 16 + rl) * W1LD + kk;
            bf16x8 bh = *(const bf16x8*)(wt_hi + boff);
            bf16x8 bl = *(const bf16x8*)(wt_lo + boff);
            acc[nf] = __builtin_amdgcn_mfma_f32_16x16x32_bf16(ah, bh, acc[nf], 0, 0, 0);
            acc[nf] = __builtin_amdgcn_mfma_f32_16x16x32_bf16(al, bh, acc[nf], 0, 0, 0);
            acc[nf] = __builtin_amdgcn_mfma_f32_16x16x32_bf16(ah, bl, acc[nf], 0, 0, 0);
        }
    }
    float* Cb = part + (size_t)blockIdx.z * NBZ * ROIN;
    const int cm = g * 4;
    #pragma unroll
    for (int nf = 0; nf < 8; ++nf) {
        int n = nf * 16 + rl;
        if (n < ROIN) {
            #pragma unroll
            for (int j = 0; j < 4; ++j)
                Cb[(size_t)(m0 + cm + j) * ROIN + n] = acc[nf][j];
        }
    }
}

// split-K reduce for proj1 (+bias +relu)
__global__ void proj_reduce(const float* __restrict__ ppart,
                            const float* __restrict__ bias, float* __restrict__ t1)
{
    int e = blockIdx.x * 256 + threadIdx.x;
    if (e >= NBZ * ROIN) return;
    int n = e % ROIN;
    float s = 0.f;
    for (int z = 0; z < PZ; ++z) s += ppart[(size_t)z * NBZ * ROIN + e];
    t1[e] = fmaxf(s + bias[n], 0.f);
}

// ---------------------------------------------------------------------------
// fp32 GEMM NT (sim = pn @ pn^T, K=116), symmetric mirror write
// ---------------------------------------------------------------------------
__global__ __launch_bounds__(256) void gemm_nt_sym(
    const float* __restrict__ A, float* __restrict__ C, int M, int K, float scale)
{
    if ((int)blockIdx.y < (int)blockIdx.x) return;
    __shared__ float As[16][65];
    __shared__ float Bs[16][65];
    const int tid = threadIdx.x;
    const int m0 = blockIdx.x * 64;
    const int n0 = blockIdx.y * 64;
    const int tm4 = (tid >> 4) * 4;
    const int tn4 = (tid & 15) * 4;
    const int rA  = tid >> 2;
    const int kbA = (tid & 3) * 4;
    float acc[4][4] = {};
    for (int kt = 0; kt < K; kt += 16) {
        int kg = kt + kbA;
        if (kg + 4 <= K) {
            float4 va = *(const float4*)(A + (size_t)(m0 + rA) * K + kg);
            As[kbA + 0][rA] = va.x; As[kbA + 1][rA] = va.y;
            As[kbA + 2][rA] = va.z; As[kbA + 3][rA] = va.w;
            float4 vb = *(const float4*)(A + (size_t)(n0 + rA) * K + kg);
            Bs[kbA + 0][rA] = vb.x; Bs[kbA + 1][rA] = vb.y;
            Bs[kbA + 2][rA] = vb.z; Bs[kbA + 3][rA] = vb.w;
        } else {
            #pragma unroll
            for (int kk = 0; kk < 4; ++kk) {
                int kgg = kg + kk;
                As[kbA + kk][rA] = (kgg < K) ? A[(size_t)(m0 + rA) * K + kgg] : 0.f;
                Bs[kbA + kk][rA] = (kgg < K) ? A[(size_t)(n0 + rA) * K + kgg] : 0.f;
            }
        }
        __syncthreads();
        #pragma unroll
        for (int k = 0; k < 16; ++k) {
            float a[4], b[4];
            #pragma unroll
            for (int i = 0; i < 4; ++i) a[i] = As[k][tm4 + i];
            #pragma unroll
            for (int j = 0; j < 4; ++j) b[j] = Bs[k][tn4 + j];
            #pragma unroll
            for (int i = 0; i < 4; ++i)
                #pragma unroll
                for (int j = 0; j < 4; ++j)
                    acc[i][j] = fmaf(a[i], b[j], acc[i][j]);
        }
        __syncthreads();
    }
    #pragma unroll
    for (int i = 0; i < 4; ++i) {
        int m = m0 + tm4 + i;
        #pragma unroll
        for (int j = 0; j < 4; ++j) {
            int n = n0 + tn4 + j;
            float v = acc[i][j] * scale;
            C[(size_t)m * M + n] = v;
            C[(size_t)n * M + m] = v;
        }
    }
}

// ---------------------------------------------------------------------------
// Gram via bf16 MFMA over padded/permuted xfh. 1D grid 576 = 36 tri x 16 z,
// XCD-affine: wg = (id&7)*72 + (id>>3) -> each XCD owns 2 complete z-slices
// (slice panels fit its 4MB L2, reused across all 36 tiles).
// ---------------------------------------------------------------------------
__global__ __launch_bounds__(256) void gram_mfma(
    const short* __restrict__ Xh, float* __restrict__ gpart)
{
    const int id = blockIdx.x;
    const int wg = (id & 7) * 72 + (id >> 3);
    const int z = wg / 36;
    const int tri = wg - z * 36;
    int bx = 0;
    #pragma unroll
    for (int b = 1; b < 8; ++b) {
        int base = b * 8 - (b * (b - 1)) / 2;
        if (base <= tri) bx = b;
    }
    const int by = tri - (bx * 8 - (bx * (bx - 1)) / 2) + bx;
    const int k0 = z * GRAMKS;
    const int wave = threadIdx.x >> 6, lane = threadIdx.x & 63;
    const int wr = wave >> 1, wc = wave & 1;
    const int row = lane & 15, koff = (lane >> 4) * 8;
    const short* Ap[4]; const short* Bp[4];
    #pragma unroll
    for (int i = 0; i < 4; ++i) {
        Ap[i] = Xh + (size_t)(bx * 128 + wr * 64 + i * 16 + row) * SROW;
        Bp[i] = Xh + (size_t)(by * 128 + wc * 64 + i * 16 + row) * SROW;
    }
    f32x4 acc[4][4];
    #pragma unroll
    for (int i = 0; i < 4; ++i)
        #pragma unroll
        for (int j = 0; j < 4; ++j) acc[i][j] = (f32x4){0.f,0.f,0.f,0.f};
    bf16x8 a[4], b[4];
    {
        int kk = k0 + koff;
        #pragma unroll
        for (int i = 0; i < 4; ++i) {
            a[i] = *(const bf16x8*)(Ap[i] + kk);
            b[i] = *(const bf16x8*)(Bp[i] + kk);
        }
    }
    for (int k = k0 + 32; k < k0 + GRAMKS; k += 32) {
        bf16x8 an[4], bn[4];
        int kk = k + koff;
        #pragma unroll
        for (int i = 0; i < 4; ++i) {
            an[i] = *(const bf16x8*)(Ap[i] + kk);
            bn[i] = *(const bf16x8*)(Bp[i] + kk);
        }
        #pragma unroll
        for (int i = 0; i < 4; ++i)
            #pragma unroll
            for (int j = 0; j < 4; ++j)
                acc[i][j] = __builtin_amdgcn_mfma_f32_16x16x32_bf16(a[i], b[j], acc[i][j], 0, 0, 0);
        #pragma unroll
        for (int i = 0; i < 4; ++i) { a[i] = an[i]; b[i] = bn[i]; }
    }
    #pragma unroll
    for (int i = 0; i < 4; ++i)
        #pragma unroll
        for (int j = 0; j < 4; ++j)
            acc[i][j] = __builtin_amdgcn_mfma_f32_16x16x32_bf16(a[i], b[j], acc[i][j], 0, 0, 0);
    float* Cb = gpart + ((size_t)z * NTRI + tri) * 16384;
    const int crow = (lane >> 4) * 4;
    const int ccol = lane & 15;
    #pragma unroll
    for (int i = 0; i < 4; ++i) {
        #pragma unroll
        for (int j = 0; j < 4; ++j) {
            int cl = wc * 64 + j * 16 + ccol;
            #pragma unroll
            for (int jj = 0; jj < 4; ++jj) {
                int rl2 = wr * 64 + i * 16 + crow + jj;
                Cb[(size_t)rl2 * 128 + cl] = acc[i][j][jj];
            }
        }
    }
}

// reduce GRAMZ packed-tri partials -> fused dist (with mirror write)
__global__ void gram_reduce_dist(const float* __restrict__ gpart,
                                 const float* __restrict__ sim, const float* __restrict__ sq,
                                 const int* __restrict__ ages, const int* __restrict__ genders,
                                 const float* __restrict__ fscal, float* __restrict__ G)
{
    const int t = blockIdx.x;   // 0..35
    int bx = 0;
    #pragma unroll
    for (int b = 1; b < 8; ++b) {
        int base = b * 8 - (b * (b - 1)) / 2;
        if (base <= t) bx = b;
    }
    const int by = t - (bx * 8 - (bx * (bx - 1)) / 2) + bx;
    int e = blockIdx.y * 1024 + threadIdx.x * 4;
    float sx = 0.f, sy = 0.f, sz = 0.f, sw = 0.f;
    for (int z = 0; z < GRAMZ; ++z) {
        float4 v = *(const float4*)(gpart + ((size_t)z * NTRI + t) * 16384 + e);
        sx += v.x; sy += v.y; sz += v.z; sw += v.w;
    }
    const int i = bx * 128 + (e >> 7), j0 = by * 128 + (e & 127);
    const float smin = fscal[0], smax = fscal[1];
    const float inv = 1.f / (smax - smin);
    const float sqi = sq[i];
    const int agei = ages[i], geni = genders[i];
    float4 simv = *(const float4*)(sim + ((size_t)i << 10) + j0);
    float gs[4] = {sx, sy, sz, sw};
    float sms[4] = {simv.x, simv.y, simv.z, simv.w};
    float out[4];
    #pragma unroll
    for (int c = 0; c < 4; ++c) {
        int j = j0 + c;
        float sn = (sms[c] - smin) * inv;
        float d2 = fmaxf(sqi + sq[j] - 2.f * gs[c], 0.f);
        float fs = expf(-ALPHA * sqrtf(d2));
        float total = fs * (1.f - sn) + sn;
        int da = agei - ages[j]; if (da < 0) da = -da;
        bool cond = (da <= BETAC) && (geni == genders[j]);
        out[c] = total * (cond ? ACOEF : 1.f - ACOEF);
    }
    float4 o = {out[0], out[1], out[2], out[3]};
    *(float4*)(G + ((size_t)i << 10) + j0) = o;
    #pragma unroll
    for (int c = 0; c < 4; ++c)
        G[((size_t)(j0 + c) << 10) + i] = out[c];
}

// p[1024,116] -> row L2-normalize in place
__global__ void rownorm(float* __restrict__ p)
{
    int row = blockIdx.x, t = threadIdx.x;   // 128 threads
    __shared__ float red[128];
    float x = 0.f, v = 0.f;
    if (t < ROIN) { x = p[row * ROIN + t]; v = x * x; }
    red[t] = v; __syncthreads();
    for (int off = 64; off > 0; off >>= 1) { if (t < off) red[t] += red[t + off]; __syncthreads(); }
    float inv = 1.f / sqrtf(red[0]);
    if (t < ROIN) p[row * ROIN + t] = x * inv;
}

// global min/max of sim
__global__ void minmax_part(const float* __restrict__ sim, float* __restrict__ mm)
{
    int t = threadIdx.x, b = blockIdx.x;   // 512 x 256
    float mn = 1e30f, mx = -1e30f;
    for (size_t i = (size_t)b * 256 + t; i < 1048576u; i += 512u * 256u) {
        float v = sim[i]; mn = fminf(mn, v); mx = fmaxf(mx, v);
    }
    __shared__ float smn[256], smx[256];
    smn[t] = mn; smx[t] = mx; __syncthreads();
    for (int off = 128; off > 0; off >>= 1) {
        if (t < off) { smn[t] = fminf(smn[t], smn[t + off]); smx[t] = fmaxf(smx[t], smx[t + off]); }
        __syncthreads();
    }
    if (t == 0) { mm[b] = smn[0]; mm[512 + b] = smx[0]; }
}
__global__ void minmax_final(const float* __restrict__ mm, float* __restrict__ fscal)
{
    int t = threadIdx.x;   // 512 threads
    __shared__ float smn[512], smx[512];
    smn[t] = mm[t]; smx[t] = mm[512 + t]; __syncthreads();
    for (int off = 256; off > 0; off >>= 1) {
        if (t < off) { smn[t] = fminf(smn[t], smn[t + off]); smx[t] = fmaxf(smx[t], smx[t + off]); }
        __syncthreads();
    }
    if (t == 0) { fscal[0] = smn[0]; fscal[1] = smx[0]; }
}

// labels[i] = argmax(site[i,0..3]) (first max)
__global__ void labels_k(const int* __restrict__ site, int* __restrict__ labels)
{
    int i = blockIdx.x * 256 + threadIdx.x;
    if (i >= NBZ) return;
    int best = site[4 * i], bi = 0;
    #pragma unroll
    for (int k = 1; k < 4; ++k) { int v = site[4 * i + k]; if (v > best) { best = v; bi = k; } }
    labels[i] = bi;
}

__global__ void rowcnt_k(const int* __restrict__ labels, int* __restrict__ rowcnt)
{
    int i = blockIdx.x * 256 + threadIdx.x;
    if (i >= NBZ) return;
    int li = labels[i], c = 0;
    for (int j = 0; j < NBZ; ++j) c += (labels[j] == li);
    rowcnt[i] = c;
}

// exclusive scan of per-row positive counts; iscal[0]=npos, iscal[1]=m
__global__ __launch_bounds__(1024) void scan_k(const int* __restrict__ rowcnt,
                                               int* __restrict__ rowoff, int* __restrict__ iscal)
{
    __shared__ int s[1024];
    int t = threadIdx.x;
    int c = rowcnt[t];
    s[t] = c; __syncthreads();
    for (int off = 1; off < 1024; off <<= 1) {
        int v = (t >= off) ? s[t - off] : 0;
        __syncthreads();
        s[t] += v;
        __syncthreads();
    }
    rowoff[t] = s[t] - c;
    if (t == 1023) {
        int npos = s[1023];
        int nneg = 1024 * 1024 - npos;
        iscal[0] = npos;
        iscal[1] = (npos < nneg) ? npos : nneg;
    }
}

// scatter sim values to rank-paired pos/neg arrays
__global__ void pair_scatter(const int* __restrict__ labels, const int* __restrict__ rowoff,
                             const int* __restrict__ iscal, const float* __restrict__ sim,
                             float* __restrict__ posval, float* __restrict__ negval)
{
    int row = blockIdx.x, t = threadIdx.x;
    int m = iscal[1];
    int li = labels[row];
    int j0 = t * 4;
    int eq[4]; int c = 0;
    #pragma unroll
    for (int kk = 0; kk < 4; ++kk) { eq[kk] = (labels[j0 + kk] == li); c += eq[kk]; }
    __shared__ int s[256];
    s[t] = c; __syncthreads();
    for (int off = 1; off < 256; off <<= 1) {
        int v = (t >= off) ? s[t - off] : 0;
        __syncthreads();
        s[t] += v;
        __syncthreads();
    }
    int r = rowoff[row] + s[t] - c;
    size_t base = (size_t)row * 1024;
    #pragma unroll
    for (int kk = 0; kk < 4; ++kk) {
        size_t f = base + j0 + kk;
        float v = sim[f];
        if (eq[kk]) { if (r < m) posval[r] = v; r++; }
        else { long nr = (long)f - r; if (nr < m) negval[nr] = v; }
    }
}

__global__ void loss_part(const float* __restrict__ posval, const float* __restrict__ negval,
                          const int* __restrict__ iscal, float* __restrict__ lp)
{
    int m = iscal[1];
    int t = threadIdx.x, b = blockIdx.x;   // 1024 x 256
    float s = 0.f;
    for (int k = b * 256 + t; k < m; k += 1024 * 256) {
        float d = negval[k] - posval[k];
        s += fmaxf(d, 0.f) + log1pf(expf(-fabsf(d)));
    }
    __shared__ float red[256];
    red[t] = s; __syncthreads();
    for (int off = 128; off > 0; off >>= 1) { if (t < off) red[t] += red[t + off]; __syncthreads(); }
    if (t == 0) lp[b] = red[0];
}

__global__ void loss_final(const float* __restrict__ lp, const int* __restrict__ iscal,
                           float* __restrict__ outp)
{
    int t = threadIdx.x;   // 256
    double s = 0.0;
    for (int k = t; k < 1024; k += 256) s += (double)lp[k];
    __shared__ double red[256];
    red[t] = s; __syncthreads();
    for (int off = 128; off > 0; off >>= 1) { if (t < off) red[t] += red[t + off]; __syncthreads(); }
    if (t == 0) {
        int m = iscal[1]; if (m < 1) m = 1;
        outp[0] = (float)(red[0] / (double)m);
    }
}

// row-wise top-8 (ties -> lower index)
__global__ void topk8(const float* __restrict__ dist, float* __restrict__ topv, int* __restrict__ topi)
{
    int row = blockIdx.x, t = threadIdx.x;
    __shared__ float sv[1024];
    __shared__ float rv[256];
    __shared__ int   ri[256];
    for (int j = t; j < 1024; j += 256) sv[j] = dist[(size_t)row * 1024 + j];
    __syncthreads();
    for (int k = 0; k < 8; ++k) {
        float bv = -1e30f; int bi = 1 << 20;
        for (int j = t; j < 1024; j += 256) {
            float x = sv[j];
            if (x > bv || (x == bv && j < bi)) { bv = x; bi = j; }
        }
        rv[t] = bv; ri[t] = bi;
        __syncthreads();
        for (int s = 128; s > 0; s >>= 1) {
            if (t < s) {
                float ov = rv[t + s]; int oi = ri[t + s];
                if (ov > rv[t] || (ov == rv[t] && oi < ri[t])) { rv[t] = ov; ri[t] = oi; }
            }
            __syncthreads();
        }
        if (t == 0) { topv[row * 8 + k] = rv[0]; topi[row * 8 + k] = ri[0]; sv[ri[0]] = -1e30f; }
        __syncthreads();
    }
}

// bn3: per-ROI-channel stats over (N=1024, L=8); writes final output
__global__ void bn3_k(const float* __restrict__ X, const float* __restrict__ g,
                      const float* __restrict__ bta, float* __restrict__ out)
{
    int c = blockIdx.x, t = threadIdx.x;   // 116 x 256
    float s = 0.f, s2 = 0.f;
    for (int k = t; k < 8192; k += 256) {
        int n = k >> 3, l = k & 7;
        float v = X[(size_t)n * 928 + c * 8 + l];
        s += v; s2 += v * v;
    }
    __shared__ float rs[256], rs2[256];
    rs[t] = s; rs2[t] = s2; __syncthreads();
    for (int off = 128; off > 0; off >>= 1) {
        if (t < off) { rs[t] += rs[t + off]; rs2[t] += rs2[t + off]; }
        __syncthreads();
    }
    __shared__ float sm, sr;
    if (t == 0) {
        float mean = rs[0] / 8192.f;
        float var = rs2[0] / 8192.f - mean * mean;
        sm = mean; sr = 1.f / sqrtf(var + EPSBN);
    }
    __syncthreads();
    float mean = sm, rstd = sr, gg = g[c], bb = bta[c];
    for (int k = t; k < 8192; k += 256) {
        int n = k >> 3, l = k & 7;
        size_t idx = (size_t)n * 928 + c * 8 + l;
        out[idx] = (X[idx] - mean) * rstd * gg + bb;
    }
}

// ---------------------------------------------------------------------------
extern "C" void kernel_launch(void* const* d_in, const int* in_sizes, int n_in,
                              void* d_out, int out_size, void* d_ws, size_t ws_size,
                              hipStream_t stream)
{
    const float* x        = (const float*)d_in[0];
    const float* pseudo   = (const float*)d_in[1];
    const int*   ages     = (const int*)d_in[2];
    const int*   genders  = (const int*)d_in[3];
    const int*   site     = (const int*)d_in[4];
    const float* fc_p_w   = (const float*)d_in[5];
    const float* fc_p_b   = (const float*)d_in[6];
    const float* proj_w1  = (const float*)d_in[7];
    const float* proj_b1  = (const float*)d_in[8];
    const float* proj_w2  = (const float*)d_in[9];
    const float* proj_b2  = (const float*)d_in[10];
    const float* gcn_w1   = (const float*)d_in[11];
    const float* gcn_b1   = (const float*)d_in[12];
    const float* gcn_w2   = (const float*)d_in[13];
    const float* gcn_b2   = (const float*)d_in[14];
    const float* gcn1_w   = (const float*)d_in[15];
    const float* gcn1_b   = (const float*)d_in[16];
    const float* gcn2_w1  = (const float*)d_in[17];
    const float* gcn2_b1  = (const float*)d_in[18];
    const float* gcn2_w2  = (const float*)d_in[19];
    const float* gcn2_b2  = (const float*)d_in[20];
    const float* bn1_g    = (const float*)d_in[21];
    const float* bn1_b    = (const float*)d_in[22];
    const float* bn2_g    = (const float*)d_in[23];
    const float* bn2_b    = (const float*)d_in[24];
    const float* bn3_g    = (const float*)d_in[25];
    const float* bn3_b    = (const float*)d_in[26];
    float* dout = (float*)d_out;

    char* w = (char*)d_ws;
    size_t off = 0;
    auto carve = [&](size_t bytes) { char* p = w + off; off = (off + bytes + 255) & ~(size_t)255; return p; };
    float* xf     = (float*)carve((size_t)NROWS * LDF * 4);   // 58.0 MB padded
    float* hA     = (float*)carve((size_t)NROWS * LDF * 4);
    float* hB     = (float*)carve((size_t)NROWS * LDF * 4);
    float* G      = (float*)carve(1048576u * 4);
    float* simb   = (float*)carve(1048576u * 4);
    float* t1     = (float*)carve((size_t)NBZ * ROIN * 4);
    float* pbuf   = (float*)carve((size_t)NBZ * ROIN * 4);
    float* sq     = (float*)carve(4096);
    float* rsq    = (float*)carve((size_t)NROWS * 4);
    int*   labels = (int*)carve(4096);
    int*   rowcnt = (int*)carve(4096);
    int*   rowoff = (int*)carve(4096);
    int*   iscal  = (int*)carve(256);
    float* fscal  = (float*)carve(256);
    float* posval = (float*)carve(524288u * 4);
    float* negval = (float*)carve(524288u * 4);
    float* lpart  = (float*)carve(4096);
    float* mmpart = (float*)carve(4096);
    float* topv   = (float*)carve(32768);
    int*   topi   = (int*)carve(32768);
    float* statp  = (float*)carve((size_t)232 * GX2 * 4);
    float* sbA    = (float*)carve(512);
    float* tbA    = (float*)carve(512);
    float* sbB    = (float*)carve(512);
    float* tbB    = (float*)carve(512);
    short* wt1_hi = (short*)carve((size_t)128 * W1LD * 2);    // 3.8 MB
    short* wt1_lo = (short*)carve((size_t)128 * W1LD * 2);
    short* wts    = (short*)carve((size_t)7 * 2 * 16384 * 2);
    // aliases into dead phases:
    float* ppart  = hA;                             // proj1 partials (13.8 MB)
    float* gpart  = hA;                             // Gram partials 16*36*64KB = 37.7 MB (fits hA)
    short* xfh    = (short*)((char*)hB + (16u << 20));  // bf16 xf 30.4 MB at hB+16MB

    auto wt_hi = [&](int i) { return wts + (size_t)i * 2 * 16384; };
    auto wt_lo = [&](int i) { return wts + (size_t)i * 2 * 16384 + 16384; };

    // 0. weight pretranspose + hi/lo split
    wt1_conv<<<(128 * W1LD) / 256, 256, 0, stream>>>(proj_w1, wt1_hi, wt1_lo);
    wt_conv<<<64, 256, 0, stream>>>(fc_p_w,   wt_hi(0), wt_lo(0), 116, 116);
    wt_conv<<<64, 256, 0, stream>>>(proj_w2,  wt_hi(1), wt_lo(1), 116, 116);
    wt_conv<<<64, 256, 0, stream>>>(gcn_w1,   wt_hi(2), wt_lo(2), 116, 116);
    wt_conv<<<64, 256, 0, stream>>>(gcn_w2,   wt_hi(3), wt_lo(3), 116, 116);
    wt_conv<<<64, 256, 0, stream>>>(gcn1_w,   wt_hi(4), wt_lo(4), 116, 116);
    wt_conv<<<64, 256, 0, stream>>>(gcn2_w1,  wt_hi(5), wt_lo(5), 116, 64);
    wt_conv<<<64, 256, 0, stream>>>(gcn2_w2,  wt_hi(6), wt_lo(6), 64, 8);

    // 1. xf = x + leaky(pseudo @ fc_p_w + b) padded; permuted bf16 xfh + row sumsq
    mfma_gemm_w<4, 1, false><<<GX2, 512, 0, stream>>>(pseudo, wt_hi(0), wt_lo(0), fc_p_b, x, xf,
                                                      xfh, rsq, nullptr, ROIN, LDF);
    sq_reduce<<<4, 256, 0, stream>>>(rsq, sq);

    // 2. proj head
    mfma_proj1<<<dim3(16, 1, PZ), 256, 0, stream>>>(xf, wt1_hi, wt1_lo, ppart);
    proj_reduce<<<(NBZ * ROIN + 255) / 256, 256, 0, stream>>>(ppart, proj_b1, t1);
    mfma_gemm_w<1, 0, false><<<8, 512, 0, stream>>>(t1, wt_hi(1), wt_lo(1), proj_b2, nullptr, pbuf,
                                                    nullptr, nullptr, nullptr, ROIN, ROIN);
    rownorm<<<NBZ, 128, 0, stream>>>(pbuf);

    // 3. sim = (pn @ pn^T) / TEMP
    gemm_nt_sym<<<dim3(16, 16, 1), 256, 0, stream>>>(pbuf, simb, NBZ, ROIN, 1.f / 0.07f);

    // 4. contrastive loss
    labels_k<<<4, 256, 0, stream>>>(site, labels);
    rowcnt_k<<<4, 256, 0, stream>>>(labels, rowcnt);
    scan_k<<<1, 1024, 0, stream>>>(rowcnt, rowoff, iscal);
    pair_scatter<<<NBZ, 256, 0, stream>>>(labels, rowoff, iscal, simb, posval, negval);
    loss_part<<<1024, 256, 0, stream>>>(posval, negval, iscal, lpart);
    loss_final<<<1, 256, 0, stream>>>(lpart, iscal, dout + (size_t)NBZ * ROIN * 8);

    // 5. sim min/max, Gram (XCD-affine), fused reduce+dist, top-k
    minmax_part<<<512, 256, 0, stream>>>(simb, mmpart);
    minmax_final<<<1, 512, 0, stream>>>(mmpart, fscal);
    gram_mfma<<<NTRI * GRAMZ, 256, 0, stream>>>(xfh, gpart);
    gram_reduce_dist<<<dim3(NTRI, 16), 256, 0, stream>>>(gpart, simb, sq, ages, genders, fscal, G);
    topk8<<<NBZ, 256, 0, stream>>>(G, topv, topi);

    // 6. GCN stack: gather fused into GEMMs; BN stats fused, apply folded
    mfma_gemm_wg<3, 0, false><<<GX2, 512, 0, stream>>>(topv, topi, xf, nullptr, nullptr,
                                                       wt_hi(2), wt_lo(2), gcn_b1, hB, nullptr);
    mfma_gemm_w<1, 2, true><<<GX2, 512, 0, stream>>>(hB, wt_hi(3), wt_lo(3), gcn_b2, nullptr, hA,
                                                     nullptr, nullptr, statp, LDF, LDF);
    bn_final_st<<<116, 256, 0, stream>>>(statp, bn1_g, bn1_b, sbA, tbA);

    mfma_gemm_wg<3, 2, true><<<GX2, 512, 0, stream>>>(topv, topi, hA, sbA, tbA,
                                                      wt_hi(4), wt_lo(4), gcn1_b, hB, statp);
    bn_final_st<<<116, 256, 0, stream>>>(statp, bn2_g, bn2_b, sbB, tbB);

    mfma_gemm45_wg<<<GX45, 256, 0, stream>>>(topv, topi, hB, sbB, tbB,
                                             wt_hi(5), wt_lo(5), gcn2_b1,
                                             wt_hi(6), wt_lo(6), gcn2_b2, hA);

    // 7. bn3 -> d_out
    bn3_k<<<116, 256, 0, stream>>>(hA, bn3_g, bn3_b, dout);
}